// Round 1
// baseline (5533.947 us; speedup 1.0000x reference)
//
#include <hip/hip_runtime.h>
#include <math.h>

#define BB 2
#define CC 128
#define NN 4096
#define KK 16
#define DIMD 256
#define PHH 64
#define AHH 1024
#define EPSF 1e-5f
#define PT 16
#define RNS 16

// ---------------- K0: zero scratch accumulators ----------------
__global__ void zero_kernel(float* p, int n) {
    int i = blockIdx.x * blockDim.x + threadIdx.x;
    if (i < n) p[i] = 0.f;
}

// ---------------- K1: exact kNN (16 nearest incl. self) ----------------
__global__ __launch_bounds__(256) void knn_kernel(const float* __restrict__ pos,
                                                  int* __restrict__ idx) {
    int bid = blockIdx.x;
    int b = bid / NN, n = bid % NN;
    int t = threadIdx.x;
    const float* px = pos + (size_t)b * 3 * NN;
    const float* py = px + NN;
    const float* pz = px + 2 * NN;
    float qx = px[n], qy = py[n], qz = pz[n];
    float qs = qx * qx + qy * qy + qz * qz;

    // each thread owns 16 candidates (static-indexed, stays in VGPRs)
    float bd[KK]; int bi[KK];
#pragma unroll
    for (int j = 0; j < KK; ++j) {
        int m = t + 256 * j;
        float mx = px[m], my = py[m], mz = pz[m];
        float ms = mx * mx + my * my + mz * mz;
        float dt = qx * mx + qy * my + qz * mz;
        bd[j] = qs + ms - 2.f * dt;
        bi[j] = m;
    }

    __shared__ float wvs[4]; __shared__ int wis[4], wos[4];
    __shared__ int winO;
    unsigned consumed = 0;

    for (int r = 0; r < KK; ++r) {
        // local argmin over unconsumed candidates (lexicographic (d, idx))
        float v = 3.4e38f; int ii = 0x7fffffff; int jb = 0;
#pragma unroll
        for (int jx = 0; jx < KK; ++jx) {
            bool alive = ((consumed >> jx) & 1u) == 0u;
            bool better = alive && (bd[jx] < v || (bd[jx] == v && bi[jx] < ii));
            if (better) { v = bd[jx]; ii = bi[jx]; jb = jx; }
        }
        int ow = t;
        // wave argmin
#pragma unroll
        for (int off = 32; off >= 1; off >>= 1) {
            float ov = __shfl_down(v, off);
            int   oi = __shfl_down(ii, off);
            int   oo = __shfl_down(ow, off);
            if (ov < v || (ov == v && oi < ii)) { v = ov; ii = oi; ow = oo; }
        }
        if ((t & 63) == 0) { int w = t >> 6; wvs[w] = v; wis[w] = ii; wos[w] = ow; }
        __syncthreads();
        if (t == 0) {
            float bv = wvs[0]; int bI = wis[0], bO = wos[0];
            for (int w = 1; w < 4; ++w)
                if (wvs[w] < bv || (wvs[w] == bv && wis[w] < bI)) { bv = wvs[w]; bI = wis[w]; bO = wos[w]; }
            winO = bO;
            idx[(size_t)bid * KK + r] = bI;
        }
        __syncthreads();
        if (t == winO) consumed |= (1u << jb);
        __syncthreads();
    }
}

// ---------------- K2: h1 = relu(W1·[key;query] + b1) ----------------
__global__ __launch_bounds__(256) void h1_kernel(const float* __restrict__ key,
                                                 const float* __restrict__ query,
                                                 const float* __restrict__ w1,
                                                 const float* __restrict__ b1,
                                                 float* __restrict__ h1) {
    int n = blockIdx.x * 256 + threadIdx.x;
    int o = blockIdx.y, b = blockIdx.z;
    const float* wr = w1 + (size_t)o * 256;
    const float* kb = key + (size_t)b * CC * NN;
    const float* qb = query + (size_t)b * CC * NN;
    float acc = b1[o];
#pragma unroll 4
    for (int i = 0; i < CC; ++i) acc += wr[i] * kb[(size_t)i * NN + n];
#pragma unroll 4
    for (int i = 0; i < CC; ++i) acc += wr[CC + i] * qb[(size_t)i * NN + n];
    h1[((size_t)b * CC + o) * NN + n] = fmaxf(acc, 0.f);
}

// ---------------- K3: value = W2·h1 + b2 + Ws·[key;query] + bs ----------------
__global__ __launch_bounds__(256) void value_kernel(const float* __restrict__ key,
                                                    const float* __restrict__ query,
                                                    const float* __restrict__ h1buf,
                                                    const float* __restrict__ w2,
                                                    const float* __restrict__ b2,
                                                    const float* __restrict__ wsk,
                                                    const float* __restrict__ bs,
                                                    float* __restrict__ value) {
    int n = blockIdx.x * 256 + threadIdx.x;
    int o = blockIdx.y, b = blockIdx.z;
    const float* w2r = w2 + (size_t)o * CC;
    const float* wsr = wsk + (size_t)o * 256;
    const float* kb = key + (size_t)b * CC * NN;
    const float* qb = query + (size_t)b * CC * NN;
    const float* hb = h1buf + (size_t)b * CC * NN;
    float acc = b2[o] + bs[o];
#pragma unroll 4
    for (int i = 0; i < CC; ++i) acc += w2r[i] * hb[(size_t)i * NN + n];
#pragma unroll 4
    for (int i = 0; i < CC; ++i) acc += wsr[i] * kb[(size_t)i * NN + n];
#pragma unroll 4
    for (int i = 0; i < CC; ++i) acc += wsr[CC + i] * qb[(size_t)i * NN + n];
    value[((size_t)b * CC + o) * NN + n] = acc;
}

// ---------------- K4: outT[b][n][o] = bias[o] + W(256x128)·X[b,:,n] ----------------
__global__ __launch_bounds__(256) void convT_kernel(const float* __restrict__ W,
                                                    const float* __restrict__ bias,
                                                    const float* __restrict__ X,
                                                    float* __restrict__ outT) {
    __shared__ float xs[PT][CC + 1];
    int b = blockIdx.y;
    int n0 = blockIdx.x * PT;
    int t = threadIdx.x;
    for (int l = t; l < PT * CC; l += 256) {
        int p = l & (PT - 1); int i = l >> 4;
        xs[p][i] = X[((size_t)b * CC + i) * NN + n0 + p];
    }
    __syncthreads();
    int o = t;
    const float* wr = W + (size_t)o * CC;
    float acc[PT];
    float bo = bias[o];
#pragma unroll
    for (int p = 0; p < PT; ++p) acc[p] = bo;
    for (int i = 0; i < CC; ++i) {
        float w = wr[i];
#pragma unroll
        for (int p = 0; p < PT; ++p) acc[p] += w * xs[p][i];
    }
#pragma unroll
    for (int p = 0; p < PT; ++p)
        outT[((size_t)b * NN + n0 + p) * DIMD + o] = acc[p];
}

// ---------------- K5: pos_rel first/second moments (9 sums) ----------------
__global__ __launch_bounds__(256) void pos_stats_kernel(const float* __restrict__ pos,
                                                        const int* __restrict__ idx,
                                                        float* __restrict__ stats) {
    int sid = blockIdx.x * 256 + threadIdx.x;
    int b = sid / (NN * KK);
    int r = sid % (NN * KK);
    int n = r / KK;
    int m = idx[sid];
    const float* px = pos + (size_t)b * 3 * NN;
    float dx = px[n] - px[m];
    float dy = px[NN + n] - px[NN + m];
    float dz = px[2 * NN + n] - px[2 * NN + m];
    float v[9] = {dx, dy, dz, dx * dx, dy * dy, dz * dz, dx * dy, dx * dz, dy * dz};
    __shared__ float red[256];
    for (int j = 0; j < 9; ++j) {
        red[threadIdx.x] = v[j];
        __syncthreads();
        for (int off = 128; off >= 1; off >>= 1) {
            if (threadIdx.x < off) red[threadIdx.x] += red[threadIdx.x + off];
            __syncthreads();
        }
        if (threadIdx.x == 0) atomicAdd(&stats[j], red[0]);
        __syncthreads();
    }
}

// ---------------- K6: pos BN affine (a1, a0) per 64 channels ----------------
__global__ void pos_bn_kernel(const float* __restrict__ stats, const float* __restrict__ pw1,
                              const float* __restrict__ pb1, const float* __restrict__ pg1,
                              const float* __restrict__ pbe1, float* __restrict__ posA) {
    int c = threadIdx.x;
    if (c >= PHH) return;
    float M = (float)(BB * NN * KK);
    float mu0 = stats[0] / M, mu1 = stats[1] / M, mu2 = stats[2] / M;
    float E00 = stats[3] / M, E11 = stats[4] / M, E22 = stats[5] / M;
    float E01 = stats[6] / M, E02 = stats[7] / M, E12 = stats[8] / M;
    float w0 = pw1[c * 3], w1 = pw1[c * 3 + 1], w2 = pw1[c * 3 + 2];
    float wmu = w0 * mu0 + w1 * mu1 + w2 * mu2;
    float mean_h = wmu + pb1[c];
    float Eh2 = w0 * w0 * E00 + w1 * w1 * E11 + w2 * w2 * E22
              + 2.f * (w0 * w1 * E01 + w0 * w2 * E02 + w1 * w2 * E12)
              + 2.f * pb1[c] * wmu + pb1[c] * pb1[c];
    float var = Eh2 - mean_h * mean_h;
    float a1 = pg1[c] * rsqrtf(var + EPSF);
    posA[c] = a1;
    posA[PHH + c] = pbe1[c] - mean_h * a1;
}

// ---------------- K7: pos_emb + s = q - k_g + pe (rows of 256) ----------------
__global__ __launch_bounds__(256) void posemb_s_kernel(const float* __restrict__ pos,
                                                       const int* __restrict__ idx,
                                                       const float* __restrict__ pw1,
                                                       const float* __restrict__ pb1,
                                                       const float* __restrict__ posA,
                                                       const float* __restrict__ pw2,
                                                       const float* __restrict__ pb2,
                                                       const float* __restrict__ qT,
                                                       const float* __restrict__ kT,
                                                       float* __restrict__ sbuf) {
    int bid = blockIdx.x;
    int b = bid / NN, n = bid % NN;
    int t = threadIdx.x;
    __shared__ int sm[KK];
    __shared__ float pr[KK][4];
    __shared__ float p1r[KK][PHH];
    if (t < KK) {
        int m = idx[(size_t)bid * KK + t];
        sm[t] = m;
        const float* px = pos + (size_t)b * 3 * NN;
        pr[t][0] = px[n] - px[m];
        pr[t][1] = px[NN + n] - px[NN + m];
        pr[t][2] = px[2 * NN + n] - px[2 * NN + m];
    }
    __syncthreads();
    for (int l = t; l < KK * PHH; l += 256) {
        int s_ = l >> 6, j = l & 63;
        float h = pw1[j * 3] * pr[s_][0] + pw1[j * 3 + 1] * pr[s_][1] + pw1[j * 3 + 2] * pr[s_][2] + pb1[j];
        p1r[s_][j] = fmaxf(h * posA[j] + posA[PHH + j], 0.f);
    }
    __syncthreads();
    int c = t;
    const float4* w2r4 = (const float4*)(pw2 + (size_t)c * PHH);
    float q = qT[((size_t)b * NN + n) * DIMD + c];
    float bb2 = pb2[c];
    float* srow = sbuf + (size_t)bid * KK * DIMD;
    for (int s_ = 0; s_ < KK; ++s_) {
        const float4* pr4 = (const float4*)p1r[s_];
        float pe = bb2;
#pragma unroll
        for (int j4 = 0; j4 < PHH / 4; ++j4) {
            float4 w4 = w2r4[j4]; float4 h4 = pr4[j4];
            pe += w4.x * h4.x + w4.y * h4.y + w4.z * h4.z + w4.w * h4.w;
        }
        float kv = kT[((size_t)b * NN + sm[s_]) * DIMD + c];
        srow[s_ * DIMD + c] = q - kv + pe;
    }
}

// ---------------- K8: mu = column sums of s ----------------
__global__ __launch_bounds__(256) void mu_kernel(const float* __restrict__ sbuf,
                                                 float* __restrict__ mu) {
    int c = threadIdx.x;
    const float* p = sbuf + (size_t)blockIdx.x * 512 * DIMD + c;
    float acc = 0.f;
    for (int i = 0; i < 512; ++i) acc += p[(size_t)i * DIMD];
    atomicAdd(&mu[c], acc);
}

// ---------------- K9: R = sum s s^T (256x256) ----------------
__global__ __launch_bounds__(256) void R_kernel(const float* __restrict__ sbuf,
                                                float* __restrict__ R) {
    int tile = blockIdx.x & 15;
    int chunk = blockIdx.x >> 4;  // 0..31
    int ti = tile >> 2, tj = tile & 3;
    int t = threadIdx.x;
    int ty = t >> 4, tx = t & 15;
    __shared__ float si[RNS][64];
    __shared__ float sj[RNS][64];
    float acc[4][4];
#pragma unroll
    for (int a = 0; a < 4; ++a)
#pragma unroll
        for (int b2 = 0; b2 < 4; ++b2) acc[a][b2] = 0.f;
    int base = chunk * 4096;
    for (int stage = 0; stage < 4096 / RNS; ++stage) {
        int sbase = base + stage * RNS;
#pragma unroll
        for (int rl = 0; rl < 8; ++rl) {
            int l = rl * 256 + t;
            int samp = l >> 7;
            int half = (l >> 6) & 1;
            int f = l & 63;
            float val = sbuf[(size_t)(sbase + samp) * DIMD + (half ? tj * 64 : ti * 64) + f];
            if (half) sj[samp][f] = val; else si[samp][f] = val;
        }
        __syncthreads();
#pragma unroll
        for (int samp = 0; samp < RNS; ++samp) {
            float4 av = *(const float4*)&si[samp][ty * 4];
            float4 bv = *(const float4*)&sj[samp][tx * 4];
            float aa[4] = {av.x, av.y, av.z, av.w};
            float bb[4] = {bv.x, bv.y, bv.z, bv.w};
#pragma unroll
            for (int a = 0; a < 4; ++a)
#pragma unroll
                for (int b2 = 0; b2 < 4; ++b2) acc[a][b2] += aa[a] * bb[b2];
        }
        __syncthreads();
    }
#pragma unroll
    for (int a = 0; a < 4; ++a)
#pragma unroll
        for (int b2 = 0; b2 < 4; ++b2)
            atomicAdd(&R[(size_t)(ti * 64 + ty * 4 + a) * DIMD + tj * 64 + tx * 4 + b2], acc[a][b2]);
}

// ---------------- K10: attn BN affine per 1024 hidden channels ----------------
__global__ __launch_bounds__(256) void attn_bn_kernel(const float* __restrict__ R,
                                                      const float* __restrict__ mu,
                                                      const float* __restrict__ aw1,
                                                      const float* __restrict__ ab1,
                                                      const float* __restrict__ ag1,
                                                      const float* __restrict__ abe1,
                                                      float* __restrict__ attA) {
    int c = blockIdx.x;
    int t = threadIdx.x;
    __shared__ float wsh[DIMD];
    __shared__ float red[DIMD];
    wsh[t] = aw1[(size_t)c * DIMD + t];
    __syncthreads();
    const float* Rr = R + (size_t)t * DIMD;
    float q = 0.f;
#pragma unroll 4
    for (int j = 0; j < DIMD; ++j) q += Rr[j] * wsh[j];
    red[t] = q * wsh[t];
    __syncthreads();
    for (int off = 128; off >= 1; off >>= 1) {
        if (t < off) red[t] += red[t + off];
        __syncthreads();
    }
    float wRw = red[0];
    __syncthreads();
    red[t] = wsh[t] * mu[t];
    __syncthreads();
    for (int off = 128; off >= 1; off >>= 1) {
        if (t < off) red[t] += red[t + off];
        __syncthreads();
    }
    if (t == 0) {
        float M = (float)(BB * NN * KK);
        float wmu = red[0] / M;
        float b1c = ab1[c];
        float Eh = wmu + b1c;
        float Eh2 = wRw / M + 2.f * b1c * wmu + b1c * b1c;
        float var = Eh2 - Eh * Eh;
        float a1 = ag1[c] * rsqrtf(var + EPSF);
        attA[c] = a1;
        attA[AHH + c] = abe1[c] - Eh * a1;
    }
}

// ---------------- K11: attn MLP + softmax + aggregation ----------------
__global__ __launch_bounds__(256) void attn_main_kernel(const int* __restrict__ idx,
                                                        const float* __restrict__ sbuf,
                                                        const float* __restrict__ aw1,
                                                        const float* __restrict__ ab1,
                                                        const float* __restrict__ attA,
                                                        const float* __restrict__ aw2,
                                                        const float* __restrict__ ab2,
                                                        const float* __restrict__ qT,
                                                        const float* __restrict__ kT,
                                                        const float* __restrict__ vT,
                                                        float* __restrict__ aggT) {
    int bid = blockIdx.x;
    int b = bid / NN, n = bid % NN;
    int t = threadIdx.x;
    __shared__ float ss[KK][DIMD];
    __shared__ float hh[KK][128];
    __shared__ int sm[KK];
    const float* srow = sbuf + (size_t)bid * KK * DIMD;
    for (int l = t; l < KK * DIMD; l += 256) ss[l >> 8][l & 255] = srow[l];
    if (t < KK) sm[t] = idx[(size_t)bid * KK + t];
    __syncthreads();

    int c = t;
    float acc[KK];
#pragma unroll
    for (int s_ = 0; s_ < KK; ++s_) acc[s_] = ab2[c];
    int j = t & 127;
    int sg = t >> 7;  // 0/1: which 8 samples this thread computes hidden for

    for (int jc = 0; jc < AHH / 128; ++jc) {
        int jrow = jc * 128 + j;
        const float4* w1r = (const float4*)(aw1 + (size_t)jrow * DIMD);
        float h[8];
        float hb = ab1[jrow];
#pragma unroll
        for (int r = 0; r < 8; ++r) h[r] = hb;
        for (int i4 = 0; i4 < DIMD / 4; ++i4) {
            float4 w4 = w1r[i4];
#pragma unroll
            for (int r = 0; r < 8; ++r) {
                float4 s4 = ((const float4*)ss[sg * 8 + r])[i4];
                h[r] += w4.x * s4.x + w4.y * s4.y + w4.z * s4.z + w4.w * s4.w;
            }
        }
        float a1 = attA[jrow], a0 = attA[AHH + jrow];
#pragma unroll
        for (int r = 0; r < 8; ++r) hh[sg * 8 + r][j] = fmaxf(h[r] * a1 + a0, 0.f);
        __syncthreads();
        const float4* w2r = (const float4*)(aw2 + (size_t)c * AHH + jc * 128);
        for (int j4 = 0; j4 < 32; ++j4) {
            float4 w4 = w2r[j4];
#pragma unroll
            for (int s_ = 0; s_ < KK; ++s_) {
                float4 h4 = ((const float4*)hh[s_])[j4];
                acc[s_] += w4.x * h4.x + w4.y * h4.y + w4.z * h4.z + w4.w * h4.w;
            }
        }
        __syncthreads();
    }

    // softmax over K (per channel c, all K logits live in this thread)
    float mx = acc[0];
#pragma unroll
    for (int s_ = 1; s_ < KK; ++s_) mx = fmaxf(mx, acc[s_]);
    float sum = 0.f;
#pragma unroll
    for (int s_ = 0; s_ < KK; ++s_) { acc[s_] = expf(acc[s_] - mx); sum += acc[s_]; }
    float inv = 1.f / sum;
    float q = qT[((size_t)b * NN + n) * DIMD + c];
    float vf = vT[((size_t)b * NN + n) * DIMD + c];
    float agg = 0.f;
#pragma unroll
    for (int s_ = 0; s_ < KK; ++s_) {
        float kv = kT[((size_t)b * NN + sm[s_]) * DIMD + c];
        // pos_emb = s - (q - k_g)  =>  v = v_f + pos_emb
        float vv = vf + ss[s_][c] - q + kv;
        agg += acc[s_] * inv * vv;
    }
    aggT[((size_t)b * NN + n) * DIMD + c] = agg;
}

// ---------------- K12: y = we·agg + be + identity ----------------
__global__ __launch_bounds__(256) void final_kernel(const float* __restrict__ aggT,
                                                    const float* __restrict__ we,
                                                    const float* __restrict__ be,
                                                    const float* __restrict__ value,
                                                    float* __restrict__ out) {
    int n = blockIdx.x * 256 + threadIdx.x;
    int o = blockIdx.y, b = blockIdx.z;
    const float* wr = we + (size_t)o * DIMD;
    const float* ar = aggT + ((size_t)b * NN + n) * DIMD;
    float acc = be[o];
#pragma unroll 4
    for (int i = 0; i < DIMD; ++i) acc += wr[i] * ar[i];
    size_t oi = ((size_t)b * CC + o) * NN + n;
    out[oi] = acc + value[oi];
}

extern "C" void kernel_launch(void* const* d_in, const int* in_sizes, int n_in,
                              void* d_out, int out_size, void* d_ws, size_t ws_size,
                              hipStream_t stream) {
    (void)in_sizes; (void)n_in; (void)out_size; (void)ws_size;
    const float* pos     = (const float*)d_in[0];
    const float* key     = (const float*)d_in[1];
    const float* query   = (const float*)d_in[2];
    const float* mlpv_w1 = (const float*)d_in[3];
    const float* mlpv_b1 = (const float*)d_in[4];
    const float* mlpv_w2 = (const float*)d_in[5];
    const float* mlpv_b2 = (const float*)d_in[6];
    const float* mlpv_ws = (const float*)d_in[7];
    const float* mlpv_bs = (const float*)d_in[8];
    const float* wk  = (const float*)d_in[9];
    const float* bk  = (const float*)d_in[10];
    const float* wq  = (const float*)d_in[11];
    const float* bq  = (const float*)d_in[12];
    const float* wv  = (const float*)d_in[13];
    const float* bv  = (const float*)d_in[14];
    const float* pw1 = (const float*)d_in[15];
    const float* pb1 = (const float*)d_in[16];
    const float* pg1 = (const float*)d_in[17];
    const float* pbe1= (const float*)d_in[18];
    const float* pw2 = (const float*)d_in[19];
    const float* pb2 = (const float*)d_in[20];
    const float* aw1 = (const float*)d_in[21];
    const float* ab1 = (const float*)d_in[22];
    const float* ag1 = (const float*)d_in[23];
    const float* abe1= (const float*)d_in[24];
    const float* aw2 = (const float*)d_in[25];
    const float* ab2 = (const float*)d_in[26];
    const float* we  = (const float*)d_in[27];
    const float* be  = (const float*)d_in[28];
    float* out = (float*)d_out;

    char* wsb = (char*)d_ws;
    size_t off = 0;
    auto alloc = [&](size_t bytes) {
        void* p = wsb + off;
        off += (bytes + 255) & ~(size_t)255;
        return p;
    };
    int*   idx   = (int*)  alloc((size_t)BB * NN * KK * 4);
    float* h1buf = (float*)alloc((size_t)BB * CC * NN * 4);
    float* value = (float*)alloc((size_t)BB * CC * NN * 4);
    float* kT    = (float*)alloc((size_t)BB * NN * DIMD * 4);
    float* qT    = (float*)alloc((size_t)BB * NN * DIMD * 4);
    float* vT    = (float*)alloc((size_t)BB * NN * DIMD * 4);
    float* aggT  = (float*)alloc((size_t)BB * NN * DIMD * 4);
    float* zero0 = (float*)alloc((size_t)(16 + 256 + 65536) * 4);
    float* stats = zero0;
    float* mu    = zero0 + 16;
    float* R     = zero0 + 16 + 256;
    float* posA  = (float*)alloc((size_t)2 * PHH * 4);
    float* attA  = (float*)alloc((size_t)2 * AHH * 4);
    float* sbuf  = (float*)alloc((size_t)BB * NN * KK * DIMD * 4);  // 128 MB

    int ZN = 16 + 256 + 65536;
    zero_kernel<<<(ZN + 255) / 256, 256, 0, stream>>>(zero0, ZN);
    knn_kernel<<<BB * NN, 256, 0, stream>>>(pos, idx);
    h1_kernel<<<dim3(NN / 256, CC, BB), 256, 0, stream>>>(key, query, mlpv_w1, mlpv_b1, h1buf);
    value_kernel<<<dim3(NN / 256, CC, BB), 256, 0, stream>>>(key, query, h1buf, mlpv_w2, mlpv_b2, mlpv_ws, mlpv_bs, value);
    convT_kernel<<<dim3(NN / PT, BB), 256, 0, stream>>>(wk, bk, key, kT);
    convT_kernel<<<dim3(NN / PT, BB), 256, 0, stream>>>(wq, bq, query, qT);
    convT_kernel<<<dim3(NN / PT, BB), 256, 0, stream>>>(wv, bv, value, vT);
    pos_stats_kernel<<<BB * NN * KK / 256, 256, 0, stream>>>(pos, idx, stats);
    pos_bn_kernel<<<1, 64, 0, stream>>>(stats, pw1, pb1, pg1, pbe1, posA);
    posemb_s_kernel<<<BB * NN, 256, 0, stream>>>(pos, idx, pw1, pb1, posA, pw2, pb2, qT, kT, sbuf);
    mu_kernel<<<BB * NN * KK / 512, 256, 0, stream>>>(sbuf, mu);
    R_kernel<<<512, 256, 0, stream>>>(sbuf, R);
    attn_bn_kernel<<<AHH, DIMD, 0, stream>>>(R, mu, aw1, ab1, ag1, abe1, attA);
    attn_main_kernel<<<BB * NN, 256, 0, stream>>>(idx, sbuf, aw1, ab1, attA, aw2, ab2, qT, kT, vT, aggT);
    final_kernel<<<dim3(NN / 256, CC, BB), 256, 0, stream>>>(aggT, we, be, value, out);
}

// Round 3
// 2198.553 us; speedup vs baseline: 2.5171x; 2.5171x over previous
//
#include <hip/hip_runtime.h>
#include <math.h>

#define BB 2
#define CC 128
#define NN 4096
#define KK 16
#define DIMD 256
#define PHH 64
#define AHH 1024
#define EPSF 1e-5f
#define PT 16
#define RNS 16
#define MCH 16384   // M-chunk rows (1024 points x K)

typedef unsigned short ushort_t;
typedef __attribute__((ext_vector_type(8))) short short8;
typedef __attribute__((ext_vector_type(4))) float f32x4;

__device__ __forceinline__ ushort_t f2b(float x) {
    union { float f; unsigned u; } v; v.f = x;
    unsigned r = v.u + 0x7fff + ((v.u >> 16) & 1);
    return (ushort_t)(r >> 16);
}
__device__ __forceinline__ float b2f(ushort_t x) {
    union { unsigned u; float f; } v; v.u = ((unsigned)x) << 16;
    return v.f;
}

#define GLDS16(gp, lp) __builtin_amdgcn_global_load_lds( \
    (const __attribute__((address_space(1))) void*)(gp), \
    (__attribute__((address_space(3))) void*)(lp), 16, 0, 0)

// ---------------- K0: zero scratch accumulators ----------------
__global__ void zero_kernel(float* p, int n) {
    int i = blockIdx.x * blockDim.x + threadIdx.x;
    if (i < n) p[i] = 0.f;
}

// ---------------- K1: exact kNN (16 nearest incl. self) ----------------
__global__ __launch_bounds__(256) void knn_kernel(const float* __restrict__ pos,
                                                  int* __restrict__ idx) {
    int bid = blockIdx.x;
    int b = bid / NN, n = bid % NN;
    int t = threadIdx.x;
    const float* px = pos + (size_t)b * 3 * NN;
    const float* py = px + NN;
    const float* pz = px + 2 * NN;
    float qx = px[n], qy = py[n], qz = pz[n];
    float qs = qx * qx + qy * qy + qz * qz;

    float bd[KK]; int bi[KK];
#pragma unroll
    for (int j = 0; j < KK; ++j) {
        int m = t + 256 * j;
        float mx = px[m], my = py[m], mz = pz[m];
        float ms = mx * mx + my * my + mz * mz;
        float dt = qx * mx + qy * my + qz * mz;
        bd[j] = qs + ms - 2.f * dt;
        bi[j] = m;
    }

    __shared__ float wvs[4]; __shared__ int wis[4], wos[4];
    __shared__ int winO;
    unsigned consumed = 0;

    for (int r = 0; r < KK; ++r) {
        float v = 3.4e38f; int ii = 0x7fffffff; int jb = 0;
#pragma unroll
        for (int jx = 0; jx < KK; ++jx) {
            bool alive = ((consumed >> jx) & 1u) == 0u;
            bool better = alive && (bd[jx] < v || (bd[jx] == v && bi[jx] < ii));
            if (better) { v = bd[jx]; ii = bi[jx]; jb = jx; }
        }
        int ow = t;
#pragma unroll
        for (int off = 32; off >= 1; off >>= 1) {
            float ov = __shfl_down(v, off);
            int   oi = __shfl_down(ii, off);
            int   oo = __shfl_down(ow, off);
            if (ov < v || (ov == v && oi < ii)) { v = ov; ii = oi; ow = oo; }
        }
        if ((t & 63) == 0) { int w = t >> 6; wvs[w] = v; wis[w] = ii; wos[w] = ow; }
        __syncthreads();
        if (t == 0) {
            float bv = wvs[0]; int bI = wis[0], bO = wos[0];
            for (int w = 1; w < 4; ++w)
                if (wvs[w] < bv || (wvs[w] == bv && wis[w] < bI)) { bv = wvs[w]; bI = wis[w]; bO = wos[w]; }
            winO = bO;
            idx[(size_t)bid * KK + r] = bI;
        }
        __syncthreads();
        if (t == winO) consumed |= (1u << jb);
        __syncthreads();
    }
}

// ---------------- K2: h1 = relu(W1·[key;query] + b1) ----------------
__global__ __launch_bounds__(256) void h1_kernel(const float* __restrict__ key,
                                                 const float* __restrict__ query,
                                                 const float* __restrict__ w1,
                                                 const float* __restrict__ b1,
                                                 float* __restrict__ h1) {
    int n = blockIdx.x * 256 + threadIdx.x;
    int o = blockIdx.y, b = blockIdx.z;
    const float* wr = w1 + (size_t)o * 256;
    const float* kb = key + (size_t)b * CC * NN;
    const float* qb = query + (size_t)b * CC * NN;
    float acc = b1[o];
#pragma unroll 4
    for (int i = 0; i < CC; ++i) acc += wr[i] * kb[(size_t)i * NN + n];
#pragma unroll 4
    for (int i = 0; i < CC; ++i) acc += wr[CC + i] * qb[(size_t)i * NN + n];
    h1[((size_t)b * CC + o) * NN + n] = fmaxf(acc, 0.f);
}

// ---------------- K3: value = W2·h1 + b2 + Ws·[key;query] + bs ----------------
__global__ __launch_bounds__(256) void value_kernel(const float* __restrict__ key,
                                                    const float* __restrict__ query,
                                                    const float* __restrict__ h1buf,
                                                    const float* __restrict__ w2,
                                                    const float* __restrict__ b2,
                                                    const float* __restrict__ wsk,
                                                    const float* __restrict__ bs,
                                                    float* __restrict__ value) {
    int n = blockIdx.x * 256 + threadIdx.x;
    int o = blockIdx.y, b = blockIdx.z;
    const float* w2r = w2 + (size_t)o * CC;
    const float* wsr = wsk + (size_t)o * 256;
    const float* kb = key + (size_t)b * CC * NN;
    const float* qb = query + (size_t)b * CC * NN;
    const float* hb = h1buf + (size_t)b * CC * NN;
    float acc = b2[o] + bs[o];
#pragma unroll 4
    for (int i = 0; i < CC; ++i) acc += w2r[i] * hb[(size_t)i * NN + n];
#pragma unroll 4
    for (int i = 0; i < CC; ++i) acc += wsr[i] * kb[(size_t)i * NN + n];
#pragma unroll 4
    for (int i = 0; i < CC; ++i) acc += wsr[CC + i] * qb[(size_t)i * NN + n];
    value[((size_t)b * CC + o) * NN + n] = acc;
}

// ---------------- K4: outT[b][n][o] = bias[o] + W(256x128)·X[b,:,n] ----------------
__global__ __launch_bounds__(256) void convT_kernel(const float* __restrict__ W,
                                                    const float* __restrict__ bias,
                                                    const float* __restrict__ X,
                                                    float* __restrict__ outT) {
    __shared__ float xs[PT][CC + 1];
    int b = blockIdx.y;
    int n0 = blockIdx.x * PT;
    int t = threadIdx.x;
    for (int l = t; l < PT * CC; l += 256) {
        int p = l & (PT - 1); int i = l >> 4;
        xs[p][i] = X[((size_t)b * CC + i) * NN + n0 + p];
    }
    __syncthreads();
    int o = t;
    const float* wr = W + (size_t)o * CC;
    float acc[PT];
    float bo = bias[o];
#pragma unroll
    for (int p = 0; p < PT; ++p) acc[p] = bo;
    for (int i = 0; i < CC; ++i) {
        float w = wr[i];
#pragma unroll
        for (int p = 0; p < PT; ++p) acc[p] += w * xs[p][i];
    }
#pragma unroll
    for (int p = 0; p < PT; ++p)
        outT[((size_t)b * NN + n0 + p) * DIMD + o] = acc[p];
}

// ---------------- K5: pos_rel first/second moments (9 sums) ----------------
__global__ __launch_bounds__(256) void pos_stats_kernel(const float* __restrict__ pos,
                                                        const int* __restrict__ idx,
                                                        float* __restrict__ stats) {
    int sid = blockIdx.x * 256 + threadIdx.x;
    int b = sid / (NN * KK);
    int r = sid % (NN * KK);
    int n = r / KK;
    int m = idx[sid];
    const float* px = pos + (size_t)b * 3 * NN;
    float dx = px[n] - px[m];
    float dy = px[NN + n] - px[NN + m];
    float dz = px[2 * NN + n] - px[2 * NN + m];
    float v[9] = {dx, dy, dz, dx * dx, dy * dy, dz * dz, dx * dy, dx * dz, dy * dz};
    __shared__ float red[256];
    for (int j = 0; j < 9; ++j) {
        red[threadIdx.x] = v[j];
        __syncthreads();
        for (int off = 128; off >= 1; off >>= 1) {
            if (threadIdx.x < off) red[threadIdx.x] += red[threadIdx.x + off];
            __syncthreads();
        }
        if (threadIdx.x == 0) atomicAdd(&stats[j], red[0]);
        __syncthreads();
    }
}

// ---------------- K6: pos BN affine (a1, a0) per 64 channels ----------------
__global__ void pos_bn_kernel(const float* __restrict__ stats, const float* __restrict__ pw1,
                              const float* __restrict__ pb1, const float* __restrict__ pg1,
                              const float* __restrict__ pbe1, float* __restrict__ posA) {
    int c = threadIdx.x;
    if (c >= PHH) return;
    float M = (float)(BB * NN * KK);
    float mu0 = stats[0] / M, mu1 = stats[1] / M, mu2 = stats[2] / M;
    float E00 = stats[3] / M, E11 = stats[4] / M, E22 = stats[5] / M;
    float E01 = stats[6] / M, E02 = stats[7] / M, E12 = stats[8] / M;
    float w0 = pw1[c * 3], w1 = pw1[c * 3 + 1], w2 = pw1[c * 3 + 2];
    float wmu = w0 * mu0 + w1 * mu1 + w2 * mu2;
    float mean_h = wmu + pb1[c];
    float Eh2 = w0 * w0 * E00 + w1 * w1 * E11 + w2 * w2 * E22
              + 2.f * (w0 * w1 * E01 + w0 * w2 * E02 + w1 * w2 * E12)
              + 2.f * pb1[c] * wmu + pb1[c] * pb1[c];
    float var = Eh2 - mean_h * mean_h;
    float a1 = pg1[c] * rsqrtf(var + EPSF);
    posA[c] = a1;
    posA[PHH + c] = pbe1[c] - mean_h * a1;
}

// ---------------- K7: pos_emb + s = q - k_g + pe, stored bf16 (M x 256) ----------------
__global__ __launch_bounds__(256) void posemb_s_kernel(const float* __restrict__ pos,
                                                       const int* __restrict__ idx,
                                                       const float* __restrict__ pw1,
                                                       const float* __restrict__ pb1,
                                                       const float* __restrict__ posA,
                                                       const float* __restrict__ pw2,
                                                       const float* __restrict__ pb2,
                                                       const float* __restrict__ qT,
                                                       const float* __restrict__ kT,
                                                       ushort_t* __restrict__ sb16) {
    int bid = blockIdx.x;
    int b = bid / NN, n = bid % NN;
    int t = threadIdx.x;
    __shared__ int sm[KK];
    __shared__ float pr[KK][4];
    __shared__ float p1r[KK][PHH];
    if (t < KK) {
        int m = idx[(size_t)bid * KK + t];
        sm[t] = m;
        const float* px = pos + (size_t)b * 3 * NN;
        pr[t][0] = px[n] - px[m];
        pr[t][1] = px[NN + n] - px[NN + m];
        pr[t][2] = px[2 * NN + n] - px[2 * NN + m];
    }
    __syncthreads();
    for (int l = t; l < KK * PHH; l += 256) {
        int s_ = l >> 6, j = l & 63;
        float h = pw1[j * 3] * pr[s_][0] + pw1[j * 3 + 1] * pr[s_][1] + pw1[j * 3 + 2] * pr[s_][2] + pb1[j];
        p1r[s_][j] = fmaxf(h * posA[j] + posA[PHH + j], 0.f);
    }
    __syncthreads();
    int c = t;
    const float4* w2r4 = (const float4*)(pw2 + (size_t)c * PHH);
    float q = qT[((size_t)b * NN + n) * DIMD + c];
    float bb2 = pb2[c];
    ushort_t* srow = sb16 + (size_t)bid * KK * DIMD;
    for (int s_ = 0; s_ < KK; ++s_) {
        const float4* pr4 = (const float4*)p1r[s_];
        float pe = bb2;
#pragma unroll
        for (int j4 = 0; j4 < PHH / 4; ++j4) {
            float4 w4 = w2r4[j4]; float4 h4 = pr4[j4];
            pe += w4.x * h4.x + w4.y * h4.y + w4.z * h4.z + w4.w * h4.w;
        }
        float kv = kT[((size_t)b * NN + sm[s_]) * DIMD + c];
        srow[s_ * DIMD + c] = f2b(q - kv + pe);
    }
}

// ---------------- K8: mu = column sums of s ----------------
__global__ __launch_bounds__(256) void mu_kernel(const ushort_t* __restrict__ sb16,
                                                 float* __restrict__ mu) {
    int c = threadIdx.x;
    const ushort_t* p = sb16 + (size_t)blockIdx.x * 512 * DIMD + c;
    float acc = 0.f;
    for (int i = 0; i < 512; ++i) acc += b2f(p[(size_t)i * DIMD]);
    atomicAdd(&mu[c], acc);
}

// ---------------- K9: R = sum s s^T (256x256) ----------------
__global__ __launch_bounds__(256) void R_kernel(const ushort_t* __restrict__ sb16,
                                                float* __restrict__ R) {
    int tile = blockIdx.x & 15;
    int chunk = blockIdx.x >> 4;
    int ti = tile >> 2, tj = tile & 3;
    int t = threadIdx.x;
    int ty = t >> 4, tx = t & 15;
    __shared__ float si[RNS][64];
    __shared__ float sj[RNS][64];
    float acc[4][4];
#pragma unroll
    for (int a = 0; a < 4; ++a)
#pragma unroll
        for (int b2 = 0; b2 < 4; ++b2) acc[a][b2] = 0.f;
    int base = chunk * 4096;
    for (int stage = 0; stage < 4096 / RNS; ++stage) {
        int sbase = base + stage * RNS;
#pragma unroll
        for (int rl = 0; rl < 8; ++rl) {
            int l = rl * 256 + t;
            int samp = l >> 7;
            int half = (l >> 6) & 1;
            int f = l & 63;
            float val = b2f(sb16[(size_t)(sbase + samp) * DIMD + (half ? tj * 64 : ti * 64) + f]);
            if (half) sj[samp][f] = val; else si[samp][f] = val;
        }
        __syncthreads();
#pragma unroll
        for (int samp = 0; samp < RNS; ++samp) {
            float4 av = *(const float4*)&si[samp][ty * 4];
            float4 bv = *(const float4*)&sj[samp][tx * 4];
            float aa[4] = {av.x, av.y, av.z, av.w};
            float bb[4] = {bv.x, bv.y, bv.z, bv.w};
#pragma unroll
            for (int a = 0; a < 4; ++a)
#pragma unroll
                for (int b2 = 0; b2 < 4; ++b2) acc[a][b2] += aa[a] * bb[b2];
        }
        __syncthreads();
    }
#pragma unroll
    for (int a = 0; a < 4; ++a)
#pragma unroll
        for (int b2 = 0; b2 < 4; ++b2)
            atomicAdd(&R[(size_t)(ti * 64 + ty * 4 + a) * DIMD + tj * 64 + tx * 4 + b2], acc[a][b2]);
}

// ---------------- K10: attn BN -> fused scale/offset per hidden channel ----------------
__global__ __launch_bounds__(256) void attn_bn_kernel(const float* __restrict__ R,
                                                      const float* __restrict__ mu,
                                                      const float* __restrict__ aw1,
                                                      const float* __restrict__ ab1,
                                                      const float* __restrict__ ag1,
                                                      const float* __restrict__ abe1,
                                                      float* __restrict__ attA) {
    int c = blockIdx.x;
    int t = threadIdx.x;
    __shared__ float wsh[DIMD];
    __shared__ float red[DIMD];
    wsh[t] = aw1[(size_t)c * DIMD + t];
    __syncthreads();
    const float* Rr = R + (size_t)t * DIMD;
    float q = 0.f;
#pragma unroll 4
    for (int j = 0; j < DIMD; ++j) q += Rr[j] * wsh[j];
    red[t] = q * wsh[t];
    __syncthreads();
    for (int off = 128; off >= 1; off >>= 1) {
        if (t < off) red[t] += red[t + off];
        __syncthreads();
    }
    float wRw = red[0];
    __syncthreads();
    red[t] = wsh[t] * mu[t];
    __syncthreads();
    for (int off = 128; off >= 1; off >>= 1) {
        if (t < off) red[t] += red[t + off];
        __syncthreads();
    }
    if (t == 0) {
        float M = (float)(BB * NN * KK);
        float wmu = red[0] / M;
        float b1c = ab1[c];
        float Eh = wmu + b1c;
        float Eh2 = wRw / M + 2.f * b1c * wmu + b1c * b1c;
        float var = Eh2 - Eh * Eh;
        float a1 = ag1[c] * rsqrtf(var + EPSF);
        attA[c] = a1;
        attA[AHH + c] = a1 * b1c + abe1[c] - Eh * a1;
    }
}

// ---------------- K10b: convert W1 (1024x256) and W2 (256x1024) to bf16 ----------------
__global__ void cvt_w_kernel(const float* __restrict__ aw1, const float* __restrict__ aw2,
                             ushort_t* __restrict__ w1b, ushort_t* __restrict__ w2b) {
    int i = blockIdx.x * 256 + threadIdx.x;
    if (i < AHH * DIMD) w1b[i] = f2b(aw1[i]);
    else {
        int j = i - AHH * DIMD;
        w2b[j] = f2b(aw2[j]);
    }
}

// ---------------- MFMA GEMM: C(M x N) = A(M x K) * B(N x K)^T, bf16 in fp32 acc ----
template <int KDIM, int EPI>
__global__ __launch_bounds__(256) void gemm_kernel(const ushort_t* __restrict__ A,
                                                   const ushort_t* __restrict__ Bm,
                                                   const float* __restrict__ p0,
                                                   const float* __restrict__ p1,
                                                   void* __restrict__ Out) {
    __shared__ ushort_t lA[128 * 32];
    __shared__ ushort_t lB[128 * 32];
    int t = threadIdx.x;
    int lane = t & 63, w = t >> 6;
    int wr = w >> 1, wc = w & 1;
    size_t row0 = (size_t)blockIdx.x * 128;
    int col0 = blockIdx.y * 128;
    int m16 = lane & 15, kg = lane >> 4;

    f32x4 acc[4][4];
#pragma unroll
    for (int i = 0; i < 4; ++i)
#pragma unroll
        for (int j = 0; j < 4; ++j) acc[i][j] = (f32x4){0.f, 0.f, 0.f, 0.f};

    const ushort_t* gA = A + (row0 + (size_t)w * 16 + m16) * KDIM + kg * 8;
    const ushort_t* gB = Bm + ((size_t)(col0 + w * 16 + m16)) * KDIM + kg * 8;
    ushort_t* lA0 = lA + w * 512;
    ushort_t* lB0 = lB + w * 512;

    for (int kt = 0; kt < KDIM / 32; ++kt) {
        int ko = kt * 32;
        GLDS16(gA + ko, lA0);
        GLDS16(gA + (size_t)64 * KDIM + ko, lA0 + 2048);
        GLDS16(gB + ko, lB0);
        GLDS16(gB + (size_t)64 * KDIM + ko, lB0 + 2048);
        __syncthreads();
        short8 af[4], bf[4];
#pragma unroll
        for (int i = 0; i < 4; ++i) {
            af[i] = *(const short8*)(lA + ((wr * 4 + i) * 512 + kg * 128 + m16 * 8));
            bf[i] = *(const short8*)(lB + ((wc * 4 + i) * 512 + kg * 128 + m16 * 8));
        }
#pragma unroll
        for (int i = 0; i < 4; ++i)
#pragma unroll
            for (int j = 0; j < 4; ++j)
                acc[i][j] = __builtin_amdgcn_mfma_f32_16x16x32_bf16(af[i], bf[j], acc[i][j], 0, 0, 0);
        __syncthreads();
    }

    if (EPI == 0) {
        ushort_t* Hb = (ushort_t*)Out;
#pragma unroll
        for (int j = 0; j < 4; ++j) {
            int n = col0 + wc * 64 + j * 16 + m16;
            float sc = p0[n], of = p1[n];
#pragma unroll
            for (int i = 0; i < 4; ++i) {
                size_t r = row0 + wr * 64 + i * 16 + kg * 4;
#pragma unroll
                for (int rg = 0; rg < 4; ++rg) {
                    float v = fmaxf(sc * acc[i][j][rg] + of, 0.f);
                    Hb[(r + rg) * (size_t)AHH + n] = f2b(v);
                }
            }
        }
    } else {
        float* Lb = (float*)Out;
#pragma unroll
        for (int j = 0; j < 4; ++j) {
            int n = col0 + wc * 64 + j * 16 + m16;
            float bi = p0[n];
#pragma unroll
            for (int i = 0; i < 4; ++i) {
                size_t r = row0 + wr * 64 + i * 16 + kg * 4;
#pragma unroll
                for (int rg = 0; rg < 4; ++rg)
                    Lb[(r + rg) * (size_t)DIMD + n] = acc[i][j][rg] + bi;
            }
        }
    }
}

// ---------------- K11: softmax over K + aggregation (per chunk) ----------------
__global__ __launch_bounds__(256) void softmax_agg_kernel(const int* __restrict__ idx,
                                                          const float* __restrict__ lbuf,
                                                          const ushort_t* __restrict__ sb16,
                                                          const float* __restrict__ qT,
                                                          const float* __restrict__ kT,
                                                          const float* __restrict__ vT,
                                                          float* __restrict__ aggT,
                                                          int pbase) {
    int p = pbase + blockIdx.x;      // global point id
    int b = p / NN, n = p % NN;
    int c = threadIdx.x;
    __shared__ int sm[KK];
    if (c < KK) sm[c] = idx[(size_t)p * KK + c];
    __syncthreads();
    const float* lrow = lbuf + (size_t)blockIdx.x * KK * DIMD + c;  // chunk-local
    float lg[KK];
#pragma unroll
    for (int s = 0; s < KK; ++s) lg[s] = lrow[(size_t)s * DIMD];
    float mx = lg[0];
#pragma unroll
    for (int s = 1; s < KK; ++s) mx = fmaxf(mx, lg[s]);
    float sum = 0.f;
#pragma unroll
    for (int s = 0; s < KK; ++s) { lg[s] = expf(lg[s] - mx); sum += lg[s]; }
    float inv = 1.f / sum;
    float q = qT[((size_t)b * NN + n) * DIMD + c];
    float vf = vT[((size_t)b * NN + n) * DIMD + c];
    const ushort_t* srow = sb16 + (size_t)p * KK * DIMD + c;
    float agg = 0.f;
#pragma unroll
    for (int s = 0; s < KK; ++s) {
        float kv = kT[((size_t)b * NN + sm[s]) * DIMD + c];
        float vv = vf + b2f(srow[(size_t)s * DIMD]) - q + kv;
        agg += lg[s] * inv * vv;
    }
    aggT[((size_t)b * NN + n) * DIMD + c] = agg;
}

// ---------------- K12: y = we·agg + be + identity ----------------
__global__ __launch_bounds__(256) void final_kernel(const float* __restrict__ aggT,
                                                    const float* __restrict__ we,
                                                    const float* __restrict__ be,
                                                    const float* __restrict__ value,
                                                    float* __restrict__ out) {
    int n = blockIdx.x * 256 + threadIdx.x;
    int o = blockIdx.y, b = blockIdx.z;
    const float* wr = we + (size_t)o * DIMD;
    const float* ar = aggT + ((size_t)b * NN + n) * DIMD;
    float acc = be[o];
#pragma unroll 4
    for (int i = 0; i < DIMD; ++i) acc += wr[i] * ar[i];
    size_t oi = ((size_t)b * CC + o) * NN + n;
    out[oi] = acc + value[oi];
}

extern "C" void kernel_launch(void* const* d_in, const int* in_sizes, int n_in,
                              void* d_out, int out_size, void* d_ws, size_t ws_size,
                              hipStream_t stream) {
    (void)in_sizes; (void)n_in; (void)out_size; (void)ws_size;
    const float* pos     = (const float*)d_in[0];
    const float* key     = (const float*)d_in[1];
    const float* query   = (const float*)d_in[2];
    const float* mlpv_w1 = (const float*)d_in[3];
    const float* mlpv_b1 = (const float*)d_in[4];
    const float* mlpv_w2 = (const float*)d_in[5];
    const float* mlpv_b2 = (const float*)d_in[6];
    const float* mlpv_ws = (const float*)d_in[7];
    const float* mlpv_bs = (const float*)d_in[8];
    const float* wk  = (const float*)d_in[9];
    const float* bk  = (const float*)d_in[10];
    const float* wq  = (const float*)d_in[11];
    const float* bq  = (const float*)d_in[12];
    const float* wv  = (const float*)d_in[13];
    const float* bv  = (const float*)d_in[14];
    const float* pw1 = (const float*)d_in[15];
    const float* pb1 = (const float*)d_in[16];
    const float* pg1 = (const float*)d_in[17];
    const float* pbe1= (const float*)d_in[18];
    const float* pw2 = (const float*)d_in[19];
    const float* pb2 = (const float*)d_in[20];
    const float* aw1 = (const float*)d_in[21];
    const float* ab1 = (const float*)d_in[22];
    const float* ag1 = (const float*)d_in[23];
    const float* abe1= (const float*)d_in[24];
    const float* aw2 = (const float*)d_in[25];
    const float* ab2 = (const float*)d_in[26];
    const float* we  = (const float*)d_in[27];
    const float* be  = (const float*)d_in[28];
    float* out = (float*)d_out;

    char* wsb = (char*)d_ws;
    size_t off = 0;
    auto alloc = [&](size_t bytes) {
        void* p = wsb + off;
        off += (bytes + 255) & ~(size_t)255;
        return p;
    };
    const size_t M = (size_t)BB * NN * KK;  // 131072 rows
    int*   idx   = (int*)  alloc(M * 4);
    float* h1buf = (float*)alloc((size_t)BB * CC * NN * 4);
    float* value = (float*)alloc((size_t)BB * CC * NN * 4);
    float* kT    = (float*)alloc((size_t)BB * NN * DIMD * 4);
    float* qT    = (float*)alloc((size_t)BB * NN * DIMD * 4);
    float* vT    = (float*)alloc((size_t)BB * NN * DIMD * 4);
    float* aggT  = (float*)alloc((size_t)BB * NN * DIMD * 4);
    float* zero0 = (float*)alloc((size_t)(16 + 256 + 65536) * 4);
    float* stats = zero0;
    float* mu    = zero0 + 16;
    float* R     = zero0 + 16 + 256;
    float* posA  = (float*)alloc((size_t)2 * PHH * 4);
    float* attA  = (float*)alloc((size_t)2 * AHH * 4);
    ushort_t* w1b = (ushort_t*)alloc((size_t)AHH * DIMD * 2);
    ushort_t* w2b = (ushort_t*)alloc((size_t)DIMD * AHH * 2);
    ushort_t* sb16 = (ushort_t*)alloc(M * DIMD * 2);          //  67 MB
    ushort_t* Hbuf = (ushort_t*)alloc((size_t)MCH * AHH * 2); //  33.5 MB (chunk)
    float*    lbuf = (float*)   alloc((size_t)MCH * DIMD * 4);//  16.8 MB (chunk)
    // total ~ 159 MB (< R1's 169 MB which passed)

    int ZN = 16 + 256 + 65536;
    zero_kernel<<<(ZN + 255) / 256, 256, 0, stream>>>(zero0, ZN);
    knn_kernel<<<BB * NN, 256, 0, stream>>>(pos, idx);
    h1_kernel<<<dim3(NN / 256, CC, BB), 256, 0, stream>>>(key, query, mlpv_w1, mlpv_b1, h1buf);
    value_kernel<<<dim3(NN / 256, CC, BB), 256, 0, stream>>>(key, query, h1buf, mlpv_w2, mlpv_b2, mlpv_ws, mlpv_bs, value);
    convT_kernel<<<dim3(NN / PT, BB), 256, 0, stream>>>(wk, bk, key, kT);
    convT_kernel<<<dim3(NN / PT, BB), 256, 0, stream>>>(wq, bq, query, qT);
    convT_kernel<<<dim3(NN / PT, BB), 256, 0, stream>>>(wv, bv, value, vT);
    pos_stats_kernel<<<BB * NN * KK / 256, 256, 0, stream>>>(pos, idx, stats);
    pos_bn_kernel<<<1, 64, 0, stream>>>(stats, pw1, pb1, pg1, pbe1, posA);
    posemb_s_kernel<<<BB * NN, 256, 0, stream>>>(pos, idx, pw1, pb1, posA, pw2, pb2, qT, kT, sb16);
    mu_kernel<<<M / 512, 256, 0, stream>>>(sb16, mu);
    R_kernel<<<512, 256, 0, stream>>>(sb16, R);
    attn_bn_kernel<<<AHH, DIMD, 0, stream>>>(R, mu, aw1, ab1, ag1, abe1, attA);
    cvt_w_kernel<<<(2 * AHH * DIMD) / 256, 256, 0, stream>>>(aw1, aw2, w1b, w2b);

    // chunked: GEMM1 -> GEMM2 -> softmax/agg, 8 chunks of MCH rows (1024 points)
    const int NCHUNK = (int)(M / MCH);
    for (int ch = 0; ch < NCHUNK; ++ch) {
        const ushort_t* Sc = sb16 + (size_t)ch * MCH * DIMD;
        gemm_kernel<DIMD, 0><<<dim3(MCH / 128, AHH / 128), 256, 0, stream>>>(Sc, w1b, attA, attA + AHH, Hbuf);
        gemm_kernel<AHH, 1><<<dim3(MCH / 128, DIMD / 128), 256, 0, stream>>>(Hbuf, w2b, ab2, nullptr, lbuf);
        softmax_agg_kernel<<<MCH / KK, 256, 0, stream>>>(idx, lbuf, sb16, qT, kT, vT, aggT, ch * (MCH / KK));
    }
    final_kernel<<<dim3(NN / 256, CC, BB), 256, 0, stream>>>(aggT, we, be, value, out);
}

// Round 4
// 1528.064 us; speedup vs baseline: 3.6215x; 1.4388x over previous
//
#include <hip/hip_runtime.h>
#include <math.h>

#define BB 2
#define CC 128
#define NN 4096
#define KK 16
#define DIMD 256
#define PHH 64
#define AHH 1024
#define EPSF 1e-5f
#define PT 16
#define MCH 16384   // M-chunk rows (1024 points x K)
#define RSPLIT 128
#define RKCH ((BB * NN * KK) / RSPLIT)   // 1024 samples per R block
#define LSTR 258    // LDS row stride (halfwords): conflict-free transposed gathers

typedef unsigned short ushort_t;
typedef __attribute__((ext_vector_type(8))) short short8;
typedef __attribute__((ext_vector_type(8))) unsigned short u16x8;
typedef __attribute__((ext_vector_type(2))) unsigned short u16x2;
typedef __attribute__((ext_vector_type(4))) float f32x4;

__device__ __forceinline__ ushort_t f2b(float x) {
    union { float f; unsigned u; } v; v.f = x;
    unsigned r = v.u + 0x7fff + ((v.u >> 16) & 1);
    return (ushort_t)(r >> 16);
}
__device__ __forceinline__ float b2f(ushort_t x) {
    union { unsigned u; float f; } v; v.u = ((unsigned)x) << 16;
    return v.f;
}

#define GLDS16(gp, lp) __builtin_amdgcn_global_load_lds( \
    (const __attribute__((address_space(1))) void*)(gp), \
    (__attribute__((address_space(3))) void*)(lp), 16, 0, 0)

// ---------------- K0: zero scratch accumulators ----------------
__global__ void zero_kernel(float* p, int n) {
    int i = blockIdx.x * blockDim.x + threadIdx.x;
    if (i < n) p[i] = 0.f;
}

// ---------------- K1: exact kNN (16 nearest incl. self) ----------------
__global__ __launch_bounds__(256) void knn_kernel(const float* __restrict__ pos,
                                                  int* __restrict__ idx) {
    int bid = blockIdx.x;
    int b = bid / NN, n = bid % NN;
    int t = threadIdx.x;
    const float* px = pos + (size_t)b * 3 * NN;
    const float* py = px + NN;
    const float* pz = px + 2 * NN;
    float qx = px[n], qy = py[n], qz = pz[n];
    float qs = qx * qx + qy * qy + qz * qz;

    float bd[KK]; int bi[KK];
#pragma unroll
    for (int j = 0; j < KK; ++j) {
        int m = t + 256 * j;
        float mx = px[m], my = py[m], mz = pz[m];
        float ms = mx * mx + my * my + mz * mz;
        float dt = qx * mx + qy * my + qz * mz;
        bd[j] = qs + ms - 2.f * dt;
        bi[j] = m;
    }

    __shared__ float wvs[4]; __shared__ int wis[4], wos[4];
    __shared__ int winO;
    unsigned consumed = 0;

    for (int r = 0; r < KK; ++r) {
        float v = 3.4e38f; int ii = 0x7fffffff; int jb = 0;
#pragma unroll
        for (int jx = 0; jx < KK; ++jx) {
            bool alive = ((consumed >> jx) & 1u) == 0u;
            bool better = alive && (bd[jx] < v || (bd[jx] == v && bi[jx] < ii));
            if (better) { v = bd[jx]; ii = bi[jx]; jb = jx; }
        }
        int ow = t;
#pragma unroll
        for (int off = 32; off >= 1; off >>= 1) {
            float ov = __shfl_down(v, off);
            int   oi = __shfl_down(ii, off);
            int   oo = __shfl_down(ow, off);
            if (ov < v || (ov == v && oi < ii)) { v = ov; ii = oi; ow = oo; }
        }
        if ((t & 63) == 0) { int w = t >> 6; wvs[w] = v; wis[w] = ii; wos[w] = ow; }
        __syncthreads();
        if (t == 0) {
            float bv = wvs[0]; int bI = wis[0], bO = wos[0];
            for (int w = 1; w < 4; ++w)
                if (wvs[w] < bv || (wvs[w] == bv && wis[w] < bI)) { bv = wvs[w]; bI = wis[w]; bO = wos[w]; }
            winO = bO;
            idx[(size_t)bid * KK + r] = bI;
        }
        __syncthreads();
        if (t == winO) consumed |= (1u << jb);
        __syncthreads();
    }
}

// ---------------- K2: h1 = relu(W1·[key;query] + b1) ----------------
__global__ __launch_bounds__(256) void h1_kernel(const float* __restrict__ key,
                                                 const float* __restrict__ query,
                                                 const float* __restrict__ w1,
                                                 const float* __restrict__ b1,
                                                 float* __restrict__ h1) {
    int n = blockIdx.x * 256 + threadIdx.x;
    int o = blockIdx.y, b = blockIdx.z;
    const float* wr = w1 + (size_t)o * 256;
    const float* kb = key + (size_t)b * CC * NN;
    const float* qb = query + (size_t)b * CC * NN;
    float acc = b1[o];
#pragma unroll 4
    for (int i = 0; i < CC; ++i) acc += wr[i] * kb[(size_t)i * NN + n];
#pragma unroll 4
    for (int i = 0; i < CC; ++i) acc += wr[CC + i] * qb[(size_t)i * NN + n];
    h1[((size_t)b * CC + o) * NN + n] = fmaxf(acc, 0.f);
}

// ---------------- K3: value = W2·h1 + b2 + Ws·[key;query] + bs ----------------
__global__ __launch_bounds__(256) void value_kernel(const float* __restrict__ key,
                                                    const float* __restrict__ query,
                                                    const float* __restrict__ h1buf,
                                                    const float* __restrict__ w2,
                                                    const float* __restrict__ b2,
                                                    const float* __restrict__ wsk,
                                                    const float* __restrict__ bs,
                                                    float* __restrict__ value) {
    int n = blockIdx.x * 256 + threadIdx.x;
    int o = blockIdx.y, b = blockIdx.z;
    const float* w2r = w2 + (size_t)o * CC;
    const float* wsr = wsk + (size_t)o * 256;
    const float* kb = key + (size_t)b * CC * NN;
    const float* qb = query + (size_t)b * CC * NN;
    const float* hb = h1buf + (size_t)b * CC * NN;
    float acc = b2[o] + bs[o];
#pragma unroll 4
    for (int i = 0; i < CC; ++i) acc += w2r[i] * hb[(size_t)i * NN + n];
#pragma unroll 4
    for (int i = 0; i < CC; ++i) acc += wsr[i] * kb[(size_t)i * NN + n];
#pragma unroll 4
    for (int i = 0; i < CC; ++i) acc += wsr[CC + i] * qb[(size_t)i * NN + n];
    value[((size_t)b * CC + o) * NN + n] = acc;
}

// ---------------- K4: outT[b][n][o] = bias[o] + W(256x128)·X[b,:,n] ----------------
__global__ __launch_bounds__(256) void convT_kernel(const float* __restrict__ W,
                                                    const float* __restrict__ bias,
                                                    const float* __restrict__ X,
                                                    float* __restrict__ outT) {
    __shared__ float xs[PT][CC + 1];
    int b = blockIdx.y;
    int n0 = blockIdx.x * PT;
    int t = threadIdx.x;
    for (int l = t; l < PT * CC; l += 256) {
        int p = l & (PT - 1); int i = l >> 4;
        xs[p][i] = X[((size_t)b * CC + i) * NN + n0 + p];
    }
    __syncthreads();
    int o = t;
    const float* wr = W + (size_t)o * CC;
    float acc[PT];
    float bo = bias[o];
#pragma unroll
    for (int p = 0; p < PT; ++p) acc[p] = bo;
    for (int i = 0; i < CC; ++i) {
        float w = wr[i];
#pragma unroll
        for (int p = 0; p < PT; ++p) acc[p] += w * xs[p][i];
    }
#pragma unroll
    for (int p = 0; p < PT; ++p)
        outT[((size_t)b * NN + n0 + p) * DIMD + o] = acc[p];
}

// ---------------- K5: pos_rel first/second moments (9 sums) ----------------
__global__ __launch_bounds__(256) void pos_stats_kernel(const float* __restrict__ pos,
                                                        const int* __restrict__ idx,
                                                        float* __restrict__ stats) {
    int sid = blockIdx.x * 256 + threadIdx.x;
    int b = sid / (NN * KK);
    int r = sid % (NN * KK);
    int n = r / KK;
    int m = idx[sid];
    const float* px = pos + (size_t)b * 3 * NN;
    float dx = px[n] - px[m];
    float dy = px[NN + n] - px[NN + m];
    float dz = px[2 * NN + n] - px[2 * NN + m];
    float v[9] = {dx, dy, dz, dx * dx, dy * dy, dz * dz, dx * dy, dx * dz, dy * dz};
    __shared__ float red[256];
    for (int j = 0; j < 9; ++j) {
        red[threadIdx.x] = v[j];
        __syncthreads();
        for (int off = 128; off >= 1; off >>= 1) {
            if (threadIdx.x < off) red[threadIdx.x] += red[threadIdx.x + off];
            __syncthreads();
        }
        if (threadIdx.x == 0) atomicAdd(&stats[j], red[0]);
        __syncthreads();
    }
}

// ---------------- K6: pos BN affine (a1, a0) per 64 channels ----------------
__global__ void pos_bn_kernel(const float* __restrict__ stats, const float* __restrict__ pw1,
                              const float* __restrict__ pb1, const float* __restrict__ pg1,
                              const float* __restrict__ pbe1, float* __restrict__ posA) {
    int c = threadIdx.x;
    if (c >= PHH) return;
    float M = (float)(BB * NN * KK);
    float mu0 = stats[0] / M, mu1 = stats[1] / M, mu2 = stats[2] / M;
    float E00 = stats[3] / M, E11 = stats[4] / M, E22 = stats[5] / M;
    float E01 = stats[6] / M, E02 = stats[7] / M, E12 = stats[8] / M;
    float w0 = pw1[c * 3], w1 = pw1[c * 3 + 1], w2 = pw1[c * 3 + 2];
    float wmu = w0 * mu0 + w1 * mu1 + w2 * mu2;
    float mean_h = wmu + pb1[c];
    float Eh2 = w0 * w0 * E00 + w1 * w1 * E11 + w2 * w2 * E22
              + 2.f * (w0 * w1 * E01 + w0 * w2 * E02 + w1 * w2 * E12)
              + 2.f * pb1[c] * wmu + pb1[c] * pb1[c];
    float var = Eh2 - mean_h * mean_h;
    float a1 = pg1[c] * rsqrtf(var + EPSF);
    posA[c] = a1;
    posA[PHH + c] = pbe1[c] - mean_h * a1;
}

// ---------------- K7: pos_emb + s = q - k_g + pe, stored bf16 (M x 256) ----------------
__global__ __launch_bounds__(256) void posemb_s_kernel(const float* __restrict__ pos,
                                                       const int* __restrict__ idx,
                                                       const float* __restrict__ pw1,
                                                       const float* __restrict__ pb1,
                                                       const float* __restrict__ posA,
                                                       const float* __restrict__ pw2,
                                                       const float* __restrict__ pb2,
                                                       const float* __restrict__ qT,
                                                       const float* __restrict__ kT,
                                                       ushort_t* __restrict__ sb16) {
    int bid = blockIdx.x;
    int b = bid / NN, n = bid % NN;
    int t = threadIdx.x;
    __shared__ int sm[KK];
    __shared__ float pr[KK][4];
    __shared__ float p1r[KK][PHH];
    if (t < KK) {
        int m = idx[(size_t)bid * KK + t];
        sm[t] = m;
        const float* px = pos + (size_t)b * 3 * NN;
        pr[t][0] = px[n] - px[m];
        pr[t][1] = px[NN + n] - px[NN + m];
        pr[t][2] = px[2 * NN + n] - px[2 * NN + m];
    }
    __syncthreads();
    for (int l = t; l < KK * PHH; l += 256) {
        int s_ = l >> 6, j = l & 63;
        float h = pw1[j * 3] * pr[s_][0] + pw1[j * 3 + 1] * pr[s_][1] + pw1[j * 3 + 2] * pr[s_][2] + pb1[j];
        p1r[s_][j] = fmaxf(h * posA[j] + posA[PHH + j], 0.f);
    }
    __syncthreads();
    int c = t;
    const float4* w2r4 = (const float4*)(pw2 + (size_t)c * PHH);
    float q = qT[((size_t)b * NN + n) * DIMD + c];
    float bb2 = pb2[c];
    ushort_t* srow = sb16 + (size_t)bid * KK * DIMD;
    for (int s_ = 0; s_ < KK; ++s_) {
        const float4* pr4 = (const float4*)p1r[s_];
        float pe = bb2;
#pragma unroll
        for (int j4 = 0; j4 < PHH / 4; ++j4) {
            float4 w4 = w2r4[j4]; float4 h4 = pr4[j4];
            pe += w4.x * h4.x + w4.y * h4.y + w4.z * h4.z + w4.w * h4.w;
        }
        float kv = kT[((size_t)b * NN + sm[s_]) * DIMD + c];
        srow[s_ * DIMD + c] = f2b(q - kv + pe);
    }
}

// ---------------- K8: mu = column sums of s ----------------
__global__ __launch_bounds__(256) void mu_kernel(const ushort_t* __restrict__ sb16,
                                                 float* __restrict__ mu) {
    int c = threadIdx.x;
    const ushort_t* p = sb16 + (size_t)blockIdx.x * 512 * DIMD + c;
    float acc = 0.f;
    for (int i = 0; i < 512; ++i) acc += b2f(p[(size_t)i * DIMD]);
    atomicAdd(&mu[c], acc);
}

// ---------------- K9: R partials via MFMA: Rpart[chunk] = S_chunk^T * S_chunk ----------
// grid (RSPLIT, 4): blockIdx.y = ti*2+tj (128x128 output tile), split-K chunks of RKCH.
// LDS: 32 samples x 256 ch, row stride LSTR=258 halfwords -> transposed u16 gathers are
// bank-conflict-free (bank = (k + c/2) & 31 spreads kg over {0,8,16,24}).
__global__ __launch_bounds__(256) void rg_kernel(const ushort_t* __restrict__ S,
                                                 float* __restrict__ Rpart) {
    __shared__ ushort_t ls[32 * LSTR];
    int t = threadIdx.x;
    int lane = t & 63, w = t >> 6;
    int wr = w >> 1, wc = w & 1;
    int ti = blockIdx.y >> 1, tj = blockIdx.y & 1;
    int m16 = lane & 15, kg = lane >> 4;
    size_t kbase = (size_t)blockIdx.x * RKCH;

    f32x4 acc[4][4];
#pragma unroll
    for (int i = 0; i < 4; ++i)
#pragma unroll
        for (int j = 0; j < 4; ++j) acc[i][j] = (f32x4){0.f, 0.f, 0.f, 0.f};

    int lm = t >> 3;           // sample row 0..31
    int lc = (t & 7) * 32;     // channel start (32 ch per thread)
    const ushort_t* gS = S + (kbase + lm) * DIMD + lc;
    ushort_t* lp = ls + lm * LSTR + lc;

    for (int kt = 0; kt < RKCH / 32; ++kt) {
        const ushort_t* gp = gS + (size_t)kt * 32 * DIMD;
        u16x8 v0 = *(const u16x8*)(gp);
        u16x8 v1 = *(const u16x8*)(gp + 8);
        u16x8 v2 = *(const u16x8*)(gp + 16);
        u16x8 v3 = *(const u16x8*)(gp + 24);
        __syncthreads();
#pragma unroll
        for (int q = 0; q < 4; ++q) {
            *(u16x2*)(lp + 0 + 2 * q) = (u16x2){v0[2 * q], v0[2 * q + 1]};
            *(u16x2*)(lp + 8 + 2 * q) = (u16x2){v1[2 * q], v1[2 * q + 1]};
            *(u16x2*)(lp + 16 + 2 * q) = (u16x2){v2[2 * q], v2[2 * q + 1]};
            *(u16x2*)(lp + 24 + 2 * q) = (u16x2){v3[2 * q], v3[2 * q + 1]};
        }
        __syncthreads();
        short8 af[4], bf[4];
#pragma unroll
        for (int i = 0; i < 4; ++i) {
            int chA = ti * 128 + wr * 64 + i * 16 + m16;
            int chB = tj * 128 + wc * 64 + i * 16 + m16;
#pragma unroll
            for (int j = 0; j < 8; ++j) {
                int k = kg * 8 + j;
                af[i][j] = (short)ls[k * LSTR + chA];
                bf[i][j] = (short)ls[k * LSTR + chB];
            }
        }
#pragma unroll
        for (int i = 0; i < 4; ++i)
#pragma unroll
            for (int j = 0; j < 4; ++j)
                acc[i][j] = __builtin_amdgcn_mfma_f32_16x16x32_bf16(af[i], bf[j], acc[i][j], 0, 0, 0);
    }

    float* rp = Rpart + (size_t)blockIdx.x * (DIMD * DIMD);
#pragma unroll
    for (int i = 0; i < 4; ++i) {
        int r0 = ti * 128 + wr * 64 + i * 16 + kg * 4;
#pragma unroll
        for (int j = 0; j < 4; ++j) {
            int cn = tj * 128 + wc * 64 + j * 16 + m16;
#pragma unroll
            for (int rg = 0; rg < 4; ++rg)
                rp[(size_t)(r0 + rg) * DIMD + cn] = acc[i][j][rg];
        }
    }
}

// ---------------- K9b: reduce R partials ----------------
__global__ __launch_bounds__(256) void r_reduce_kernel(const float* __restrict__ Rpart,
                                                       float* __restrict__ R) {
    int e = blockIdx.x * 256 + threadIdx.x;
    float s = 0.f;
    for (int p = 0; p < RSPLIT; ++p) s += Rpart[(size_t)p * (DIMD * DIMD) + e];
    R[e] = s;
}

// ---------------- K10: attn BN -> fused scale/offset per hidden channel ----------------
__global__ __launch_bounds__(256) void attn_bn_kernel(const float* __restrict__ R,
                                                      const float* __restrict__ mu,
                                                      const float* __restrict__ aw1,
                                                      const float* __restrict__ ab1,
                                                      const float* __restrict__ ag1,
                                                      const float* __restrict__ abe1,
                                                      float* __restrict__ attA) {
    int c = blockIdx.x;
    int t = threadIdx.x;
    __shared__ float wsh[DIMD];
    __shared__ float red[DIMD];
    wsh[t] = aw1[(size_t)c * DIMD + t];
    __syncthreads();
    const float* Rr = R + (size_t)t * DIMD;
    float q = 0.f;
#pragma unroll 4
    for (int j = 0; j < DIMD; ++j) q += Rr[j] * wsh[j];
    red[t] = q * wsh[t];
    __syncthreads();
    for (int off = 128; off >= 1; off >>= 1) {
        if (t < off) red[t] += red[t + off];
        __syncthreads();
    }
    float wRw = red[0];
    __syncthreads();
    red[t] = wsh[t] * mu[t];
    __syncthreads();
    for (int off = 128; off >= 1; off >>= 1) {
        if (t < off) red[t] += red[t + off];
        __syncthreads();
    }
    if (t == 0) {
        float M = (float)(BB * NN * KK);
        float wmu = red[0] / M;
        float b1c = ab1[c];
        float Eh = wmu + b1c;
        float Eh2 = wRw / M + 2.f * b1c * wmu + b1c * b1c;
        float var = Eh2 - Eh * Eh;
        float a1 = ag1[c] * rsqrtf(var + EPSF);
        attA[c] = a1;
        attA[AHH + c] = a1 * b1c + abe1[c] - Eh * a1;
    }
}

// ---------------- K10b: convert W1 (1024x256) and W2 (256x1024) to bf16 ----------------
__global__ void cvt_w_kernel(const float* __restrict__ aw1, const float* __restrict__ aw2,
                             ushort_t* __restrict__ w1b, ushort_t* __restrict__ w2b) {
    int i = blockIdx.x * 256 + threadIdx.x;
    if (i < AHH * DIMD) w1b[i] = f2b(aw1[i]);
    else {
        int j = i - AHH * DIMD;
        w2b[j] = f2b(aw2[j]);
    }
}

// ---------------- MFMA GEMM: C(M x N) = A(M x K) * B(N x K)^T, bf16 in fp32 acc ----
template <int KDIM, int EPI>
__global__ __launch_bounds__(256) void gemm_kernel(const ushort_t* __restrict__ A,
                                                   const ushort_t* __restrict__ Bm,
                                                   const float* __restrict__ p0,
                                                   const float* __restrict__ p1,
                                                   void* __restrict__ Out) {
    __shared__ ushort_t lA[128 * 32];
    __shared__ ushort_t lB[128 * 32];
    int t = threadIdx.x;
    int lane = t & 63, w = t >> 6;
    int wr = w >> 1, wc = w & 1;
    size_t row0 = (size_t)blockIdx.x * 128;
    int col0 = blockIdx.y * 128;
    int m16 = lane & 15, kg = lane >> 4;

    f32x4 acc[4][4];
#pragma unroll
    for (int i = 0; i < 4; ++i)
#pragma unroll
        for (int j = 0; j < 4; ++j) acc[i][j] = (f32x4){0.f, 0.f, 0.f, 0.f};

    const ushort_t* gA = A + (row0 + (size_t)w * 16 + m16) * KDIM + kg * 8;
    const ushort_t* gB = Bm + ((size_t)(col0 + w * 16 + m16)) * KDIM + kg * 8;
    ushort_t* lA0 = lA + w * 512;
    ushort_t* lB0 = lB + w * 512;

    for (int kt = 0; kt < KDIM / 32; ++kt) {
        int ko = kt * 32;
        GLDS16(gA + ko, lA0);
        GLDS16(gA + (size_t)64 * KDIM + ko, lA0 + 2048);
        GLDS16(gB + ko, lB0);
        GLDS16(gB + (size_t)64 * KDIM + ko, lB0 + 2048);
        __syncthreads();
        short8 af[4], bf[4];
#pragma unroll
        for (int i = 0; i < 4; ++i) {
            af[i] = *(const short8*)(lA + ((wr * 4 + i) * 512 + kg * 128 + m16 * 8));
            bf[i] = *(const short8*)(lB + ((wc * 4 + i) * 512 + kg * 128 + m16 * 8));
        }
#pragma unroll
        for (int i = 0; i < 4; ++i)
#pragma unroll
            for (int j = 0; j < 4; ++j)
                acc[i][j] = __builtin_amdgcn_mfma_f32_16x16x32_bf16(af[i], bf[j], acc[i][j], 0, 0, 0);
        __syncthreads();
    }

    if (EPI == 0) {
        ushort_t* Hb = (ushort_t*)Out;
#pragma unroll
        for (int j = 0; j < 4; ++j) {
            int n = col0 + wc * 64 + j * 16 + m16;
            float sc = p0[n], of = p1[n];
#pragma unroll
            for (int i = 0; i < 4; ++i) {
                size_t r = row0 + wr * 64 + i * 16 + kg * 4;
#pragma unroll
                for (int rg = 0; rg < 4; ++rg) {
                    float v = fmaxf(sc * acc[i][j][rg] + of, 0.f);
                    Hb[(r + rg) * (size_t)AHH + n] = f2b(v);
                }
            }
        }
    } else {
        float* Lb = (float*)Out;
#pragma unroll
        for (int j = 0; j < 4; ++j) {
            int n = col0 + wc * 64 + j * 16 + m16;
            float bi = p0[n];
#pragma unroll
            for (int i = 0; i < 4; ++i) {
                size_t r = row0 + wr * 64 + i * 16 + kg * 4;
#pragma unroll
                for (int rg = 0; rg < 4; ++rg)
                    Lb[(r + rg) * (size_t)DIMD + n] = acc[i][j][rg] + bi;
            }
        }
    }
}

// ---------------- K11: softmax over K + aggregation (per chunk) ----------------
__global__ __launch_bounds__(256) void softmax_agg_kernel(const int* __restrict__ idx,
                                                          const float* __restrict__ lbuf,
                                                          const ushort_t* __restrict__ sb16,
                                                          const float* __restrict__ qT,
                                                          const float* __restrict__ kT,
                                                          const float* __restrict__ vT,
                                                          float* __restrict__ aggT,
                                                          int pbase) {
    int p = pbase + blockIdx.x;      // global point id
    int b = p / NN, n = p % NN;
    int c = threadIdx.x;
    __shared__ int sm[KK];
    if (c < KK) sm[c] = idx[(size_t)p * KK + c];
    __syncthreads();
    const float* lrow = lbuf + (size_t)blockIdx.x * KK * DIMD + c;  // chunk-local
    float lg[KK];
#pragma unroll
    for (int s = 0; s < KK; ++s) lg[s] = lrow[(size_t)s * DIMD];
    float mx = lg[0];
#pragma unroll
    for (int s = 1; s < KK; ++s) mx = fmaxf(mx, lg[s]);
    float sum = 0.f;
#pragma unroll
    for (int s = 0; s < KK; ++s) { lg[s] = expf(lg[s] - mx); sum += lg[s]; }
    float inv = 1.f / sum;
    float q = qT[((size_t)b * NN + n) * DIMD + c];
    float vf = vT[((size_t)b * NN + n) * DIMD + c];
    const ushort_t* srow = sb16 + (size_t)p * KK * DIMD + c;
    float agg = 0.f;
#pragma unroll
    for (int s = 0; s < KK; ++s) {
        float kv = kT[((size_t)b * NN + sm[s]) * DIMD + c];
        float vv = vf + b2f(srow[(size_t)s * DIMD]) - q + kv;
        agg += lg[s] * inv * vv;
    }
    aggT[((size_t)b * NN + n) * DIMD + c] = agg;
}

// ---------------- K12: y = we·agg + be + identity ----------------
__global__ __launch_bounds__(256) void final_kernel(const float* __restrict__ aggT,
                                                    const float* __restrict__ we,
                                                    const float* __restrict__ be,
                                                    const float* __restrict__ value,
                                                    float* __restrict__ out) {
    int n = blockIdx.x * 256 + threadIdx.x;
    int o = blockIdx.y, b = blockIdx.z;
    const float* wr = we + (size_t)o * DIMD;
    const float* ar = aggT + ((size_t)b * NN + n) * DIMD;
    float acc = be[o];
#pragma unroll 4
    for (int i = 0; i < DIMD; ++i) acc += wr[i] * ar[i];
    size_t oi = ((size_t)b * CC + o) * NN + n;
    out[oi] = acc + value[oi];
}

extern "C" void kernel_launch(void* const* d_in, const int* in_sizes, int n_in,
                              void* d_out, int out_size, void* d_ws, size_t ws_size,
                              hipStream_t stream) {
    (void)in_sizes; (void)n_in; (void)out_size; (void)ws_size;
    const float* pos     = (const float*)d_in[0];
    const float* key     = (const float*)d_in[1];
    const float* query   = (const float*)d_in[2];
    const float* mlpv_w1 = (const float*)d_in[3];
    const float* mlpv_b1 = (const float*)d_in[4];
    const float* mlpv_w2 = (const float*)d_in[5];
    const float* mlpv_b2 = (const float*)d_in[6];
    const float* mlpv_ws = (const float*)d_in[7];
    const float* mlpv_bs = (const float*)d_in[8];
    const float* wk  = (const float*)d_in[9];
    const float* bk  = (const float*)d_in[10];
    const float* wq  = (const float*)d_in[11];
    const float* bq  = (const float*)d_in[12];
    const float* wv  = (const float*)d_in[13];
    const float* bv  = (const float*)d_in[14];
    const float* pw1 = (const float*)d_in[15];
    const float* pb1 = (const float*)d_in[16];
    const float* pg1 = (const float*)d_in[17];
    const float* pbe1= (const float*)d_in[18];
    const float* pw2 = (const float*)d_in[19];
    const float* pb2 = (const float*)d_in[20];
    const float* aw1 = (const float*)d_in[21];
    const float* ab1 = (const float*)d_in[22];
    const float* ag1 = (const float*)d_in[23];
    const float* abe1= (const float*)d_in[24];
    const float* aw2 = (const float*)d_in[25];
    const float* ab2 = (const float*)d_in[26];
    const float* we  = (const float*)d_in[27];
    const float* be  = (const float*)d_in[28];
    float* out = (float*)d_out;

    char* wsb = (char*)d_ws;
    size_t off = 0;
    auto alloc = [&](size_t bytes) {
        void* p = wsb + off;
        off += (bytes + 255) & ~(size_t)255;
        return p;
    };
    const size_t M = (size_t)BB * NN * KK;  // 131072 rows
    int*   idx   = (int*)  alloc(M * 4);
    float* h1buf = (float*)alloc((size_t)BB * CC * NN * 4);
    float* value = (float*)alloc((size_t)BB * CC * NN * 4);
    float* kT    = (float*)alloc((size_t)BB * NN * DIMD * 4);
    float* qT    = (float*)alloc((size_t)BB * NN * DIMD * 4);
    float* vT    = (float*)alloc((size_t)BB * NN * DIMD * 4);
    float* aggT  = (float*)alloc((size_t)BB * NN * DIMD * 4);
    float* zero0 = (float*)alloc((size_t)(16 + 256 + 65536) * 4);
    float* stats = zero0;
    float* mu    = zero0 + 16;
    float* R     = zero0 + 16 + 256;
    float* posA  = (float*)alloc((size_t)2 * PHH * 4);
    float* attA  = (float*)alloc((size_t)2 * AHH * 4);
    ushort_t* w1b = (ushort_t*)alloc((size_t)AHH * DIMD * 2);
    ushort_t* w2b = (ushort_t*)alloc((size_t)DIMD * AHH * 2);
    ushort_t* sb16 = (ushort_t*)alloc(M * DIMD * 2);          //  67 MB
    // overlay: Rpart (33.5 MB, used before chunk loop) | Hbuf+lbuf (50.3 MB, chunk loop)
    char* ovl = (char*)alloc((size_t)MCH * AHH * 2 + (size_t)MCH * DIMD * 4);
    float*    Rpart = (float*)ovl;
    ushort_t* Hbuf  = (ushort_t*)ovl;
    float*    lbuf  = (float*)(ovl + (size_t)MCH * AHH * 2);
    // total ~169 MB (== R1's passing footprint)

    int ZN = 16 + 256 + 65536;
    zero_kernel<<<(ZN + 255) / 256, 256, 0, stream>>>(zero0, ZN);
    knn_kernel<<<BB * NN, 256, 0, stream>>>(pos, idx);
    h1_kernel<<<dim3(NN / 256, CC, BB), 256, 0, stream>>>(key, query, mlpv_w1, mlpv_b1, h1buf);
    value_kernel<<<dim3(NN / 256, CC, BB), 256, 0, stream>>>(key, query, h1buf, mlpv_w2, mlpv_b2, mlpv_ws, mlpv_bs, value);
    convT_kernel<<<dim3(NN / PT, BB), 256, 0, stream>>>(wk, bk, key, kT);
    convT_kernel<<<dim3(NN / PT, BB), 256, 0, stream>>>(wq, bq, query, qT);
    convT_kernel<<<dim3(NN / PT, BB), 256, 0, stream>>>(wv, bv, value, vT);
    pos_stats_kernel<<<BB * NN * KK / 256, 256, 0, stream>>>(pos, idx, stats);
    pos_bn_kernel<<<1, 64, 0, stream>>>(stats, pw1, pb1, pg1, pbe1, posA);
    posemb_s_kernel<<<BB * NN, 256, 0, stream>>>(pos, idx, pw1, pb1, posA, pw2, pb2, qT, kT, sb16);
    mu_kernel<<<M / 512, 256, 0, stream>>>(sb16, mu);
    rg_kernel<<<dim3(RSPLIT, 4), 256, 0, stream>>>(sb16, Rpart);
    r_reduce_kernel<<<DIMD * DIMD / 256, 256, 0, stream>>>(Rpart, R);
    attn_bn_kernel<<<AHH, DIMD, 0, stream>>>(R, mu, aw1, ab1, ag1, abe1, attA);
    cvt_w_kernel<<<(2 * AHH * DIMD) / 256, 256, 0, stream>>>(aw1, aw2, w1b, w2b);

    // chunked: GEMM1 -> GEMM2 -> softmax/agg, 8 chunks of MCH rows (1024 points)
    const int NCHUNK = (int)(M / MCH);
    for (int ch = 0; ch < NCHUNK; ++ch) {
        const ushort_t* Sc = sb16 + (size_t)ch * MCH * DIMD;
        gemm_kernel<DIMD, 0><<<dim3(MCH / 128, AHH / 128), 256, 0, stream>>>(Sc, w1b, attA, attA + AHH, Hbuf);
        gemm_kernel<AHH, 1><<<dim3(MCH / 128, DIMD / 128), 256, 0, stream>>>(Hbuf, w2b, ab2, nullptr, lbuf);
        softmax_agg_kernel<<<MCH / KK, 256, 0, stream>>>(idx, lbuf, sb16, qT, kT, vT, aggT, ch * (MCH / KK));
    }
    final_kernel<<<dim3(NN / 256, CC, BB), 256, 0, stream>>>(aggT, we, be, value, out);
}

// Round 5
// 1342.522 us; speedup vs baseline: 4.1221x; 1.1382x over previous
//
#include <hip/hip_runtime.h>
#include <math.h>

#define BB 2
#define CC 128
#define NN 4096
#define KK 16
#define DIMD 256
#define PHH 64
#define AHH 1024
#define EPSF 1e-5f
#define PT 16
#define MCH 16384   // M-chunk rows (1024 points x K)
#define RSPLIT 128
#define RKCH ((BB * NN * KK) / RSPLIT)   // 1024 samples per R block
#define LSTR 258    // LDS row stride (halfwords): conflict-free transposed gathers
#define KNN_CAP 512

typedef unsigned short ushort_t;
typedef unsigned long long u64;
typedef __attribute__((ext_vector_type(8))) short short8;
typedef __attribute__((ext_vector_type(8))) unsigned short u16x8;
typedef __attribute__((ext_vector_type(2))) unsigned short u16x2;
typedef __attribute__((ext_vector_type(4))) float f32x4;

__device__ __forceinline__ ushort_t f2b(float x) {
    union { float f; unsigned u; } v; v.f = x;
    unsigned r = v.u + 0x7fff + ((v.u >> 16) & 1);
    return (ushort_t)(r >> 16);
}
__device__ __forceinline__ float b2f(ushort_t x) {
    union { unsigned u; float f; } v; v.u = ((unsigned)x) << 16;
    return v.f;
}
__device__ __forceinline__ unsigned fsort(float x) {
    union { float f; unsigned u; } v; v.f = x;
    return v.u ^ ((v.u >> 31) ? 0xFFFFFFFFu : 0x80000000u);
}

#define GLDS16(gp, lp) __builtin_amdgcn_global_load_lds( \
    (const __attribute__((address_space(1))) void*)(gp), \
    (__attribute__((address_space(3))) void*)(lp), 16, 0, 0)

// ---------------- K0: zero scratch accumulators ----------------
__global__ void zero_kernel(float* p, int n) {
    int i = blockIdx.x * blockDim.x + threadIdx.x;
    if (i < n) p[i] = 0.f;
}

// ---------------- K1: exact kNN via u64-key threshold select ----------------
// key = (sortable(d2) << 32) | idx  -> distinct keys, lexicographic (d2, idx) order.
// Phase 1: per-thread min of 16; per-wave extract 4 smallest lane-minima;
//          T0 = max over waves of wave-4th-min  => >=16 elements have key <= T0.
// Phase 2: collect all keys <= T0 to LDS pool (E[count] ~ 16 for random data).
// Phase 3: rank each pooled key (count of smaller keys); rank r<16 -> output slot r.
__global__ __launch_bounds__(256) void knn_kernel(const float* __restrict__ pos,
                                                  int* __restrict__ idx) {
    int bid = blockIdx.x;
    int b = bid / NN, n = bid % NN;
    int t = threadIdx.x;
    int lane = t & 63, w = t >> 6;
    const float* px = pos + (size_t)b * 3 * NN;
    const float* py = px + NN;
    const float* pz = px + 2 * NN;
    float qx = px[n], qy = py[n], qz = pz[n];
    float qs = qx * qx + qy * qy + qz * qz;

    u64 keys[KK];
    u64 lmin = ~0ull;
#pragma unroll
    for (int j = 0; j < KK; ++j) {
        int m = t + 256 * j;
        float mx = px[m], my = py[m], mz = pz[m];
        float ms = mx * mx + my * my + mz * mz;
        float dt = qx * mx + qy * my + qz * mz;
        float d = qs + ms - 2.f * dt;
        u64 k = ((u64)fsort(d) << 32) | (unsigned)m;
        keys[j] = k;
        lmin = k < lmin ? k : lmin;
    }

    __shared__ u64 T0s[4];
    __shared__ u64 pool[KNN_CAP];
    __shared__ int cnt;

    // wave: extract 4 smallest lane-minima
    u64 k = lmin, m4 = 0;
#pragma unroll
    for (int r = 0; r < 4; ++r) {
        u64 mv = k;
#pragma unroll
        for (int off = 32; off >= 1; off >>= 1) {
            u64 o = __shfl_xor(mv, off);
            mv = o < mv ? o : mv;
        }
        if (r == 3) m4 = mv;
        if (k == mv) k = ~0ull;
    }
    if (lane == 0) T0s[w] = m4;
    if (t == 0) cnt = 0;
    __syncthreads();
    u64 T0 = T0s[0];
    T0 = T0s[1] > T0 ? T0s[1] : T0;
    T0 = T0s[2] > T0 ? T0s[2] : T0;
    T0 = T0s[3] > T0 ? T0s[3] : T0;

#pragma unroll
    for (int j = 0; j < KK; ++j) {
        if (keys[j] <= T0) {
            int p = atomicAdd(&cnt, 1);
            if (p < KNN_CAP) pool[p] = keys[j];
        }
    }
    __syncthreads();
    int C = cnt < KNN_CAP ? cnt : KNN_CAP;
    if (t < C) {
        u64 me = pool[t];
        int r = 0;
        for (int i = 0; i < C; ++i) r += (pool[i] < me);
        if (r < KK) idx[(size_t)bid * KK + r] = (int)(me & 0xFFFFFFFFu);
    }
}

// ---------------- K2: h1 = relu(W1·[key;query] + b1) ----------------
__global__ __launch_bounds__(256) void h1_kernel(const float* __restrict__ key,
                                                 const float* __restrict__ query,
                                                 const float* __restrict__ w1,
                                                 const float* __restrict__ b1,
                                                 float* __restrict__ h1) {
    int n = blockIdx.x * 256 + threadIdx.x;
    int o = blockIdx.y, b = blockIdx.z;
    const float* wr = w1 + (size_t)o * 256;
    const float* kb = key + (size_t)b * CC * NN;
    const float* qb = query + (size_t)b * CC * NN;
    float acc = b1[o];
#pragma unroll 4
    for (int i = 0; i < CC; ++i) acc += wr[i] * kb[(size_t)i * NN + n];
#pragma unroll 4
    for (int i = 0; i < CC; ++i) acc += wr[CC + i] * qb[(size_t)i * NN + n];
    h1[((size_t)b * CC + o) * NN + n] = fmaxf(acc, 0.f);
}

// ---------------- K3: value = W2·h1 + b2 + Ws·[key;query] + bs ----------------
__global__ __launch_bounds__(256) void value_kernel(const float* __restrict__ key,
                                                    const float* __restrict__ query,
                                                    const float* __restrict__ h1buf,
                                                    const float* __restrict__ w2,
                                                    const float* __restrict__ b2,
                                                    const float* __restrict__ wsk,
                                                    const float* __restrict__ bs,
                                                    float* __restrict__ value) {
    int n = blockIdx.x * 256 + threadIdx.x;
    int o = blockIdx.y, b = blockIdx.z;
    const float* w2r = w2 + (size_t)o * CC;
    const float* wsr = wsk + (size_t)o * 256;
    const float* kb = key + (size_t)b * CC * NN;
    const float* qb = query + (size_t)b * CC * NN;
    const float* hb = h1buf + (size_t)b * CC * NN;
    float acc = b2[o] + bs[o];
#pragma unroll 4
    for (int i = 0; i < CC; ++i) acc += w2r[i] * hb[(size_t)i * NN + n];
#pragma unroll 4
    for (int i = 0; i < CC; ++i) acc += wsr[i] * kb[(size_t)i * NN + n];
#pragma unroll 4
    for (int i = 0; i < CC; ++i) acc += wsr[CC + i] * qb[(size_t)i * NN + n];
    value[((size_t)b * CC + o) * NN + n] = acc;
}

// ---------------- K4: outT[b][n][o] = bias[o] + W(256x128)·X[b,:,n] ----------------
__global__ __launch_bounds__(256) void convT_kernel(const float* __restrict__ W,
                                                    const float* __restrict__ bias,
                                                    const float* __restrict__ X,
                                                    float* __restrict__ outT) {
    __shared__ float xs[PT][CC + 1];
    int b = blockIdx.y;
    int n0 = blockIdx.x * PT;
    int t = threadIdx.x;
    for (int l = t; l < PT * CC; l += 256) {
        int p = l & (PT - 1); int i = l >> 4;
        xs[p][i] = X[((size_t)b * CC + i) * NN + n0 + p];
    }
    __syncthreads();
    int o = t;
    const float* wr = W + (size_t)o * CC;
    float acc[PT];
    float bo = bias[o];
#pragma unroll
    for (int p = 0; p < PT; ++p) acc[p] = bo;
    for (int i = 0; i < CC; ++i) {
        float w = wr[i];
#pragma unroll
        for (int p = 0; p < PT; ++p) acc[p] += w * xs[p][i];
    }
#pragma unroll
    for (int p = 0; p < PT; ++p)
        outT[((size_t)b * NN + n0 + p) * DIMD + o] = acc[p];
}

// ---------------- K5: pos_rel first/second moments (9 sums) ----------------
__global__ __launch_bounds__(256) void pos_stats_kernel(const float* __restrict__ pos,
                                                        const int* __restrict__ idx,
                                                        float* __restrict__ stats) {
    int sid = blockIdx.x * 256 + threadIdx.x;
    int b = sid / (NN * KK);
    int r = sid % (NN * KK);
    int n = r / KK;
    int m = idx[sid];
    const float* px = pos + (size_t)b * 3 * NN;
    float dx = px[n] - px[m];
    float dy = px[NN + n] - px[NN + m];
    float dz = px[2 * NN + n] - px[2 * NN + m];
    float v[9] = {dx, dy, dz, dx * dx, dy * dy, dz * dz, dx * dy, dx * dz, dy * dz};
    __shared__ float red[256];
    for (int j = 0; j < 9; ++j) {
        red[threadIdx.x] = v[j];
        __syncthreads();
        for (int off = 128; off >= 1; off >>= 1) {
            if (threadIdx.x < off) red[threadIdx.x] += red[threadIdx.x + off];
            __syncthreads();
        }
        if (threadIdx.x == 0) atomicAdd(&stats[j], red[0]);
        __syncthreads();
    }
}

// ---------------- K6: pos BN affine (a1, a0) per 64 channels ----------------
__global__ void pos_bn_kernel(const float* __restrict__ stats, const float* __restrict__ pw1,
                              const float* __restrict__ pb1, const float* __restrict__ pg1,
                              const float* __restrict__ pbe1, float* __restrict__ posA) {
    int c = threadIdx.x;
    if (c >= PHH) return;
    float M = (float)(BB * NN * KK);
    float mu0 = stats[0] / M, mu1 = stats[1] / M, mu2 = stats[2] / M;
    float E00 = stats[3] / M, E11 = stats[4] / M, E22 = stats[5] / M;
    float E01 = stats[6] / M, E02 = stats[7] / M, E12 = stats[8] / M;
    float w0 = pw1[c * 3], w1 = pw1[c * 3 + 1], w2 = pw1[c * 3 + 2];
    float wmu = w0 * mu0 + w1 * mu1 + w2 * mu2;
    float mean_h = wmu + pb1[c];
    float Eh2 = w0 * w0 * E00 + w1 * w1 * E11 + w2 * w2 * E22
              + 2.f * (w0 * w1 * E01 + w0 * w2 * E02 + w1 * w2 * E12)
              + 2.f * pb1[c] * wmu + pb1[c] * pb1[c];
    float var = Eh2 - mean_h * mean_h;
    float a1 = pg1[c] * rsqrtf(var + EPSF);
    posA[c] = a1;
    posA[PHH + c] = pbe1[c] - mean_h * a1;
}

// ---------------- K7: pos_emb + s = q - k_g + pe, stored bf16 (M x 256) ----------------
__global__ __launch_bounds__(256) void posemb_s_kernel(const float* __restrict__ pos,
                                                       const int* __restrict__ idx,
                                                       const float* __restrict__ pw1,
                                                       const float* __restrict__ pb1,
                                                       const float* __restrict__ posA,
                                                       const float* __restrict__ pw2,
                                                       const float* __restrict__ pb2,
                                                       const float* __restrict__ qT,
                                                       const float* __restrict__ kT,
                                                       ushort_t* __restrict__ sb16) {
    int bid = blockIdx.x;
    int b = bid / NN, n = bid % NN;
    int t = threadIdx.x;
    __shared__ int sm[KK];
    __shared__ float pr[KK][4];
    __shared__ float p1r[KK][PHH];
    if (t < KK) {
        int m = idx[(size_t)bid * KK + t];
        sm[t] = m;
        const float* px = pos + (size_t)b * 3 * NN;
        pr[t][0] = px[n] - px[m];
        pr[t][1] = px[NN + n] - px[NN + m];
        pr[t][2] = px[2 * NN + n] - px[2 * NN + m];
    }
    __syncthreads();
    for (int l = t; l < KK * PHH; l += 256) {
        int s_ = l >> 6, j = l & 63;
        float h = pw1[j * 3] * pr[s_][0] + pw1[j * 3 + 1] * pr[s_][1] + pw1[j * 3 + 2] * pr[s_][2] + pb1[j];
        p1r[s_][j] = fmaxf(h * posA[j] + posA[PHH + j], 0.f);
    }
    __syncthreads();
    int c = t;
    const float4* w2r4 = (const float4*)(pw2 + (size_t)c * PHH);
    float q = qT[((size_t)b * NN + n) * DIMD + c];
    float bb2 = pb2[c];
    ushort_t* srow = sb16 + (size_t)bid * KK * DIMD;
    for (int s_ = 0; s_ < KK; ++s_) {
        const float4* pr4 = (const float4*)p1r[s_];
        float pe = bb2;
#pragma unroll
        for (int j4 = 0; j4 < PHH / 4; ++j4) {
            float4 w4 = w2r4[j4]; float4 h4 = pr4[j4];
            pe += w4.x * h4.x + w4.y * h4.y + w4.z * h4.z + w4.w * h4.w;
        }
        float kv = kT[((size_t)b * NN + sm[s_]) * DIMD + c];
        srow[s_ * DIMD + c] = f2b(q - kv + pe);
    }
}

// ---------------- K8: mu = column sums of s ----------------
__global__ __launch_bounds__(256) void mu_kernel(const ushort_t* __restrict__ sb16,
                                                 float* __restrict__ mu) {
    int c = threadIdx.x;
    const ushort_t* p = sb16 + (size_t)blockIdx.x * 512 * DIMD + c;
    float acc = 0.f;
    for (int i = 0; i < 512; ++i) acc += b2f(p[(size_t)i * DIMD]);
    atomicAdd(&mu[c], acc);
}

// ---------------- K9: R partials via MFMA: Rpart[chunk] = S_chunk^T * S_chunk ----------
__global__ __launch_bounds__(256) void rg_kernel(const ushort_t* __restrict__ S,
                                                 float* __restrict__ Rpart) {
    __shared__ ushort_t ls[32 * LSTR];
    int t = threadIdx.x;
    int lane = t & 63, w = t >> 6;
    int wr = w >> 1, wc = w & 1;
    int ti = blockIdx.y >> 1, tj = blockIdx.y & 1;
    int m16 = lane & 15, kg = lane >> 4;
    size_t kbase = (size_t)blockIdx.x * RKCH;

    f32x4 acc[4][4];
#pragma unroll
    for (int i = 0; i < 4; ++i)
#pragma unroll
        for (int j = 0; j < 4; ++j) acc[i][j] = (f32x4){0.f, 0.f, 0.f, 0.f};

    int lm = t >> 3;
    int lc = (t & 7) * 32;
    const ushort_t* gS = S + (kbase + lm) * DIMD + lc;
    ushort_t* lp = ls + lm * LSTR + lc;

    for (int kt = 0; kt < RKCH / 32; ++kt) {
        const ushort_t* gp = gS + (size_t)kt * 32 * DIMD;
        u16x8 v0 = *(const u16x8*)(gp);
        u16x8 v1 = *(const u16x8*)(gp + 8);
        u16x8 v2 = *(const u16x8*)(gp + 16);
        u16x8 v3 = *(const u16x8*)(gp + 24);
        __syncthreads();
#pragma unroll
        for (int q = 0; q < 4; ++q) {
            *(u16x2*)(lp + 0 + 2 * q) = (u16x2){v0[2 * q], v0[2 * q + 1]};
            *(u16x2*)(lp + 8 + 2 * q) = (u16x2){v1[2 * q], v1[2 * q + 1]};
            *(u16x2*)(lp + 16 + 2 * q) = (u16x2){v2[2 * q], v2[2 * q + 1]};
            *(u16x2*)(lp + 24 + 2 * q) = (u16x2){v3[2 * q], v3[2 * q + 1]};
        }
        __syncthreads();
        short8 af[4], bf[4];
#pragma unroll
        for (int i = 0; i < 4; ++i) {
            int chA = ti * 128 + wr * 64 + i * 16 + m16;
            int chB = tj * 128 + wc * 64 + i * 16 + m16;
#pragma unroll
            for (int j = 0; j < 8; ++j) {
                int k = kg * 8 + j;
                af[i][j] = (short)ls[k * LSTR + chA];
                bf[i][j] = (short)ls[k * LSTR + chB];
            }
        }
#pragma unroll
        for (int i = 0; i < 4; ++i)
#pragma unroll
            for (int j = 0; j < 4; ++j)
                acc[i][j] = __builtin_amdgcn_mfma_f32_16x16x32_bf16(af[i], bf[j], acc[i][j], 0, 0, 0);
    }

    float* rp = Rpart + (size_t)blockIdx.x * (DIMD * DIMD);
#pragma unroll
    for (int i = 0; i < 4; ++i) {
        int r0 = ti * 128 + wr * 64 + i * 16 + kg * 4;
#pragma unroll
        for (int j = 0; j < 4; ++j) {
            int cn = tj * 128 + wc * 64 + j * 16 + m16;
#pragma unroll
            for (int rg = 0; rg < 4; ++rg)
                rp[(size_t)(r0 + rg) * DIMD + cn] = acc[i][j][rg];
        }
    }
}

// ---------------- K9b: reduce R partials ----------------
__global__ __launch_bounds__(256) void r_reduce_kernel(const float* __restrict__ Rpart,
                                                       float* __restrict__ R) {
    int e = blockIdx.x * 256 + threadIdx.x;
    float s = 0.f;
    for (int p = 0; p < RSPLIT; ++p) s += Rpart[(size_t)p * (DIMD * DIMD) + e];
    R[e] = s;
}

// ---------------- K10: attn BN -> fused scale/offset per hidden channel ----------------
__global__ __launch_bounds__(256) void attn_bn_kernel(const float* __restrict__ R,
                                                      const float* __restrict__ mu,
                                                      const float* __restrict__ aw1,
                                                      const float* __restrict__ ab1,
                                                      const float* __restrict__ ag1,
                                                      const float* __restrict__ abe1,
                                                      float* __restrict__ attA) {
    int c = blockIdx.x;
    int t = threadIdx.x;
    __shared__ float wsh[DIMD];
    __shared__ float red[DIMD];
    wsh[t] = aw1[(size_t)c * DIMD + t];
    __syncthreads();
    const float* Rr = R + (size_t)t * DIMD;
    float q = 0.f;
#pragma unroll 4
    for (int j = 0; j < DIMD; ++j) q += Rr[j] * wsh[j];
    red[t] = q * wsh[t];
    __syncthreads();
    for (int off = 128; off >= 1; off >>= 1) {
        if (t < off) red[t] += red[t + off];
        __syncthreads();
    }
    float wRw = red[0];
    __syncthreads();
    red[t] = wsh[t] * mu[t];
    __syncthreads();
    for (int off = 128; off >= 1; off >>= 1) {
        if (t < off) red[t] += red[t + off];
        __syncthreads();
    }
    if (t == 0) {
        float M = (float)(BB * NN * KK);
        float wmu = red[0] / M;
        float b1c = ab1[c];
        float Eh = wmu + b1c;
        float Eh2 = wRw / M + 2.f * b1c * wmu + b1c * b1c;
        float var = Eh2 - Eh * Eh;
        float a1 = ag1[c] * rsqrtf(var + EPSF);
        attA[c] = a1;
        attA[AHH + c] = a1 * b1c + abe1[c] - Eh * a1;
    }
}

// ---------------- K10b: convert W1 (1024x256) and W2 (256x1024) to bf16 ----------------
__global__ void cvt_w_kernel(const float* __restrict__ aw1, const float* __restrict__ aw2,
                             ushort_t* __restrict__ w1b, ushort_t* __restrict__ w2b) {
    int i = blockIdx.x * 256 + threadIdx.x;
    if (i < AHH * DIMD) w1b[i] = f2b(aw1[i]);
    else {
        int j = i - AHH * DIMD;
        w2b[j] = f2b(aw2[j]);
    }
}

// ---------------- MFMA GEMM: C(M x N) = A(M x K) * B(N x K)^T, bf16 in fp32 acc ----
template <int KDIM, int EPI>
__global__ __launch_bounds__(256) void gemm_kernel(const ushort_t* __restrict__ A,
                                                   const ushort_t* __restrict__ Bm,
                                                   const float* __restrict__ p0,
                                                   const float* __restrict__ p1,
                                                   void* __restrict__ Out) {
    __shared__ ushort_t lA[128 * 32];
    __shared__ ushort_t lB[128 * 32];
    int t = threadIdx.x;
    int lane = t & 63, w = t >> 6;
    int wr = w >> 1, wc = w & 1;
    size_t row0 = (size_t)blockIdx.x * 128;
    int col0 = blockIdx.y * 128;
    int m16 = lane & 15, kg = lane >> 4;

    f32x4 acc[4][4];
#pragma unroll
    for (int i = 0; i < 4; ++i)
#pragma unroll
        for (int j = 0; j < 4; ++j) acc[i][j] = (f32x4){0.f, 0.f, 0.f, 0.f};

    const ushort_t* gA = A + (row0 + (size_t)w * 16 + m16) * KDIM + kg * 8;
    const ushort_t* gB = Bm + ((size_t)(col0 + w * 16 + m16)) * KDIM + kg * 8;
    ushort_t* lA0 = lA + w * 512;
    ushort_t* lB0 = lB + w * 512;

    for (int kt = 0; kt < KDIM / 32; ++kt) {
        int ko = kt * 32;
        GLDS16(gA + ko, lA0);
        GLDS16(gA + (size_t)64 * KDIM + ko, lA0 + 2048);
        GLDS16(gB + ko, lB0);
        GLDS16(gB + (size_t)64 * KDIM + ko, lB0 + 2048);
        __syncthreads();
        short8 af[4], bf[4];
#pragma unroll
        for (int i = 0; i < 4; ++i) {
            af[i] = *(const short8*)(lA + ((wr * 4 + i) * 512 + kg * 128 + m16 * 8));
            bf[i] = *(const short8*)(lB + ((wc * 4 + i) * 512 + kg * 128 + m16 * 8));
        }
#pragma unroll
        for (int i = 0; i < 4; ++i)
#pragma unroll
            for (int j = 0; j < 4; ++j)
                acc[i][j] = __builtin_amdgcn_mfma_f32_16x16x32_bf16(af[i], bf[j], acc[i][j], 0, 0, 0);
        __syncthreads();
    }

    if (EPI == 0) {
        ushort_t* Hb = (ushort_t*)Out;
#pragma unroll
        for (int j = 0; j < 4; ++j) {
            int n = col0 + wc * 64 + j * 16 + m16;
            float sc = p0[n], of = p1[n];
#pragma unroll
            for (int i = 0; i < 4; ++i) {
                size_t r = row0 + wr * 64 + i * 16 + kg * 4;
#pragma unroll
                for (int rg = 0; rg < 4; ++rg) {
                    float v = fmaxf(sc * acc[i][j][rg] + of, 0.f);
                    Hb[(r + rg) * (size_t)AHH + n] = f2b(v);
                }
            }
        }
    } else {
        float* Lb = (float*)Out;
#pragma unroll
        for (int j = 0; j < 4; ++j) {
            int n = col0 + wc * 64 + j * 16 + m16;
            float bi = p0[n];
#pragma unroll
            for (int i = 0; i < 4; ++i) {
                size_t r = row0 + wr * 64 + i * 16 + kg * 4;
#pragma unroll
                for (int rg = 0; rg < 4; ++rg)
                    Lb[(r + rg) * (size_t)DIMD + n] = acc[i][j][rg] + bi;
            }
        }
    }
}

// ---------------- K11: softmax over K + aggregation (per chunk) ----------------
__global__ __launch_bounds__(256) void softmax_agg_kernel(const int* __restrict__ idx,
                                                          const float* __restrict__ lbuf,
                                                          const ushort_t* __restrict__ sb16,
                                                          const float* __restrict__ qT,
                                                          const float* __restrict__ kT,
                                                          const float* __restrict__ vT,
                                                          float* __restrict__ aggT,
                                                          int pbase) {
    int p = pbase + blockIdx.x;      // global point id
    int b = p / NN, n = p % NN;
    int c = threadIdx.x;
    __shared__ int sm[KK];
    if (c < KK) sm[c] = idx[(size_t)p * KK + c];
    __syncthreads();
    const float* lrow = lbuf + (size_t)blockIdx.x * KK * DIMD + c;  // chunk-local
    float lg[KK];
#pragma unroll
    for (int s = 0; s < KK; ++s) lg[s] = lrow[(size_t)s * DIMD];
    float mx = lg[0];
#pragma unroll
    for (int s = 1; s < KK; ++s) mx = fmaxf(mx, lg[s]);
    float sum = 0.f;
#pragma unroll
    for (int s = 0; s < KK; ++s) { lg[s] = expf(lg[s] - mx); sum += lg[s]; }
    float inv = 1.f / sum;
    float q = qT[((size_t)b * NN + n) * DIMD + c];
    float vf = vT[((size_t)b * NN + n) * DIMD + c];
    const ushort_t* srow = sb16 + (size_t)p * KK * DIMD + c;
    float agg = 0.f;
#pragma unroll
    for (int s = 0; s < KK; ++s) {
        float kv = kT[((size_t)b * NN + sm[s]) * DIMD + c];
        float vv = vf + b2f(srow[(size_t)s * DIMD]) - q + kv;
        agg += lg[s] * inv * vv;
    }
    aggT[((size_t)b * NN + n) * DIMD + c] = agg;
}

// ---------------- K12: y = we·agg + be + identity ----------------
__global__ __launch_bounds__(256) void final_kernel(const float* __restrict__ aggT,
                                                    const float* __restrict__ we,
                                                    const float* __restrict__ be,
                                                    const float* __restrict__ value,
                                                    float* __restrict__ out) {
    int n = blockIdx.x * 256 + threadIdx.x;
    int o = blockIdx.y, b = blockIdx.z;
    const float* wr = we + (size_t)o * DIMD;
    const float* ar = aggT + ((size_t)b * NN + n) * DIMD;
    float acc = be[o];
#pragma unroll 4
    for (int i = 0; i < DIMD; ++i) acc += wr[i] * ar[i];
    size_t oi = ((size_t)b * CC + o) * NN + n;
    out[oi] = acc + value[oi];
}

extern "C" void kernel_launch(void* const* d_in, const int* in_sizes, int n_in,
                              void* d_out, int out_size, void* d_ws, size_t ws_size,
                              hipStream_t stream) {
    (void)in_sizes; (void)n_in; (void)out_size; (void)ws_size;
    const float* pos     = (const float*)d_in[0];
    const float* key     = (const float*)d_in[1];
    const float* query   = (const float*)d_in[2];
    const float* mlpv_w1 = (const float*)d_in[3];
    const float* mlpv_b1 = (const float*)d_in[4];
    const float* mlpv_w2 = (const float*)d_in[5];
    const float* mlpv_b2 = (const float*)d_in[6];
    const float* mlpv_ws = (const float*)d_in[7];
    const float* mlpv_bs = (const float*)d_in[8];
    const float* wk  = (const float*)d_in[9];
    const float* bk  = (const float*)d_in[10];
    const float* wq  = (const float*)d_in[11];
    const float* bq  = (const float*)d_in[12];
    const float* wv  = (const float*)d_in[13];
    const float* bv  = (const float*)d_in[14];
    const float* pw1 = (const float*)d_in[15];
    const float* pb1 = (const float*)d_in[16];
    const float* pg1 = (const float*)d_in[17];
    const float* pbe1= (const float*)d_in[18];
    const float* pw2 = (const float*)d_in[19];
    const float* pb2 = (const float*)d_in[20];
    const float* aw1 = (const float*)d_in[21];
    const float* ab1 = (const float*)d_in[22];
    const float* ag1 = (const float*)d_in[23];
    const float* abe1= (const float*)d_in[24];
    const float* aw2 = (const float*)d_in[25];
    const float* ab2 = (const float*)d_in[26];
    const float* we  = (const float*)d_in[27];
    const float* be  = (const float*)d_in[28];
    float* out = (float*)d_out;

    char* wsb = (char*)d_ws;
    size_t off = 0;
    auto alloc = [&](size_t bytes) {
        void* p = wsb + off;
        off += (bytes + 255) & ~(size_t)255;
        return p;
    };
    const size_t M = (size_t)BB * NN * KK;  // 131072 rows
    int*   idx   = (int*)  alloc(M * 4);
    float* h1buf = (float*)alloc((size_t)BB * CC * NN * 4);
    float* value = (float*)alloc((size_t)BB * CC * NN * 4);
    float* kT    = (float*)alloc((size_t)BB * NN * DIMD * 4);
    float* qT    = (float*)alloc((size_t)BB * NN * DIMD * 4);
    float* vT    = (float*)alloc((size_t)BB * NN * DIMD * 4);
    float* aggT  = (float*)alloc((size_t)BB * NN * DIMD * 4);
    float* zero0 = (float*)alloc((size_t)(16 + 256 + 65536) * 4);
    float* stats = zero0;
    float* mu    = zero0 + 16;
    float* R     = zero0 + 16 + 256;
    float* posA  = (float*)alloc((size_t)2 * PHH * 4);
    float* attA  = (float*)alloc((size_t)2 * AHH * 4);
    ushort_t* w1b = (ushort_t*)alloc((size_t)AHH * DIMD * 2);
    ushort_t* w2b = (ushort_t*)alloc((size_t)DIMD * AHH * 2);
    ushort_t* sb16 = (ushort_t*)alloc(M * DIMD * 2);          //  67 MB
    char* ovl = (char*)alloc((size_t)MCH * AHH * 2 + (size_t)MCH * DIMD * 4);
    float*    Rpart = (float*)ovl;
    ushort_t* Hbuf  = (ushort_t*)ovl;
    float*    lbuf  = (float*)(ovl + (size_t)MCH * AHH * 2);

    int ZN = 16 + 256 + 65536;
    zero_kernel<<<(ZN + 255) / 256, 256, 0, stream>>>(zero0, ZN);
    knn_kernel<<<BB * NN, 256, 0, stream>>>(pos, idx);
    h1_kernel<<<dim3(NN / 256, CC, BB), 256, 0, stream>>>(key, query, mlpv_w1, mlpv_b1, h1buf);
    value_kernel<<<dim3(NN / 256, CC, BB), 256, 0, stream>>>(key, query, h1buf, mlpv_w2, mlpv_b2, mlpv_ws, mlpv_bs, value);
    convT_kernel<<<dim3(NN / PT, BB), 256, 0, stream>>>(wk, bk, key, kT);
    convT_kernel<<<dim3(NN / PT, BB), 256, 0, stream>>>(wq, bq, query, qT);
    convT_kernel<<<dim3(NN / PT, BB), 256, 0, stream>>>(wv, bv, value, vT);
    pos_stats_kernel<<<BB * NN * KK / 256, 256, 0, stream>>>(pos, idx, stats);
    pos_bn_kernel<<<1, 64, 0, stream>>>(stats, pw1, pb1, pg1, pbe1, posA);
    posemb_s_kernel<<<BB * NN, 256, 0, stream>>>(pos, idx, pw1, pb1, posA, pw2, pb2, qT, kT, sb16);
    mu_kernel<<<M / 512, 256, 0, stream>>>(sb16, mu);
    rg_kernel<<<dim3(RSPLIT, 4), 256, 0, stream>>>(sb16, Rpart);
    r_reduce_kernel<<<DIMD * DIMD / 256, 256, 0, stream>>>(Rpart, R);
    attn_bn_kernel<<<AHH, DIMD, 0, stream>>>(R, mu, aw1, ab1, ag1, abe1, attA);
    cvt_w_kernel<<<(2 * AHH * DIMD) / 256, 256, 0, stream>>>(aw1, aw2, w1b, w2b);

    const int NCHUNK = (int)(M / MCH);
    for (int ch = 0; ch < NCHUNK; ++ch) {
        const ushort_t* Sc = sb16 + (size_t)ch * MCH * DIMD;
        gemm_kernel<DIMD, 0><<<dim3(MCH / 128, AHH / 128), 256, 0, stream>>>(Sc, w1b, attA, attA + AHH, Hbuf);
        gemm_kernel<AHH, 1><<<dim3(MCH / 128, DIMD / 128), 256, 0, stream>>>(Hbuf, w2b, ab2, nullptr, lbuf);
        softmax_agg_kernel<<<MCH / KK, 256, 0, stream>>>(idx, lbuf, sb16, qT, kT, vT, aggT, ch * (MCH / KK));
    }
    final_kernel<<<dim3(NN / 256, CC, BB), 256, 0, stream>>>(aggT, we, be, value, out);
}

// Round 6
// 1176.542 us; speedup vs baseline: 4.7036x; 1.1411x over previous
//
#include <hip/hip_runtime.h>
#include <math.h>

#define BB 2
#define CC 128
#define NN 4096
#define KK 16
#define DIMD 256
#define PHH 64
#define AHH 1024
#define EPSF 1e-5f
#define PT 16
#define MCH 16384   // M-chunk rows (1024 points x K)
#define RSPLIT 128
#define RKCH ((BB * NN * KK) / RSPLIT)   // 1024 samples per R block
#define LSTR 258    // LDS row stride (halfwords): conflict-free transposed gathers
#define KNN_CAP 512
#define FPT 8       // final_kernel points per thread

typedef unsigned short ushort_t;
typedef unsigned long long u64;
typedef __attribute__((ext_vector_type(8))) short short8;
typedef __attribute__((ext_vector_type(8))) unsigned short u16x8;
typedef __attribute__((ext_vector_type(2))) unsigned short u16x2;
typedef __attribute__((ext_vector_type(4))) float f32x4;

__device__ __forceinline__ ushort_t f2b(float x) {
    union { float f; unsigned u; } v; v.f = x;
    unsigned r = v.u + 0x7fff + ((v.u >> 16) & 1);
    return (ushort_t)(r >> 16);
}
__device__ __forceinline__ float b2f(ushort_t x) {
    union { unsigned u; float f; } v; v.u = ((unsigned)x) << 16;
    return v.f;
}
__device__ __forceinline__ unsigned fsort(float x) {
    union { float f; unsigned u; } v; v.f = x;
    return v.u ^ ((v.u >> 31) ? 0xFFFFFFFFu : 0x80000000u);
}

#define GLDS16(gp, lp) __builtin_amdgcn_global_load_lds( \
    (const __attribute__((address_space(1))) void*)(gp), \
    (__attribute__((address_space(3))) void*)(lp), 16, 0, 0)

// ---------------- K0: zero scratch accumulators ----------------
__global__ void zero_kernel(float* p, int n) {
    int i = blockIdx.x * blockDim.x + threadIdx.x;
    if (i < n) p[i] = 0.f;
}

// ---------------- K1: exact kNN via u64-key threshold select ----------------
__global__ __launch_bounds__(256) void knn_kernel(const float* __restrict__ pos,
                                                  int* __restrict__ idx) {
    int bid = blockIdx.x;
    int b = bid / NN, n = bid % NN;
    int t = threadIdx.x;
    int lane = t & 63, w = t >> 6;
    const float* px = pos + (size_t)b * 3 * NN;
    const float* py = px + NN;
    const float* pz = px + 2 * NN;
    float qx = px[n], qy = py[n], qz = pz[n];
    float qs = qx * qx + qy * qy + qz * qz;

    u64 keys[KK];
    u64 lmin = ~0ull;
#pragma unroll
    for (int j = 0; j < KK; ++j) {
        int m = t + 256 * j;
        float mx = px[m], my = py[m], mz = pz[m];
        float ms = mx * mx + my * my + mz * mz;
        float dt = qx * mx + qy * my + qz * mz;
        float d = qs + ms - 2.f * dt;
        u64 k = ((u64)fsort(d) << 32) | (unsigned)m;
        keys[j] = k;
        lmin = k < lmin ? k : lmin;
    }

    __shared__ u64 T0s[4];
    __shared__ u64 pool[KNN_CAP];
    __shared__ int cnt;

    u64 k = lmin, m4 = 0;
#pragma unroll
    for (int r = 0; r < 4; ++r) {
        u64 mv = k;
#pragma unroll
        for (int off = 32; off >= 1; off >>= 1) {
            u64 o = __shfl_xor(mv, off);
            mv = o < mv ? o : mv;
        }
        if (r == 3) m4 = mv;
        if (k == mv) k = ~0ull;
    }
    if (lane == 0) T0s[w] = m4;
    if (t == 0) cnt = 0;
    __syncthreads();
    u64 T0 = T0s[0];
    T0 = T0s[1] > T0 ? T0s[1] : T0;
    T0 = T0s[2] > T0 ? T0s[2] : T0;
    T0 = T0s[3] > T0 ? T0s[3] : T0;

#pragma unroll
    for (int j = 0; j < KK; ++j) {
        if (keys[j] <= T0) {
            int p = atomicAdd(&cnt, 1);
            if (p < KNN_CAP) pool[p] = keys[j];
        }
    }
    __syncthreads();
    int C = cnt < KNN_CAP ? cnt : KNN_CAP;
    if (t < C) {
        u64 me = pool[t];
        int r = 0;
        for (int i = 0; i < C; ++i) r += (pool[i] < me);
        if (r < KK) idx[(size_t)bid * KK + r] = (int)(me & 0xFFFFFFFFu);
    }
}

// ---------------- K2: h1 = relu(W1·[key;query] + b1) ----------------
__global__ __launch_bounds__(256) void h1_kernel(const float* __restrict__ key,
                                                 const float* __restrict__ query,
                                                 const float* __restrict__ w1,
                                                 const float* __restrict__ b1,
                                                 float* __restrict__ h1) {
    int n = blockIdx.x * 256 + threadIdx.x;
    int o = blockIdx.y, b = blockIdx.z;
    const float* wr = w1 + (size_t)o * 256;
    const float* kb = key + (size_t)b * CC * NN;
    const float* qb = query + (size_t)b * CC * NN;
    float acc = b1[o];
#pragma unroll 4
    for (int i = 0; i < CC; ++i) acc += wr[i] * kb[(size_t)i * NN + n];
#pragma unroll 4
    for (int i = 0; i < CC; ++i) acc += wr[CC + i] * qb[(size_t)i * NN + n];
    h1[((size_t)b * CC + o) * NN + n] = fmaxf(acc, 0.f);
}

// ---------------- K3: value = W2·h1 + b2 + Ws·[key;query] + bs ----------------
__global__ __launch_bounds__(256) void value_kernel(const float* __restrict__ key,
                                                    const float* __restrict__ query,
                                                    const float* __restrict__ h1buf,
                                                    const float* __restrict__ w2,
                                                    const float* __restrict__ b2,
                                                    const float* __restrict__ wsk,
                                                    const float* __restrict__ bs,
                                                    float* __restrict__ value) {
    int n = blockIdx.x * 256 + threadIdx.x;
    int o = blockIdx.y, b = blockIdx.z;
    const float* w2r = w2 + (size_t)o * CC;
    const float* wsr = wsk + (size_t)o * 256;
    const float* kb = key + (size_t)b * CC * NN;
    const float* qb = query + (size_t)b * CC * NN;
    const float* hb = h1buf + (size_t)b * CC * NN;
    float acc = b2[o] + bs[o];
#pragma unroll 4
    for (int i = 0; i < CC; ++i) acc += w2r[i] * hb[(size_t)i * NN + n];
#pragma unroll 4
    for (int i = 0; i < CC; ++i) acc += wsr[i] * kb[(size_t)i * NN + n];
#pragma unroll 4
    for (int i = 0; i < CC; ++i) acc += wsr[CC + i] * qb[(size_t)i * NN + n];
    value[((size_t)b * CC + o) * NN + n] = acc;
}

// ---------------- K4: outT[b][n][o] = bias[o] + W(256x128)·X[b,:,n] ----------------
__global__ __launch_bounds__(256) void convT_kernel(const float* __restrict__ W,
                                                    const float* __restrict__ bias,
                                                    const float* __restrict__ X,
                                                    float* __restrict__ outT) {
    __shared__ float xs[PT][CC + 1];
    int b = blockIdx.y;
    int n0 = blockIdx.x * PT;
    int t = threadIdx.x;
    for (int l = t; l < PT * CC; l += 256) {
        int p = l & (PT - 1); int i = l >> 4;
        xs[p][i] = X[((size_t)b * CC + i) * NN + n0 + p];
    }
    __syncthreads();
    int o = t;
    const float* wr = W + (size_t)o * CC;
    float acc[PT];
    float bo = bias[o];
#pragma unroll
    for (int p = 0; p < PT; ++p) acc[p] = bo;
    for (int i = 0; i < CC; ++i) {
        float w = wr[i];
#pragma unroll
        for (int p = 0; p < PT; ++p) acc[p] += w * xs[p][i];
    }
#pragma unroll
    for (int p = 0; p < PT; ++p)
        outT[((size_t)b * NN + n0 + p) * DIMD + o] = acc[p];
}

// ---------------- K5: pos_rel first/second moments (9 sums) ----------------
__global__ __launch_bounds__(256) void pos_stats_kernel(const float* __restrict__ pos,
                                                        const int* __restrict__ idx,
                                                        float* __restrict__ stats) {
    int sid = blockIdx.x * 256 + threadIdx.x;
    int b = sid / (NN * KK);
    int r = sid % (NN * KK);
    int n = r / KK;
    int m = idx[sid];
    const float* px = pos + (size_t)b * 3 * NN;
    float dx = px[n] - px[m];
    float dy = px[NN + n] - px[NN + m];
    float dz = px[2 * NN + n] - px[2 * NN + m];
    float v[9] = {dx, dy, dz, dx * dx, dy * dy, dz * dz, dx * dy, dx * dz, dy * dz};
    __shared__ float red[256];
    for (int j = 0; j < 9; ++j) {
        red[threadIdx.x] = v[j];
        __syncthreads();
        for (int off = 128; off >= 1; off >>= 1) {
            if (threadIdx.x < off) red[threadIdx.x] += red[threadIdx.x + off];
            __syncthreads();
        }
        if (threadIdx.x == 0) atomicAdd(&stats[j], red[0]);
        __syncthreads();
    }
}

// ---------------- K6: pos BN affine (a1, a0) per 64 channels ----------------
__global__ void pos_bn_kernel(const float* __restrict__ stats, const float* __restrict__ pw1,
                              const float* __restrict__ pb1, const float* __restrict__ pg1,
                              const float* __restrict__ pbe1, float* __restrict__ posA) {
    int c = threadIdx.x;
    if (c >= PHH) return;
    float M = (float)(BB * NN * KK);
    float mu0 = stats[0] / M, mu1 = stats[1] / M, mu2 = stats[2] / M;
    float E00 = stats[3] / M, E11 = stats[4] / M, E22 = stats[5] / M;
    float E01 = stats[6] / M, E02 = stats[7] / M, E12 = stats[8] / M;
    float w0 = pw1[c * 3], w1 = pw1[c * 3 + 1], w2 = pw1[c * 3 + 2];
    float wmu = w0 * mu0 + w1 * mu1 + w2 * mu2;
    float mean_h = wmu + pb1[c];
    float Eh2 = w0 * w0 * E00 + w1 * w1 * E11 + w2 * w2 * E22
              + 2.f * (w0 * w1 * E01 + w0 * w2 * E02 + w1 * w2 * E12)
              + 2.f * pb1[c] * wmu + pb1[c] * pb1[c];
    float var = Eh2 - mean_h * mean_h;
    float a1 = pg1[c] * rsqrtf(var + EPSF);
    posA[c] = a1;
    posA[PHH + c] = pbe1[c] - mean_h * a1;
}

// ---------------- K7: pos_emb + s = q - k_g + pe, stored bf16 (M x 256) ----------------
__global__ __launch_bounds__(256) void posemb_s_kernel(const float* __restrict__ pos,
                                                       const int* __restrict__ idx,
                                                       const float* __restrict__ pw1,
                                                       const float* __restrict__ pb1,
                                                       const float* __restrict__ posA,
                                                       const float* __restrict__ pw2,
                                                       const float* __restrict__ pb2,
                                                       const float* __restrict__ qT,
                                                       const float* __restrict__ kT,
                                                       ushort_t* __restrict__ sb16) {
    int bid = blockIdx.x;
    int b = bid / NN, n = bid % NN;
    int t = threadIdx.x;
    __shared__ int sm[KK];
    __shared__ float pr[KK][4];
    __shared__ float p1r[KK][PHH];
    if (t < KK) {
        int m = idx[(size_t)bid * KK + t];
        sm[t] = m;
        const float* px = pos + (size_t)b * 3 * NN;
        pr[t][0] = px[n] - px[m];
        pr[t][1] = px[NN + n] - px[NN + m];
        pr[t][2] = px[2 * NN + n] - px[2 * NN + m];
    }
    __syncthreads();
    for (int l = t; l < KK * PHH; l += 256) {
        int s_ = l >> 6, j = l & 63;
        float h = pw1[j * 3] * pr[s_][0] + pw1[j * 3 + 1] * pr[s_][1] + pw1[j * 3 + 2] * pr[s_][2] + pb1[j];
        p1r[s_][j] = fmaxf(h * posA[j] + posA[PHH + j], 0.f);
    }
    __syncthreads();
    int c = t;
    // hoist the 64-float pw2 row into registers (was re-loaded 16x)
    float4 wreg[PHH / 4];
    const float4* w2r4 = (const float4*)(pw2 + (size_t)c * PHH);
#pragma unroll
    for (int j4 = 0; j4 < PHH / 4; ++j4) wreg[j4] = w2r4[j4];
    float q = qT[((size_t)b * NN + n) * DIMD + c];
    float bb2 = pb2[c];
    ushort_t* srow = sb16 + (size_t)bid * KK * DIMD;
    for (int s_ = 0; s_ < KK; ++s_) {
        const float4* pr4 = (const float4*)p1r[s_];
        float pe = bb2;
#pragma unroll
        for (int j4 = 0; j4 < PHH / 4; ++j4) {
            float4 w4 = wreg[j4]; float4 h4 = pr4[j4];
            pe += w4.x * h4.x + w4.y * h4.y + w4.z * h4.z + w4.w * h4.w;
        }
        float kv = kT[((size_t)b * NN + sm[s_]) * DIMD + c];
        srow[s_ * DIMD + c] = f2b(q - kv + pe);
    }
}

// ---------------- K8: mu = column sums of s ----------------
__global__ __launch_bounds__(256) void mu_kernel(const ushort_t* __restrict__ sb16,
                                                 float* __restrict__ mu) {
    int c = threadIdx.x;
    const ushort_t* p = sb16 + (size_t)blockIdx.x * 512 * DIMD + c;
    float acc = 0.f;
    for (int i = 0; i < 512; ++i) acc += b2f(p[(size_t)i * DIMD]);
    atomicAdd(&mu[c], acc);
}

// ---------------- K9: R partials via MFMA: Rpart[chunk] = S_chunk^T * S_chunk ----------
__global__ __launch_bounds__(256) void rg_kernel(const ushort_t* __restrict__ S,
                                                 float* __restrict__ Rpart) {
    __shared__ ushort_t ls[32 * LSTR];
    int t = threadIdx.x;
    int lane = t & 63, w = t >> 6;
    int wr = w >> 1, wc = w & 1;
    int ti = blockIdx.y >> 1, tj = blockIdx.y & 1;
    int m16 = lane & 15, kg = lane >> 4;
    size_t kbase = (size_t)blockIdx.x * RKCH;

    f32x4 acc[4][4];
#pragma unroll
    for (int i = 0; i < 4; ++i)
#pragma unroll
        for (int j = 0; j < 4; ++j) acc[i][j] = (f32x4){0.f, 0.f, 0.f, 0.f};

    int lm = t >> 3;
    int lc = (t & 7) * 32;
    const ushort_t* gS = S + (kbase + lm) * DIMD + lc;
    ushort_t* lp = ls + lm * LSTR + lc;

    for (int kt = 0; kt < RKCH / 32; ++kt) {
        const ushort_t* gp = gS + (size_t)kt * 32 * DIMD;
        u16x8 v0 = *(const u16x8*)(gp);
        u16x8 v1 = *(const u16x8*)(gp + 8);
        u16x8 v2 = *(const u16x8*)(gp + 16);
        u16x8 v3 = *(const u16x8*)(gp + 24);
        __syncthreads();
#pragma unroll
        for (int q = 0; q < 4; ++q) {
            *(u16x2*)(lp + 0 + 2 * q) = (u16x2){v0[2 * q], v0[2 * q + 1]};
            *(u16x2*)(lp + 8 + 2 * q) = (u16x2){v1[2 * q], v1[2 * q + 1]};
            *(u16x2*)(lp + 16 + 2 * q) = (u16x2){v2[2 * q], v2[2 * q + 1]};
            *(u16x2*)(lp + 24 + 2 * q) = (u16x2){v3[2 * q], v3[2 * q + 1]};
        }
        __syncthreads();
        short8 af[4], bf[4];
#pragma unroll
        for (int i = 0; i < 4; ++i) {
            int chA = ti * 128 + wr * 64 + i * 16 + m16;
            int chB = tj * 128 + wc * 64 + i * 16 + m16;
#pragma unroll
            for (int j = 0; j < 8; ++j) {
                int k = kg * 8 + j;
                af[i][j] = (short)ls[k * LSTR + chA];
                bf[i][j] = (short)ls[k * LSTR + chB];
            }
        }
#pragma unroll
        for (int i = 0; i < 4; ++i)
#pragma unroll
            for (int j = 0; j < 4; ++j)
                acc[i][j] = __builtin_amdgcn_mfma_f32_16x16x32_bf16(af[i], bf[j], acc[i][j], 0, 0, 0);
    }

    float* rp = Rpart + (size_t)blockIdx.x * (DIMD * DIMD);
#pragma unroll
    for (int i = 0; i < 4; ++i) {
        int r0 = ti * 128 + wr * 64 + i * 16 + kg * 4;
#pragma unroll
        for (int j = 0; j < 4; ++j) {
            int cn = tj * 128 + wc * 64 + j * 16 + m16;
#pragma unroll
            for (int rg = 0; rg < 4; ++rg)
                rp[(size_t)(r0 + rg) * DIMD + cn] = acc[i][j][rg];
        }
    }
}

// ---------------- K9b: reduce R partials ----------------
__global__ __launch_bounds__(256) void r_reduce_kernel(const float* __restrict__ Rpart,
                                                       float* __restrict__ R) {
    int e = blockIdx.x * 256 + threadIdx.x;
    float s = 0.f;
    for (int p = 0; p < RSPLIT; ++p) s += Rpart[(size_t)p * (DIMD * DIMD) + e];
    R[e] = s;
}

// ---------------- K10: attn BN -> fused scale/offset per hidden channel ----------------
__global__ __launch_bounds__(256) void attn_bn_kernel(const float* __restrict__ R,
                                                      const float* __restrict__ mu,
                                                      const float* __restrict__ aw1,
                                                      const float* __restrict__ ab1,
                                                      const float* __restrict__ ag1,
                                                      const float* __restrict__ abe1,
                                                      float* __restrict__ attA) {
    int c = blockIdx.x;
    int t = threadIdx.x;
    __shared__ float wsh[DIMD];
    __shared__ float red[DIMD];
    wsh[t] = aw1[(size_t)c * DIMD + t];
    __syncthreads();
    const float* Rr = R + (size_t)t * DIMD;
    float q = 0.f;
#pragma unroll 4
    for (int j = 0; j < DIMD; ++j) q += Rr[j] * wsh[j];
    red[t] = q * wsh[t];
    __syncthreads();
    for (int off = 128; off >= 1; off >>= 1) {
        if (t < off) red[t] += red[t + off];
        __syncthreads();
    }
    float wRw = red[0];
    __syncthreads();
    red[t] = wsh[t] * mu[t];
    __syncthreads();
    for (int off = 128; off >= 1; off >>= 1) {
        if (t < off) red[t] += red[t + off];
        __syncthreads();
    }
    if (t == 0) {
        float M = (float)(BB * NN * KK);
        float wmu = red[0] / M;
        float b1c = ab1[c];
        float Eh = wmu + b1c;
        float Eh2 = wRw / M + 2.f * b1c * wmu + b1c * b1c;
        float var = Eh2 - Eh * Eh;
        float a1 = ag1[c] * rsqrtf(var + EPSF);
        attA[c] = a1;
        attA[AHH + c] = a1 * b1c + abe1[c] - Eh * a1;
    }
}

// ---------------- K10b: convert W1 (1024x256) and W2 (256x1024) to bf16 ----------------
__global__ void cvt_w_kernel(const float* __restrict__ aw1, const float* __restrict__ aw2,
                             ushort_t* __restrict__ w1b, ushort_t* __restrict__ w2b) {
    int i = blockIdx.x * 256 + threadIdx.x;
    if (i < AHH * DIMD) w1b[i] = f2b(aw1[i]);
    else {
        int j = i - AHH * DIMD;
        w2b[j] = f2b(aw2[j]);
    }
}

// ---------------- MFMA GEMM: C(M x N) = A(M x K) * B(N x K)^T, bf16 in fp32 acc ----
template <int KDIM, int EPI>
__global__ __launch_bounds__(256) void gemm_kernel(const ushort_t* __restrict__ A,
                                                   const ushort_t* __restrict__ Bm,
                                                   const float* __restrict__ p0,
                                                   const float* __restrict__ p1,
                                                   void* __restrict__ Out) {
    __shared__ ushort_t lA[128 * 32];
    __shared__ ushort_t lB[128 * 32];
    int t = threadIdx.x;
    int lane = t & 63, w = t >> 6;
    int wr = w >> 1, wc = w & 1;
    size_t row0 = (size_t)blockIdx.x * 128;
    int col0 = blockIdx.y * 128;
    int m16 = lane & 15, kg = lane >> 4;

    f32x4 acc[4][4];
#pragma unroll
    for (int i = 0; i < 4; ++i)
#pragma unroll
        for (int j = 0; j < 4; ++j) acc[i][j] = (f32x4){0.f, 0.f, 0.f, 0.f};

    const ushort_t* gA = A + (row0 + (size_t)w * 16 + m16) * KDIM + kg * 8;
    const ushort_t* gB = Bm + ((size_t)(col0 + w * 16 + m16)) * KDIM + kg * 8;
    ushort_t* lA0 = lA + w * 512;
    ushort_t* lB0 = lB + w * 512;

    for (int kt = 0; kt < KDIM / 32; ++kt) {
        int ko = kt * 32;
        GLDS16(gA + ko, lA0);
        GLDS16(gA + (size_t)64 * KDIM + ko, lA0 + 2048);
        GLDS16(gB + ko, lB0);
        GLDS16(gB + (size_t)64 * KDIM + ko, lB0 + 2048);
        __syncthreads();
        short8 af[4], bf[4];
#pragma unroll
        for (int i = 0; i < 4; ++i) {
            af[i] = *(const short8*)(lA + ((wr * 4 + i) * 512 + kg * 128 + m16 * 8));
            bf[i] = *(const short8*)(lB + ((wc * 4 + i) * 512 + kg * 128 + m16 * 8));
        }
#pragma unroll
        for (int i = 0; i < 4; ++i)
#pragma unroll
            for (int j = 0; j < 4; ++j)
                acc[i][j] = __builtin_amdgcn_mfma_f32_16x16x32_bf16(af[i], bf[j], acc[i][j], 0, 0, 0);
        __syncthreads();
    }

    if (EPI == 0) {
        ushort_t* Hb = (ushort_t*)Out;
#pragma unroll
        for (int j = 0; j < 4; ++j) {
            int n = col0 + wc * 64 + j * 16 + m16;
            float sc = p0[n], of = p1[n];
#pragma unroll
            for (int i = 0; i < 4; ++i) {
                size_t r = row0 + wr * 64 + i * 16 + kg * 4;
#pragma unroll
                for (int rg = 0; rg < 4; ++rg) {
                    float v = fmaxf(sc * acc[i][j][rg] + of, 0.f);
                    Hb[(r + rg) * (size_t)AHH + n] = f2b(v);
                }
            }
        }
    } else {
        float* Lb = (float*)Out;
#pragma unroll
        for (int j = 0; j < 4; ++j) {
            int n = col0 + wc * 64 + j * 16 + m16;
            float bi = p0[n];
#pragma unroll
            for (int i = 0; i < 4; ++i) {
                size_t r = row0 + wr * 64 + i * 16 + kg * 4;
#pragma unroll
                for (int rg = 0; rg < 4; ++rg)
                    Lb[(r + rg) * (size_t)DIMD + n] = acc[i][j][rg] + bi;
            }
        }
    }
}

// ---------------- K11: softmax over K + aggregation (per chunk) ----------------
__global__ __launch_bounds__(256) void softmax_agg_kernel(const int* __restrict__ idx,
                                                          const float* __restrict__ lbuf,
                                                          const ushort_t* __restrict__ sb16,
                                                          const float* __restrict__ qT,
                                                          const float* __restrict__ kT,
                                                          const float* __restrict__ vT,
                                                          float* __restrict__ aggT,
                                                          int pbase) {
    int p = pbase + blockIdx.x;      // global point id
    int b = p / NN, n = p % NN;
    int c = threadIdx.x;
    __shared__ int sm[KK];
    if (c < KK) sm[c] = idx[(size_t)p * KK + c];
    __syncthreads();
    const float* lrow = lbuf + (size_t)blockIdx.x * KK * DIMD + c;  // chunk-local
    float lg[KK];
#pragma unroll
    for (int s = 0; s < KK; ++s) lg[s] = lrow[(size_t)s * DIMD];
    float mx = lg[0];
#pragma unroll
    for (int s = 1; s < KK; ++s) mx = fmaxf(mx, lg[s]);
    float sum = 0.f;
#pragma unroll
    for (int s = 0; s < KK; ++s) { lg[s] = expf(lg[s] - mx); sum += lg[s]; }
    float inv = 1.f / sum;
    float q = qT[((size_t)b * NN + n) * DIMD + c];
    float vf = vT[((size_t)b * NN + n) * DIMD + c];
    const ushort_t* srow = sb16 + (size_t)p * KK * DIMD + c;
    float agg = 0.f;
#pragma unroll
    for (int s = 0; s < KK; ++s) {
        float kv = kT[((size_t)b * NN + sm[s]) * DIMD + c];
        float vv = vf + b2f(srow[(size_t)s * DIMD]) - q + kv;
        agg += lg[s] * inv * vv;
    }
    aggT[((size_t)b * NN + n) * DIMD + c] = agg;
}

// ---------------- K12: y = we·agg + be + identity (LDS-staged, coalesced) ----------------
__global__ __launch_bounds__(256) void final_kernel(const float* __restrict__ aggT,
                                                    const float* __restrict__ we,
                                                    const float* __restrict__ be,
                                                    const float* __restrict__ value,
                                                    float* __restrict__ out) {
    __shared__ float xs[2 * FPT][DIMD];   // 16 points x 256 ch = 16 KB
    int b = blockIdx.y;
    int n0 = blockIdx.x * (2 * FPT);
    int t = threadIdx.x;
    const float4* src = (const float4*)(aggT + ((size_t)b * NN + n0) * DIMD);
    float4* dst = (float4*)xs;
#pragma unroll
    for (int l = 0; l < (2 * FPT * DIMD / 4) / 256; ++l) dst[t + 256 * l] = src[t + 256 * l];
    __syncthreads();
    int o = t & 127, ph = t >> 7;
    float acc[FPT];
#pragma unroll
    for (int p = 0; p < FPT; ++p) acc[p] = 0.f;
    const float4* wr = (const float4*)(we + (size_t)o * DIMD);
#pragma unroll 8
    for (int i4 = 0; i4 < DIMD / 4; ++i4) {
        float4 w4 = wr[i4];
#pragma unroll
        for (int p = 0; p < FPT; ++p) {
            float4 x4 = *(const float4*)&xs[ph * FPT + p][i4 * 4];
            acc[p] += w4.x * x4.x + w4.y * x4.y + w4.z * x4.z + w4.w * x4.w;
        }
    }
    float bo = be[o];
#pragma unroll
    for (int p = 0; p < FPT; ++p) {
        size_t oi = ((size_t)b * CC + o) * NN + n0 + ph * FPT + p;
        out[oi] = acc[p] + bo + value[oi];
    }
}

extern "C" void kernel_launch(void* const* d_in, const int* in_sizes, int n_in,
                              void* d_out, int out_size, void* d_ws, size_t ws_size,
                              hipStream_t stream) {
    (void)in_sizes; (void)n_in; (void)out_size; (void)ws_size;
    const float* pos     = (const float*)d_in[0];
    const float* key     = (const float*)d_in[1];
    const float* query   = (const float*)d_in[2];
    const float* mlpv_w1 = (const float*)d_in[3];
    const float* mlpv_b1 = (const float*)d_in[4];
    const float* mlpv_w2 = (const float*)d_in[5];
    const float* mlpv_b2 = (const float*)d_in[6];
    const float* mlpv_ws = (const float*)d_in[7];
    const float* mlpv_bs = (const float*)d_in[8];
    const float* wk  = (const float*)d_in[9];
    const float* bk  = (const float*)d_in[10];
    const float* wq  = (const float*)d_in[11];
    const float* bq  = (const float*)d_in[12];
    const float* wv  = (const float*)d_in[13];
    const float* bv  = (const float*)d_in[14];
    const float* pw1 = (const float*)d_in[15];
    const float* pb1 = (const float*)d_in[16];
    const float* pg1 = (const float*)d_in[17];
    const float* pbe1= (const float*)d_in[18];
    const float* pw2 = (const float*)d_in[19];
    const float* pb2 = (const float*)d_in[20];
    const float* aw1 = (const float*)d_in[21];
    const float* ab1 = (const float*)d_in[22];
    const float* ag1 = (const float*)d_in[23];
    const float* abe1= (const float*)d_in[24];
    const float* aw2 = (const float*)d_in[25];
    const float* ab2 = (const float*)d_in[26];
    const float* we  = (const float*)d_in[27];
    const float* be  = (const float*)d_in[28];
    float* out = (float*)d_out;

    char* wsb = (char*)d_ws;
    size_t off = 0;
    auto alloc = [&](size_t bytes) {
        void* p = wsb + off;
        off += (bytes + 255) & ~(size_t)255;
        return p;
    };
    const size_t M = (size_t)BB * NN * KK;  // 131072 rows
    int*   idx   = (int*)  alloc(M * 4);
    float* h1buf = (float*)alloc((size_t)BB * CC * NN * 4);
    float* value = (float*)alloc((size_t)BB * CC * NN * 4);
    float* kT    = (float*)alloc((size_t)BB * NN * DIMD * 4);
    float* qT    = (float*)alloc((size_t)BB * NN * DIMD * 4);
    float* vT    = (float*)alloc((size_t)BB * NN * DIMD * 4);
    float* aggT  = (float*)alloc((size_t)BB * NN * DIMD * 4);
    float* zero0 = (float*)alloc((size_t)(16 + 256 + 65536) * 4);
    float* stats = zero0;
    float* mu    = zero0 + 16;
    float* R     = zero0 + 16 + 256;
    float* posA  = (float*)alloc((size_t)2 * PHH * 4);
    float* attA  = (float*)alloc((size_t)2 * AHH * 4);
    ushort_t* w1b = (ushort_t*)alloc((size_t)AHH * DIMD * 2);
    ushort_t* w2b = (ushort_t*)alloc((size_t)DIMD * AHH * 2);
    ushort_t* sb16 = (ushort_t*)alloc(M * DIMD * 2);          //  67 MB
    char* ovl = (char*)alloc((size_t)MCH * AHH * 2 + (size_t)MCH * DIMD * 4);
    float*    Rpart = (float*)ovl;
    ushort_t* Hbuf  = (ushort_t*)ovl;
    float*    lbuf  = (float*)(ovl + (size_t)MCH * AHH * 2);

    int ZN = 16 + 256 + 65536;
    zero_kernel<<<(ZN + 255) / 256, 256, 0, stream>>>(zero0, ZN);
    knn_kernel<<<BB * NN, 256, 0, stream>>>(pos, idx);
    h1_kernel<<<dim3(NN / 256, CC, BB), 256, 0, stream>>>(key, query, mlpv_w1, mlpv_b1, h1buf);
    value_kernel<<<dim3(NN / 256, CC, BB), 256, 0, stream>>>(key, query, h1buf, mlpv_w2, mlpv_b2, mlpv_ws, mlpv_bs, value);
    convT_kernel<<<dim3(NN / PT, BB), 256, 0, stream>>>(wk, bk, key, kT);
    convT_kernel<<<dim3(NN / PT, BB), 256, 0, stream>>>(wq, bq, query, qT);
    convT_kernel<<<dim3(NN / PT, BB), 256, 0, stream>>>(wv, bv, value, vT);
    pos_stats_kernel<<<BB * NN * KK / 256, 256, 0, stream>>>(pos, idx, stats);
    pos_bn_kernel<<<1, 64, 0, stream>>>(stats, pw1, pb1, pg1, pbe1, posA);
    posemb_s_kernel<<<BB * NN, 256, 0, stream>>>(pos, idx, pw1, pb1, posA, pw2, pb2, qT, kT, sb16);
    mu_kernel<<<M / 512, 256, 0, stream>>>(sb16, mu);
    rg_kernel<<<dim3(RSPLIT, 4), 256, 0, stream>>>(sb16, Rpart);
    r_reduce_kernel<<<DIMD * DIMD / 256, 256, 0, stream>>>(Rpart, R);
    attn_bn_kernel<<<AHH, DIMD, 0, stream>>>(R, mu, aw1, ab1, ag1, abe1, attA);
    cvt_w_kernel<<<(2 * AHH * DIMD) / 256, 256, 0, stream>>>(aw1, aw2, w1b, w2b);

    const int NCHUNK = (int)(M / MCH);
    for (int ch = 0; ch < NCHUNK; ++ch) {
        const ushort_t* Sc = sb16 + (size_t)ch * MCH * DIMD;
        gemm_kernel<DIMD, 0><<<dim3(MCH / 128, AHH / 128), 256, 0, stream>>>(Sc, w1b, attA, attA + AHH, Hbuf);
        gemm_kernel<AHH, 1><<<dim3(MCH / 128, DIMD / 128), 256, 0, stream>>>(Hbuf, w2b, ab2, nullptr, lbuf);
        softmax_agg_kernel<<<MCH / KK, 256, 0, stream>>>(idx, lbuf, sb16, qT, kT, vT, aggT, ch * (MCH / KK));
    }
    final_kernel<<<dim3(NN / (2 * FPT), BB), 256, 0, stream>>>(aggT, we, be, value, out);
}

// Round 7
// 1065.186 us; speedup vs baseline: 5.1953x; 1.1045x over previous
//
#include <hip/hip_runtime.h>
#include <math.h>

#define BB 2
#define CC 128
#define NN 4096
#define KK 16
#define DIMD 256
#define PHH 64
#define AHH 1024
#define EPSF 1e-5f
#define PT 16
#define MCH 16384   // M-chunk rows (1024 points x K)
#define RSPLIT 128
#define RKCH ((BB * NN * KK) / RSPLIT)   // 1024 samples per R block
#define LSTR 258    // LDS row stride (halfwords): conflict-free transposed gathers
#define KNN_CAP 512
#define FPT 8       // final_kernel points per thread

typedef unsigned short ushort_t;
typedef unsigned long long u64;
typedef __attribute__((ext_vector_type(8))) short short8;
typedef __attribute__((ext_vector_type(8))) unsigned short u16x8;
typedef __attribute__((ext_vector_type(2))) unsigned short u16x2;
typedef __attribute__((ext_vector_type(4))) float f32x4;

__device__ __forceinline__ ushort_t f2b(float x) {
    union { float f; unsigned u; } v; v.f = x;
    unsigned r = v.u + 0x7fff + ((v.u >> 16) & 1);
    return (ushort_t)(r >> 16);
}
__device__ __forceinline__ float b2f(ushort_t x) {
    union { unsigned u; float f; } v; v.u = ((unsigned)x) << 16;
    return v.f;
}
__device__ __forceinline__ unsigned fsort(float x) {
    union { float f; unsigned u; } v; v.f = x;
    return v.u ^ ((v.u >> 31) ? 0xFFFFFFFFu : 0x80000000u);
}

#define GLDS16(gp, lp) __builtin_amdgcn_global_load_lds( \
    (const __attribute__((address_space(1))) void*)(gp), \
    (__attribute__((address_space(3))) void*)(lp), 16, 0, 0)

// ---------------- K0: zero scratch accumulators ----------------
__global__ void zero_kernel(float* p, int n) {
    int i = blockIdx.x * blockDim.x + threadIdx.x;
    if (i < n) p[i] = 0.f;
}

// ---------------- K1: exact kNN via u64-key threshold select ----------------
__global__ __launch_bounds__(256) void knn_kernel(const float* __restrict__ pos,
                                                  int* __restrict__ idx) {
    int bid = blockIdx.x;
    int b = bid / NN, n = bid % NN;
    int t = threadIdx.x;
    int lane = t & 63, w = t >> 6;
    const float* px = pos + (size_t)b * 3 * NN;
    const float* py = px + NN;
    const float* pz = px + 2 * NN;
    float qx = px[n], qy = py[n], qz = pz[n];
    float qs = qx * qx + qy * qy + qz * qz;

    u64 keys[KK];
    u64 lmin = ~0ull;
#pragma unroll
    for (int j = 0; j < KK; ++j) {
        int m = t + 256 * j;
        float mx = px[m], my = py[m], mz = pz[m];
        float ms = mx * mx + my * my + mz * mz;
        float dt = qx * mx + qy * my + qz * mz;
        float d = qs + ms - 2.f * dt;
        u64 k = ((u64)fsort(d) << 32) | (unsigned)m;
        keys[j] = k;
        lmin = k < lmin ? k : lmin;
    }

    __shared__ u64 T0s[4];
    __shared__ u64 pool[KNN_CAP];
    __shared__ int cnt;

    u64 k = lmin, m4 = 0;
#pragma unroll
    for (int r = 0; r < 4; ++r) {
        u64 mv = k;
#pragma unroll
        for (int off = 32; off >= 1; off >>= 1) {
            u64 o = __shfl_xor(mv, off);
            mv = o < mv ? o : mv;
        }
        if (r == 3) m4 = mv;
        if (k == mv) k = ~0ull;
    }
    if (lane == 0) T0s[w] = m4;
    if (t == 0) cnt = 0;
    __syncthreads();
    u64 T0 = T0s[0];
    T0 = T0s[1] > T0 ? T0s[1] : T0;
    T0 = T0s[2] > T0 ? T0s[2] : T0;
    T0 = T0s[3] > T0 ? T0s[3] : T0;

#pragma unroll
    for (int j = 0; j < KK; ++j) {
        if (keys[j] <= T0) {
            int p = atomicAdd(&cnt, 1);
            if (p < KNN_CAP) pool[p] = keys[j];
        }
    }
    __syncthreads();
    int C = cnt < KNN_CAP ? cnt : KNN_CAP;
    if (t < C) {
        u64 me = pool[t];
        int r = 0;
        for (int i = 0; i < C; ++i) r += (pool[i] < me);
        if (r < KK) idx[(size_t)bid * KK + r] = (int)(me & 0xFFFFFFFFu);
    }
}

// ---------------- K2: h1 = relu(W1·[key;query] + b1) ----------------
__global__ __launch_bounds__(256) void h1_kernel(const float* __restrict__ key,
                                                 const float* __restrict__ query,
                                                 const float* __restrict__ w1,
                                                 const float* __restrict__ b1,
                                                 float* __restrict__ h1) {
    int n = blockIdx.x * 256 + threadIdx.x;
    int o = blockIdx.y, b = blockIdx.z;
    const float* wr = w1 + (size_t)o * 256;
    const float* kb = key + (size_t)b * CC * NN;
    const float* qb = query + (size_t)b * CC * NN;
    float acc = b1[o];
#pragma unroll 4
    for (int i = 0; i < CC; ++i) acc += wr[i] * kb[(size_t)i * NN + n];
#pragma unroll 4
    for (int i = 0; i < CC; ++i) acc += wr[CC + i] * qb[(size_t)i * NN + n];
    h1[((size_t)b * CC + o) * NN + n] = fmaxf(acc, 0.f);
}

// ---------------- K3: value = W2·h1 + b2 + Ws·[key;query] + bs ----------------
__global__ __launch_bounds__(256) void value_kernel(const float* __restrict__ key,
                                                    const float* __restrict__ query,
                                                    const float* __restrict__ h1buf,
                                                    const float* __restrict__ w2,
                                                    const float* __restrict__ b2,
                                                    const float* __restrict__ wsk,
                                                    const float* __restrict__ bs,
                                                    float* __restrict__ value) {
    int n = blockIdx.x * 256 + threadIdx.x;
    int o = blockIdx.y, b = blockIdx.z;
    const float* w2r = w2 + (size_t)o * CC;
    const float* wsr = wsk + (size_t)o * 256;
    const float* kb = key + (size_t)b * CC * NN;
    const float* qb = query + (size_t)b * CC * NN;
    const float* hb = h1buf + (size_t)b * CC * NN;
    float acc = b2[o] + bs[o];
#pragma unroll 4
    for (int i = 0; i < CC; ++i) acc += w2r[i] * hb[(size_t)i * NN + n];
#pragma unroll 4
    for (int i = 0; i < CC; ++i) acc += wsr[i] * kb[(size_t)i * NN + n];
#pragma unroll 4
    for (int i = 0; i < CC; ++i) acc += wsr[CC + i] * qb[(size_t)i * NN + n];
    value[((size_t)b * CC + o) * NN + n] = acc;
}

// ---------------- K4: outT[b][n][o] = bias[o] + W(256x128)·X[b,:,n] ----------------
__global__ __launch_bounds__(256) void convT_kernel(const float* __restrict__ W,
                                                    const float* __restrict__ bias,
                                                    const float* __restrict__ X,
                                                    float* __restrict__ outT) {
    __shared__ float xs[PT][CC + 1];
    int b = blockIdx.y;
    int n0 = blockIdx.x * PT;
    int t = threadIdx.x;
    for (int l = t; l < PT * CC; l += 256) {
        int p = l & (PT - 1); int i = l >> 4;
        xs[p][i] = X[((size_t)b * CC + i) * NN + n0 + p];
    }
    __syncthreads();
    int o = t;
    const float* wr = W + (size_t)o * CC;
    float acc[PT];
    float bo = bias[o];
#pragma unroll
    for (int p = 0; p < PT; ++p) acc[p] = bo;
    for (int i = 0; i < CC; ++i) {
        float w = wr[i];
#pragma unroll
        for (int p = 0; p < PT; ++p) acc[p] += w * xs[p][i];
    }
#pragma unroll
    for (int p = 0; p < PT; ++p)
        outT[((size_t)b * NN + n0 + p) * DIMD + o] = acc[p];
}

// ---------------- K5: pos_rel first/second moments (9 sums) ----------------
__global__ __launch_bounds__(256) void pos_stats_kernel(const float* __restrict__ pos,
                                                        const int* __restrict__ idx,
                                                        float* __restrict__ stats) {
    int sid = blockIdx.x * 256 + threadIdx.x;
    int b = sid / (NN * KK);
    int r = sid % (NN * KK);
    int n = r / KK;
    int m = idx[sid];
    const float* px = pos + (size_t)b * 3 * NN;
    float dx = px[n] - px[m];
    float dy = px[NN + n] - px[NN + m];
    float dz = px[2 * NN + n] - px[2 * NN + m];
    float v[9] = {dx, dy, dz, dx * dx, dy * dy, dz * dz, dx * dy, dx * dz, dy * dz};
    __shared__ float red[256];
    for (int j = 0; j < 9; ++j) {
        red[threadIdx.x] = v[j];
        __syncthreads();
        for (int off = 128; off >= 1; off >>= 1) {
            if (threadIdx.x < off) red[threadIdx.x] += red[threadIdx.x + off];
            __syncthreads();
        }
        if (threadIdx.x == 0) atomicAdd(&stats[j], red[0]);
        __syncthreads();
    }
}

// ---------------- K6: pos BN affine (a1, a0) per 64 channels ----------------
__global__ void pos_bn_kernel(const float* __restrict__ stats, const float* __restrict__ pw1,
                              const float* __restrict__ pb1, const float* __restrict__ pg1,
                              const float* __restrict__ pbe1, float* __restrict__ posA) {
    int c = threadIdx.x;
    if (c >= PHH) return;
    float M = (float)(BB * NN * KK);
    float mu0 = stats[0] / M, mu1 = stats[1] / M, mu2 = stats[2] / M;
    float E00 = stats[3] / M, E11 = stats[4] / M, E22 = stats[5] / M;
    float E01 = stats[6] / M, E02 = stats[7] / M, E12 = stats[8] / M;
    float w0 = pw1[c * 3], w1 = pw1[c * 3 + 1], w2 = pw1[c * 3 + 2];
    float wmu = w0 * mu0 + w1 * mu1 + w2 * mu2;
    float mean_h = wmu + pb1[c];
    float Eh2 = w0 * w0 * E00 + w1 * w1 * E11 + w2 * w2 * E22
              + 2.f * (w0 * w1 * E01 + w0 * w2 * E02 + w1 * w2 * E12)
              + 2.f * pb1[c] * wmu + pb1[c] * pb1[c];
    float var = Eh2 - mean_h * mean_h;
    float a1 = pg1[c] * rsqrtf(var + EPSF);
    posA[c] = a1;
    posA[PHH + c] = pbe1[c] - mean_h * a1;
}

// ---------------- K7a: P1 = relu(BNaffine(pw1 . pos_rel)) bf16 (M x 64) ----------------
__global__ __launch_bounds__(256) void p1_kernel(const float* __restrict__ pos,
                                                 const int* __restrict__ idx,
                                                 const float* __restrict__ pw1,
                                                 const float* __restrict__ pb1,
                                                 const float* __restrict__ posA,
                                                 ushort_t* __restrict__ p1) {
    int gid = blockIdx.x * 256 + threadIdx.x;
    int samp = gid >> 6, c = gid & 63;
    int p = samp >> 4;           // global point b*NN+n
    int b = p >> 12, n = p & (NN - 1);
    int m = idx[samp];
    const float* px = pos + (size_t)b * 3 * NN;
    float dx = px[n] - px[m];
    float dy = px[NN + n] - px[NN + m];
    float dz = px[2 * NN + n] - px[2 * NN + m];
    float h = pw1[c * 3] * dx + pw1[c * 3 + 1] * dy + pw1[c * 3 + 2] * dz + pb1[c];
    p1[gid] = f2b(fmaxf(h * posA[c] + posA[PHH + c], 0.f));
}

// ---------------- K8: mu = column sums of s ----------------
__global__ __launch_bounds__(256) void mu_kernel(const ushort_t* __restrict__ sb16,
                                                 float* __restrict__ mu) {
    int c = threadIdx.x;
    const ushort_t* p = sb16 + (size_t)blockIdx.x * 512 * DIMD + c;
    float acc = 0.f;
    for (int i = 0; i < 512; ++i) acc += b2f(p[(size_t)i * DIMD]);
    atomicAdd(&mu[c], acc);
}

// ---------------- K9: R partials via MFMA: Rpart[chunk] = S_chunk^T * S_chunk ----------
__global__ __launch_bounds__(256) void rg_kernel(const ushort_t* __restrict__ S,
                                                 float* __restrict__ Rpart) {
    __shared__ ushort_t ls[32 * LSTR];
    int t = threadIdx.x;
    int lane = t & 63, w = t >> 6;
    int wr = w >> 1, wc = w & 1;
    int ti = blockIdx.y >> 1, tj = blockIdx.y & 1;
    int m16 = lane & 15, kg = lane >> 4;
    size_t kbase = (size_t)blockIdx.x * RKCH;

    f32x4 acc[4][4];
#pragma unroll
    for (int i = 0; i < 4; ++i)
#pragma unroll
        for (int j = 0; j < 4; ++j) acc[i][j] = (f32x4){0.f, 0.f, 0.f, 0.f};

    int lm = t >> 3;
    int lc = (t & 7) * 32;
    const ushort_t* gS = S + (kbase + lm) * DIMD + lc;
    ushort_t* lp = ls + lm * LSTR + lc;

    for (int kt = 0; kt < RKCH / 32; ++kt) {
        const ushort_t* gp = gS + (size_t)kt * 32 * DIMD;
        u16x8 v0 = *(const u16x8*)(gp);
        u16x8 v1 = *(const u16x8*)(gp + 8);
        u16x8 v2 = *(const u16x8*)(gp + 16);
        u16x8 v3 = *(const u16x8*)(gp + 24);
        __syncthreads();
#pragma unroll
        for (int q = 0; q < 4; ++q) {
            *(u16x2*)(lp + 0 + 2 * q) = (u16x2){v0[2 * q], v0[2 * q + 1]};
            *(u16x2*)(lp + 8 + 2 * q) = (u16x2){v1[2 * q], v1[2 * q + 1]};
            *(u16x2*)(lp + 16 + 2 * q) = (u16x2){v2[2 * q], v2[2 * q + 1]};
            *(u16x2*)(lp + 24 + 2 * q) = (u16x2){v3[2 * q], v3[2 * q + 1]};
        }
        __syncthreads();
        short8 af[4], bf[4];
#pragma unroll
        for (int i = 0; i < 4; ++i) {
            int chA = ti * 128 + wr * 64 + i * 16 + m16;
            int chB = tj * 128 + wc * 64 + i * 16 + m16;
#pragma unroll
            for (int j = 0; j < 8; ++j) {
                int k = kg * 8 + j;
                af[i][j] = (short)ls[k * LSTR + chA];
                bf[i][j] = (short)ls[k * LSTR + chB];
            }
        }
#pragma unroll
        for (int i = 0; i < 4; ++i)
#pragma unroll
            for (int j = 0; j < 4; ++j)
                acc[i][j] = __builtin_amdgcn_mfma_f32_16x16x32_bf16(af[i], bf[j], acc[i][j], 0, 0, 0);
    }

    float* rp = Rpart + (size_t)blockIdx.x * (DIMD * DIMD);
#pragma unroll
    for (int i = 0; i < 4; ++i) {
        int r0 = ti * 128 + wr * 64 + i * 16 + kg * 4;
#pragma unroll
        for (int j = 0; j < 4; ++j) {
            int cn = tj * 128 + wc * 64 + j * 16 + m16;
#pragma unroll
            for (int rg = 0; rg < 4; ++rg)
                rp[(size_t)(r0 + rg) * DIMD + cn] = acc[i][j][rg];
        }
    }
}

// ---------------- K9b: reduce R partials ----------------
__global__ __launch_bounds__(256) void r_reduce_kernel(const float* __restrict__ Rpart,
                                                       float* __restrict__ R) {
    int e = blockIdx.x * 256 + threadIdx.x;
    float s = 0.f;
    for (int p = 0; p < RSPLIT; ++p) s += Rpart[(size_t)p * (DIMD * DIMD) + e];
    R[e] = s;
}

// ---------------- K10: attn BN -> fused scale/offset per hidden channel ----------------
__global__ __launch_bounds__(256) void attn_bn_kernel(const float* __restrict__ R,
                                                      const float* __restrict__ mu,
                                                      const float* __restrict__ aw1,
                                                      const float* __restrict__ ab1,
                                                      const float* __restrict__ ag1,
                                                      const float* __restrict__ abe1,
                                                      float* __restrict__ attA) {
    int c = blockIdx.x;
    int t = threadIdx.x;
    __shared__ float wsh[DIMD];
    __shared__ float red[DIMD];
    wsh[t] = aw1[(size_t)c * DIMD + t];
    __syncthreads();
    const float* Rr = R + (size_t)t * DIMD;
    float q = 0.f;
#pragma unroll 4
    for (int j = 0; j < DIMD; ++j) q += Rr[j] * wsh[j];
    red[t] = q * wsh[t];
    __syncthreads();
    for (int off = 128; off >= 1; off >>= 1) {
        if (t < off) red[t] += red[t + off];
        __syncthreads();
    }
    float wRw = red[0];
    __syncthreads();
    red[t] = wsh[t] * mu[t];
    __syncthreads();
    for (int off = 128; off >= 1; off >>= 1) {
        if (t < off) red[t] += red[t + off];
        __syncthreads();
    }
    if (t == 0) {
        float M = (float)(BB * NN * KK);
        float wmu = red[0] / M;
        float b1c = ab1[c];
        float Eh = wmu + b1c;
        float Eh2 = wRw / M + 2.f * b1c * wmu + b1c * b1c;
        float var = Eh2 - Eh * Eh;
        float a1 = ag1[c] * rsqrtf(var + EPSF);
        attA[c] = a1;
        attA[AHH + c] = a1 * b1c + abe1[c] - Eh * a1;
    }
}

// ---------------- K10b: convert W1, W2, pos_w2 to bf16 ----------------
__global__ void cvt_w_kernel(const float* __restrict__ aw1, const float* __restrict__ aw2,
                             const float* __restrict__ pw2,
                             ushort_t* __restrict__ w1b, ushort_t* __restrict__ w2b,
                             ushort_t* __restrict__ pw2b) {
    int i = blockIdx.x * 256 + threadIdx.x;
    if (i < AHH * DIMD) w1b[i] = f2b(aw1[i]);
    else if (i < 2 * AHH * DIMD) w2b[i - AHH * DIMD] = f2b(aw2[i - AHH * DIMD]);
    else {
        int j = i - 2 * AHH * DIMD;
        if (j < DIMD * PHH) pw2b[j] = f2b(pw2[j]);
    }
}

// ---------------- MFMA GEMM: C(M x N) = A(M x K) * B(N x K)^T, bf16 in fp32 acc ----
// EPI 0: out bf16 = relu(scale[n]*acc + off[n]), stride AHH
// EPI 1: out fp32 = acc + bias[n], stride DIMD
// EPI 2: out bf16 = qT[row/16][n] - kT[b*NN+idx[row]][n] + acc + bias[n], stride DIMD (s-build)
template <int KDIM, int EPI>
__global__ __launch_bounds__(256) void gemm_kernel(const ushort_t* __restrict__ A,
                                                   const ushort_t* __restrict__ Bm,
                                                   const float* __restrict__ p0,
                                                   const float* __restrict__ p1,
                                                   void* __restrict__ Out,
                                                   const float* __restrict__ qT,
                                                   const float* __restrict__ kT,
                                                   const int* __restrict__ gidx) {
    __shared__ ushort_t lA[128 * 32];
    __shared__ ushort_t lB[128 * 32];
    int t = threadIdx.x;
    int lane = t & 63, w = t >> 6;
    int wr = w >> 1, wc = w & 1;
    size_t row0 = (size_t)blockIdx.x * 128;
    int col0 = blockIdx.y * 128;
    int m16 = lane & 15, kg = lane >> 4;

    f32x4 acc[4][4];
#pragma unroll
    for (int i = 0; i < 4; ++i)
#pragma unroll
        for (int j = 0; j < 4; ++j) acc[i][j] = (f32x4){0.f, 0.f, 0.f, 0.f};

    const ushort_t* gA = A + (row0 + (size_t)w * 16 + m16) * KDIM + kg * 8;
    const ushort_t* gB = Bm + ((size_t)(col0 + w * 16 + m16)) * KDIM + kg * 8;
    ushort_t* lA0 = lA + w * 512;
    ushort_t* lB0 = lB + w * 512;

    for (int kt = 0; kt < KDIM / 32; ++kt) {
        int ko = kt * 32;
        GLDS16(gA + ko, lA0);
        GLDS16(gA + (size_t)64 * KDIM + ko, lA0 + 2048);
        GLDS16(gB + ko, lB0);
        GLDS16(gB + (size_t)64 * KDIM + ko, lB0 + 2048);
        __syncthreads();
        short8 af[4], bf[4];
#pragma unroll
        for (int i = 0; i < 4; ++i) {
            af[i] = *(const short8*)(lA + ((wr * 4 + i) * 512 + kg * 128 + m16 * 8));
            bf[i] = *(const short8*)(lB + ((wc * 4 + i) * 512 + kg * 128 + m16 * 8));
        }
#pragma unroll
        for (int i = 0; i < 4; ++i)
#pragma unroll
            for (int j = 0; j < 4; ++j)
                acc[i][j] = __builtin_amdgcn_mfma_f32_16x16x32_bf16(af[i], bf[j], acc[i][j], 0, 0, 0);
        __syncthreads();
    }

    if (EPI == 0) {
        ushort_t* Hb = (ushort_t*)Out;
#pragma unroll
        for (int j = 0; j < 4; ++j) {
            int n = col0 + wc * 64 + j * 16 + m16;
            float sc = p0[n], of = p1[n];
#pragma unroll
            for (int i = 0; i < 4; ++i) {
                size_t r = row0 + wr * 64 + i * 16 + kg * 4;
#pragma unroll
                for (int rg = 0; rg < 4; ++rg) {
                    float v = fmaxf(sc * acc[i][j][rg] + of, 0.f);
                    Hb[(r + rg) * (size_t)AHH + n] = f2b(v);
                }
            }
        }
    } else if (EPI == 1) {
        float* Lb = (float*)Out;
#pragma unroll
        for (int j = 0; j < 4; ++j) {
            int n = col0 + wc * 64 + j * 16 + m16;
            float bi = p0[n];
#pragma unroll
            for (int i = 0; i < 4; ++i) {
                size_t r = row0 + wr * 64 + i * 16 + kg * 4;
#pragma unroll
                for (int rg = 0; rg < 4; ++rg)
                    Lb[(r + rg) * (size_t)DIMD + n] = acc[i][j][rg] + bi;
            }
        }
    } else {
        ushort_t* Sb = (ushort_t*)Out;
        int nn[4]; float bi[4];
#pragma unroll
        for (int j = 0; j < 4; ++j) { nn[j] = col0 + wc * 64 + j * 16 + m16; bi[j] = p0[nn[j]]; }
#pragma unroll
        for (int i = 0; i < 4; ++i) {
            size_t r = row0 + wr * 64 + i * 16 + kg * 4;
#pragma unroll
            for (int rg = 0; rg < 4; ++rg) {
                size_t rr = r + rg;
                int p = (int)(rr >> 4);                 // global point b*NN+n
                int krow = (p & ~(NN - 1)) + gidx[rr];  // b*NN + neighbor
                const float* qrow = qT + (size_t)p * DIMD;
                const float* kro = kT + (size_t)krow * DIMD;
#pragma unroll
                for (int j = 0; j < 4; ++j) {
                    float sv = qrow[nn[j]] - kro[nn[j]] + acc[i][j][rg] + bi[j];
                    Sb[rr * (size_t)DIMD + nn[j]] = f2b(sv);
                }
            }
        }
    }
}

// ---------------- K11: softmax over K + aggregation (per chunk) ----------------
__global__ __launch_bounds__(256) void softmax_agg_kernel(const int* __restrict__ idx,
                                                          const float* __restrict__ lbuf,
                                                          const ushort_t* __restrict__ sb16,
                                                          const float* __restrict__ qT,
                                                          const float* __restrict__ kT,
                                                          const float* __restrict__ vT,
                                                          float* __restrict__ aggT,
                                                          int pbase) {
    int p = pbase + blockIdx.x;      // global point id
    int b = p / NN, n = p % NN;
    int c = threadIdx.x;
    __shared__ int sm[KK];
    if (c < KK) sm[c] = idx[(size_t)p * KK + c];
    __syncthreads();
    const float* lrow = lbuf + (size_t)blockIdx.x * KK * DIMD + c;  // chunk-local
    float lg[KK];
#pragma unroll
    for (int s = 0; s < KK; ++s) lg[s] = lrow[(size_t)s * DIMD];
    float mx = lg[0];
#pragma unroll
    for (int s = 1; s < KK; ++s) mx = fmaxf(mx, lg[s]);
    float sum = 0.f;
#pragma unroll
    for (int s = 0; s < KK; ++s) { lg[s] = expf(lg[s] - mx); sum += lg[s]; }
    float inv = 1.f / sum;
    float q = qT[((size_t)b * NN + n) * DIMD + c];
    float vf = vT[((size_t)b * NN + n) * DIMD + c];
    const ushort_t* srow = sb16 + (size_t)p * KK * DIMD + c;
    float agg = 0.f;
#pragma unroll
    for (int s = 0; s < KK; ++s) {
        float kv = kT[((size_t)b * NN + sm[s]) * DIMD + c];
        float vv = vf + b2f(srow[(size_t)s * DIMD]) - q + kv;
        agg += lg[s] * inv * vv;
    }
    aggT[((size_t)b * NN + n) * DIMD + c] = agg;
}

// ---------------- K12: y = we·agg + be + identity (LDS-staged, coalesced) ----------------
__global__ __launch_bounds__(256) void final_kernel(const float* __restrict__ aggT,
                                                    const float* __restrict__ we,
                                                    const float* __restrict__ be,
                                                    const float* __restrict__ value,
                                                    float* __restrict__ out) {
    __shared__ float xs[2 * FPT][DIMD];
    int b = blockIdx.y;
    int n0 = blockIdx.x * (2 * FPT);
    int t = threadIdx.x;
    const float4* src = (const float4*)(aggT + ((size_t)b * NN + n0) * DIMD);
    float4* dst = (float4*)xs;
#pragma unroll
    for (int l = 0; l < (2 * FPT * DIMD / 4) / 256; ++l) dst[t + 256 * l] = src[t + 256 * l];
    __syncthreads();
    int o = t & 127, ph = t >> 7;
    float acc[FPT];
#pragma unroll
    for (int p = 0; p < FPT; ++p) acc[p] = 0.f;
    const float4* wr = (const float4*)(we + (size_t)o * DIMD);
#pragma unroll 8
    for (int i4 = 0; i4 < DIMD / 4; ++i4) {
        float4 w4 = wr[i4];
#pragma unroll
        for (int p = 0; p < FPT; ++p) {
            float4 x4 = *(const float4*)&xs[ph * FPT + p][i4 * 4];
            acc[p] += w4.x * x4.x + w4.y * x4.y + w4.z * x4.z + w4.w * x4.w;
        }
    }
    float bo = be[o];
#pragma unroll
    for (int p = 0; p < FPT; ++p) {
        size_t oi = ((size_t)b * CC + o) * NN + n0 + ph * FPT + p;
        out[oi] = acc[p] + bo + value[oi];
    }
}

extern "C" void kernel_launch(void* const* d_in, const int* in_sizes, int n_in,
                              void* d_out, int out_size, void* d_ws, size_t ws_size,
                              hipStream_t stream) {
    (void)in_sizes; (void)n_in; (void)out_size; (void)ws_size;
    const float* pos     = (const float*)d_in[0];
    const float* key     = (const float*)d_in[1];
    const float* query   = (const float*)d_in[2];
    const float* mlpv_w1 = (const float*)d_in[3];
    const float* mlpv_b1 = (const float*)d_in[4];
    const float* mlpv_w2 = (const float*)d_in[5];
    const float* mlpv_b2 = (const float*)d_in[6];
    const float* mlpv_ws = (const float*)d_in[7];
    const float* mlpv_bs = (const float*)d_in[8];
    const float* wk  = (const float*)d_in[9];
    const float* bk  = (const float*)d_in[10];
    const float* wq  = (const float*)d_in[11];
    const float* bq  = (const float*)d_in[12];
    const float* wv  = (const float*)d_in[13];
    const float* bv  = (const float*)d_in[14];
    const float* pw1 = (const float*)d_in[15];
    const float* pb1 = (const float*)d_in[16];
    const float* pg1 = (const float*)d_in[17];
    const float* pbe1= (const float*)d_in[18];
    const float* pw2 = (const float*)d_in[19];
    const float* pb2 = (const float*)d_in[20];
    const float* aw1 = (const float*)d_in[21];
    const float* ab1 = (const float*)d_in[22];
    const float* ag1 = (const float*)d_in[23];
    const float* abe1= (const float*)d_in[24];
    const float* aw2 = (const float*)d_in[25];
    const float* ab2 = (const float*)d_in[26];
    const float* we  = (const float*)d_in[27];
    const float* be  = (const float*)d_in[28];
    float* out = (float*)d_out;

    char* wsb = (char*)d_ws;
    size_t off = 0;
    auto alloc = [&](size_t bytes) {
        void* p = wsb + off;
        off += (bytes + 255) & ~(size_t)255;
        return p;
    };
    const size_t M = (size_t)BB * NN * KK;  // 131072 rows
    int*   idx   = (int*)  alloc(M * 4);
    float* h1buf = (float*)alloc((size_t)BB * CC * NN * 4);
    float* value = (float*)alloc((size_t)BB * CC * NN * 4);
    float* kT    = (float*)alloc((size_t)BB * NN * DIMD * 4);
    float* qT    = (float*)alloc((size_t)BB * NN * DIMD * 4);
    float* vT    = (float*)alloc((size_t)BB * NN * DIMD * 4);
    float* aggT  = (float*)alloc((size_t)BB * NN * DIMD * 4);
    float* zero0 = (float*)alloc((size_t)(16 + 256 + 65536) * 4);
    float* stats = zero0;
    float* mu    = zero0 + 16;
    float* R     = zero0 + 16 + 256;
    float* posA  = (float*)alloc((size_t)2 * PHH * 4);
    float* attA  = (float*)alloc((size_t)2 * AHH * 4);
    ushort_t* w1b = (ushort_t*)alloc((size_t)AHH * DIMD * 2);
    ushort_t* w2b = (ushort_t*)alloc((size_t)DIMD * AHH * 2);
    ushort_t* pw2b = (ushort_t*)alloc((size_t)DIMD * PHH * 2);
    ushort_t* sb16 = (ushort_t*)alloc(M * DIMD * 2);          //  67 MB
    // overlay: [Rpart | p1] before chunk loop, [Hbuf | lbuf] during chunk loop
    char* ovl = (char*)alloc((size_t)MCH * AHH * 2 + (size_t)MCH * DIMD * 4);
    float*    Rpart = (float*)ovl;                             // 33.5 MB
    ushort_t* Hbuf  = (ushort_t*)ovl;                          // 33.5 MB
    ushort_t* p1buf = (ushort_t*)(ovl + (size_t)MCH * AHH * 2);// 16.8 MB (= lbuf slot)
    float*    lbuf  = (float*)(ovl + (size_t)MCH * AHH * 2);   // 16.8 MB

    int ZN = 16 + 256 + 65536;
    zero_kernel<<<(ZN + 255) / 256, 256, 0, stream>>>(zero0, ZN);
    knn_kernel<<<BB * NN, 256, 0, stream>>>(pos, idx);
    h1_kernel<<<dim3(NN / 256, CC, BB), 256, 0, stream>>>(key, query, mlpv_w1, mlpv_b1, h1buf);
    value_kernel<<<dim3(NN / 256, CC, BB), 256, 0, stream>>>(key, query, h1buf, mlpv_w2, mlpv_b2, mlpv_ws, mlpv_bs, value);
    convT_kernel<<<dim3(NN / PT, BB), 256, 0, stream>>>(wk, bk, key, kT);
    convT_kernel<<<dim3(NN / PT, BB), 256, 0, stream>>>(wq, bq, query, qT);
    convT_kernel<<<dim3(NN / PT, BB), 256, 0, stream>>>(wv, bv, value, vT);
    pos_stats_kernel<<<BB * NN * KK / 256, 256, 0, stream>>>(pos, idx, stats);
    pos_bn_kernel<<<1, 64, 0, stream>>>(stats, pw1, pb1, pg1, pbe1, posA);
    cvt_w_kernel<<<(2 * AHH * DIMD + DIMD * PHH + 255) / 256, 256, 0, stream>>>(aw1, aw2, pw2, w1b, w2b, pw2b);
    // P1 (M x 64 bf16), then s = q - k_g + (P1 . pw2^T + pb2) via MFMA GEMM (K=64)
    p1_kernel<<<(int)(M * PHH / 256), 256, 0, stream>>>(pos, idx, pw1, pb1, posA, p1buf);
    gemm_kernel<PHH, 2><<<dim3(M / 128, DIMD / 128), 256, 0, stream>>>(p1buf, pw2b, pb2, nullptr, sb16, qT, kT, idx);
    mu_kernel<<<M / 512, 256, 0, stream>>>(sb16, mu);
    rg_kernel<<<dim3(RSPLIT, 4), 256, 0, stream>>>(sb16, Rpart);
    r_reduce_kernel<<<DIMD * DIMD / 256, 256, 0, stream>>>(Rpart, R);
    attn_bn_kernel<<<AHH, DIMD, 0, stream>>>(R, mu, aw1, ab1, ag1, abe1, attA);

    const int NCHUNK = (int)(M / MCH);
    for (int ch = 0; ch < NCHUNK; ++ch) {
        const ushort_t* Sc = sb16 + (size_t)ch * MCH * DIMD;
        gemm_kernel<DIMD, 0><<<dim3(MCH / 128, AHH / 128), 256, 0, stream>>>(Sc, w1b, attA, attA + AHH, Hbuf, nullptr, nullptr, nullptr);
        gemm_kernel<AHH, 1><<<dim3(MCH / 128, DIMD / 128), 256, 0, stream>>>(Hbuf, w2b, ab2, nullptr, lbuf, nullptr, nullptr, nullptr);
        softmax_agg_kernel<<<MCH / KK, 256, 0, stream>>>(idx, lbuf, sb16, qT, kT, vT, aggT, ch * (MCH / KK));
    }
    final_kernel<<<dim3(NN / (2 * FPT), BB), 256, 0, stream>>>(aggT, we, be, value, out);
}

// Round 8
// 880.814 us; speedup vs baseline: 6.2828x; 1.2093x over previous
//
#include <hip/hip_runtime.h>
#include <math.h>

#define BB 2
#define CC 128
#define NN 4096
#define KK 16
#define DIMD 256
#define PHH 64
#define AHH 1024
#define EPSF 1e-5f
#define PT 16
#define RSPLIT 128
#define RKCH ((BB * NN * KK) / RSPLIT)   // 1024 samples per R block
#define LSTR 258    // LDS row stride (halfwords): conflict-free transposed gathers
#define KNN_CAP 512
#define FPT 8       // final_kernel points per thread

typedef unsigned short ushort_t;
typedef unsigned long long u64;
typedef __attribute__((ext_vector_type(8))) short short8;
typedef __attribute__((ext_vector_type(8))) unsigned short u16x8;
typedef __attribute__((ext_vector_type(4))) unsigned short u16x4;
typedef __attribute__((ext_vector_type(2))) unsigned short u16x2;
typedef __attribute__((ext_vector_type(4))) float f32x4;

__device__ __forceinline__ ushort_t f2b(float x) {
    union { float f; unsigned u; } v; v.f = x;
    unsigned r = v.u + 0x7fff + ((v.u >> 16) & 1);
    return (ushort_t)(r >> 16);
}
__device__ __forceinline__ float b2f(ushort_t x) {
    union { unsigned u; float f; } v; v.u = ((unsigned)x) << 16;
    return v.f;
}
__device__ __forceinline__ unsigned fsort(float x) {
    union { float f; unsigned u; } v; v.f = x;
    return v.u ^ ((v.u >> 31) ? 0xFFFFFFFFu : 0x80000000u);
}

#define GLDS16(gp, lp) __builtin_amdgcn_global_load_lds( \
    (const __attribute__((address_space(1))) void*)(gp), \
    (__attribute__((address_space(3))) void*)(lp), 16, 0, 0)

// ---------------- K0: zero scratch accumulators ----------------
__global__ void zero_kernel(float* p, int n) {
    int i = blockIdx.x * blockDim.x + threadIdx.x;
    if (i < n) p[i] = 0.f;
}

// ---------------- K1: exact kNN via u64-key threshold select ----------------
__global__ __launch_bounds__(256) void knn_kernel(const float* __restrict__ pos,
                                                  int* __restrict__ idx) {
    int bid = blockIdx.x;
    int b = bid / NN, n = bid % NN;
    int t = threadIdx.x;
    int lane = t & 63, w = t >> 6;
    const float* px = pos + (size_t)b * 3 * NN;
    const float* py = px + NN;
    const float* pz = px + 2 * NN;
    float qx = px[n], qy = py[n], qz = pz[n];
    float qs = qx * qx + qy * qy + qz * qz;

    u64 keys[KK];
    u64 lmin = ~0ull;
#pragma unroll
    for (int j = 0; j < KK; ++j) {
        int m = t + 256 * j;
        float mx = px[m], my = py[m], mz = pz[m];
        float ms = mx * mx + my * my + mz * mz;
        float dt = qx * mx + qy * my + qz * mz;
        float d = qs + ms - 2.f * dt;
        u64 k = ((u64)fsort(d) << 32) | (unsigned)m;
        keys[j] = k;
        lmin = k < lmin ? k : lmin;
    }

    __shared__ u64 T0s[4];
    __shared__ u64 pool[KNN_CAP];
    __shared__ int cnt;

    u64 k = lmin, m4 = 0;
#pragma unroll
    for (int r = 0; r < 4; ++r) {
        u64 mv = k;
#pragma unroll
        for (int off = 32; off >= 1; off >>= 1) {
            u64 o = __shfl_xor(mv, off);
            mv = o < mv ? o : mv;
        }
        if (r == 3) m4 = mv;
        if (k == mv) k = ~0ull;
    }
    if (lane == 0) T0s[w] = m4;
    if (t == 0) cnt = 0;
    __syncthreads();
    u64 T0 = T0s[0];
    T0 = T0s[1] > T0 ? T0s[1] : T0;
    T0 = T0s[2] > T0 ? T0s[2] : T0;
    T0 = T0s[3] > T0 ? T0s[3] : T0;

#pragma unroll
    for (int j = 0; j < KK; ++j) {
        if (keys[j] <= T0) {
            int p = atomicAdd(&cnt, 1);
            if (p < KNN_CAP) pool[p] = keys[j];
        }
    }
    __syncthreads();
    int C = cnt < KNN_CAP ? cnt : KNN_CAP;
    if (t < C) {
        u64 me = pool[t];
        int r = 0;
        for (int i = 0; i < C; ++i) r += (pool[i] < me);
        if (r < KK) idx[(size_t)bid * KK + r] = (int)(me & 0xFFFFFFFFu);
    }
}

// ---------------- K2: h1 = relu(W1·[key;query] + b1) ----------------
__global__ __launch_bounds__(256) void h1_kernel(const float* __restrict__ key,
                                                 const float* __restrict__ query,
                                                 const float* __restrict__ w1,
                                                 const float* __restrict__ b1,
                                                 float* __restrict__ h1) {
    int n = blockIdx.x * 256 + threadIdx.x;
    int o = blockIdx.y, b = blockIdx.z;
    const float* wr = w1 + (size_t)o * 256;
    const float* kb = key + (size_t)b * CC * NN;
    const float* qb = query + (size_t)b * CC * NN;
    float acc = b1[o];
#pragma unroll 4
    for (int i = 0; i < CC; ++i) acc += wr[i] * kb[(size_t)i * NN + n];
#pragma unroll 4
    for (int i = 0; i < CC; ++i) acc += wr[CC + i] * qb[(size_t)i * NN + n];
    h1[((size_t)b * CC + o) * NN + n] = fmaxf(acc, 0.f);
}

// ---------------- K3: value = W2·h1 + b2 + Ws·[key;query] + bs ----------------
__global__ __launch_bounds__(256) void value_kernel(const float* __restrict__ key,
                                                    const float* __restrict__ query,
                                                    const float* __restrict__ h1buf,
                                                    const float* __restrict__ w2,
                                                    const float* __restrict__ b2,
                                                    const float* __restrict__ wsk,
                                                    const float* __restrict__ bs,
                                                    float* __restrict__ value) {
    int n = blockIdx.x * 256 + threadIdx.x;
    int o = blockIdx.y, b = blockIdx.z;
    const float* w2r = w2 + (size_t)o * CC;
    const float* wsr = wsk + (size_t)o * 256;
    const float* kb = key + (size_t)b * CC * NN;
    const float* qb = query + (size_t)b * CC * NN;
    const float* hb = h1buf + (size_t)b * CC * NN;
    float acc = b2[o] + bs[o];
#pragma unroll 4
    for (int i = 0; i < CC; ++i) acc += w2r[i] * hb[(size_t)i * NN + n];
#pragma unroll 4
    for (int i = 0; i < CC; ++i) acc += wsr[i] * kb[(size_t)i * NN + n];
#pragma unroll 4
    for (int i = 0; i < CC; ++i) acc += wsr[CC + i] * qb[(size_t)i * NN + n];
    value[((size_t)b * CC + o) * NN + n] = acc;
}

// ---------------- K4: outT[b][n][o] = bias[o] + W(256x128)·X[b,:,n] ----------------
__global__ __launch_bounds__(256) void convT_kernel(const float* __restrict__ W,
                                                    const float* __restrict__ bias,
                                                    const float* __restrict__ X,
                                                    float* __restrict__ outT) {
    __shared__ float xs[PT][CC + 1];
    int b = blockIdx.y;
    int n0 = blockIdx.x * PT;
    int t = threadIdx.x;
    for (int l = t; l < PT * CC; l += 256) {
        int p = l & (PT - 1); int i = l >> 4;
        xs[p][i] = X[((size_t)b * CC + i) * NN + n0 + p];
    }
    __syncthreads();
    int o = t;
    const float* wr = W + (size_t)o * CC;
    float acc[PT];
    float bo = bias[o];
#pragma unroll
    for (int p = 0; p < PT; ++p) acc[p] = bo;
    for (int i = 0; i < CC; ++i) {
        float w = wr[i];
#pragma unroll
        for (int p = 0; p < PT; ++p) acc[p] += w * xs[p][i];
    }
#pragma unroll
    for (int p = 0; p < PT; ++p)
        outT[((size_t)b * NN + n0 + p) * DIMD + o] = acc[p];
}

// ---------------- K5: pos_rel first/second moments (9 sums) ----------------
__global__ __launch_bounds__(256) void pos_stats_kernel(const float* __restrict__ pos,
                                                        const int* __restrict__ idx,
                                                        float* __restrict__ stats) {
    int sid = blockIdx.x * 256 + threadIdx.x;
    int b = sid / (NN * KK);
    int r = sid % (NN * KK);
    int n = r / KK;
    int m = idx[sid];
    const float* px = pos + (size_t)b * 3 * NN;
    float dx = px[n] - px[m];
    float dy = px[NN + n] - px[NN + m];
    float dz = px[2 * NN + n] - px[2 * NN + m];
    float v[9] = {dx, dy, dz, dx * dx, dy * dy, dz * dz, dx * dy, dx * dz, dy * dz};
    __shared__ float red[256];
    for (int j = 0; j < 9; ++j) {
        red[threadIdx.x] = v[j];
        __syncthreads();
        for (int off = 128; off >= 1; off >>= 1) {
            if (threadIdx.x < off) red[threadIdx.x] += red[threadIdx.x + off];
            __syncthreads();
        }
        if (threadIdx.x == 0) atomicAdd(&stats[j], red[0]);
        __syncthreads();
    }
}

// ---------------- K6: pos BN affine (a1, a0) per 64 channels ----------------
__global__ void pos_bn_kernel(const float* __restrict__ stats, const float* __restrict__ pw1,
                              const float* __restrict__ pb1, const float* __restrict__ pg1,
                              const float* __restrict__ pbe1, float* __restrict__ posA) {
    int c = threadIdx.x;
    if (c >= PHH) return;
    float M = (float)(BB * NN * KK);
    float mu0 = stats[0] / M, mu1 = stats[1] / M, mu2 = stats[2] / M;
    float E00 = stats[3] / M, E11 = stats[4] / M, E22 = stats[5] / M;
    float E01 = stats[6] / M, E02 = stats[7] / M, E12 = stats[8] / M;
    float w0 = pw1[c * 3], w1 = pw1[c * 3 + 1], w2 = pw1[c * 3 + 2];
    float wmu = w0 * mu0 + w1 * mu1 + w2 * mu2;
    float mean_h = wmu + pb1[c];
    float Eh2 = w0 * w0 * E00 + w1 * w1 * E11 + w2 * w2 * E22
              + 2.f * (w0 * w1 * E01 + w0 * w2 * E02 + w1 * w2 * E12)
              + 2.f * pb1[c] * wmu + pb1[c] * pb1[c];
    float var = Eh2 - mean_h * mean_h;
    float a1 = pg1[c] * rsqrtf(var + EPSF);
    posA[c] = a1;
    posA[PHH + c] = pbe1[c] - mean_h * a1;
}

// ---------------- K7a: P1 = relu(BNaffine(pw1 . pos_rel)) bf16 (M x 64) ----------------
__global__ __launch_bounds__(256) void p1_kernel(const float* __restrict__ pos,
                                                 const int* __restrict__ idx,
                                                 const float* __restrict__ pw1,
                                                 const float* __restrict__ pb1,
                                                 const float* __restrict__ posA,
                                                 ushort_t* __restrict__ p1) {
    int gid = blockIdx.x * 256 + threadIdx.x;
    int samp = gid >> 6, c = gid & 63;
    int p = samp >> 4;           // global point b*NN+n
    int b = p >> 12, n = p & (NN - 1);
    int m = idx[samp];
    const float* px = pos + (size_t)b * 3 * NN;
    float dx = px[n] - px[m];
    float dy = px[NN + n] - px[NN + m];
    float dz = px[2 * NN + n] - px[2 * NN + m];
    float h = pw1[c * 3] * dx + pw1[c * 3 + 1] * dy + pw1[c * 3 + 2] * dz + pb1[c];
    p1[gid] = f2b(fmaxf(h * posA[c] + posA[PHH + c], 0.f));
}

// ---------------- K8: mu = column sums of s ----------------
__global__ __launch_bounds__(256) void mu_kernel(const ushort_t* __restrict__ sb16,
                                                 float* __restrict__ mu) {
    int c = threadIdx.x;
    const ushort_t* p = sb16 + (size_t)blockIdx.x * 512 * DIMD + c;
    float acc = 0.f;
    for (int i = 0; i < 512; ++i) acc += b2f(p[(size_t)i * DIMD]);
    atomicAdd(&mu[c], acc);
}

// ---------------- K9: R partials via MFMA: Rpart[chunk] = S_chunk^T * S_chunk ----------
__global__ __launch_bounds__(256) void rg_kernel(const ushort_t* __restrict__ S,
                                                 float* __restrict__ Rpart) {
    __shared__ ushort_t ls[32 * LSTR];
    int t = threadIdx.x;
    int lane = t & 63, w = t >> 6;
    int wr = w >> 1, wc = w & 1;
    int ti = blockIdx.y >> 1, tj = blockIdx.y & 1;
    int m16 = lane & 15, kg = lane >> 4;
    size_t kbase = (size_t)blockIdx.x * RKCH;

    f32x4 acc[4][4];
#pragma unroll
    for (int i = 0; i < 4; ++i)
#pragma unroll
        for (int j = 0; j < 4; ++j) acc[i][j] = (f32x4){0.f, 0.f, 0.f, 0.f};

    int lm = t >> 3;
    int lc = (t & 7) * 32;
    const ushort_t* gS = S + (kbase + lm) * DIMD + lc;
    ushort_t* lp = ls + lm * LSTR + lc;

    for (int kt = 0; kt < RKCH / 32; ++kt) {
        const ushort_t* gp = gS + (size_t)kt * 32 * DIMD;
        u16x8 v0 = *(const u16x8*)(gp);
        u16x8 v1 = *(const u16x8*)(gp + 8);
        u16x8 v2 = *(const u16x8*)(gp + 16);
        u16x8 v3 = *(const u16x8*)(gp + 24);
        __syncthreads();
#pragma unroll
        for (int q = 0; q < 4; ++q) {
            *(u16x2*)(lp + 0 + 2 * q) = (u16x2){v0[2 * q], v0[2 * q + 1]};
            *(u16x2*)(lp + 8 + 2 * q) = (u16x2){v1[2 * q], v1[2 * q + 1]};
            *(u16x2*)(lp + 16 + 2 * q) = (u16x2){v2[2 * q], v2[2 * q + 1]};
            *(u16x2*)(lp + 24 + 2 * q) = (u16x2){v3[2 * q], v3[2 * q + 1]};
        }
        __syncthreads();
        short8 af[4], bf[4];
#pragma unroll
        for (int i = 0; i < 4; ++i) {
            int chA = ti * 128 + wr * 64 + i * 16 + m16;
            int chB = tj * 128 + wc * 64 + i * 16 + m16;
#pragma unroll
            for (int j = 0; j < 8; ++j) {
                int k = kg * 8 + j;
                af[i][j] = (short)ls[k * LSTR + chA];
                bf[i][j] = (short)ls[k * LSTR + chB];
            }
        }
#pragma unroll
        for (int i = 0; i < 4; ++i)
#pragma unroll
            for (int j = 0; j < 4; ++j)
                acc[i][j] = __builtin_amdgcn_mfma_f32_16x16x32_bf16(af[i], bf[j], acc[i][j], 0, 0, 0);
    }

    float* rp = Rpart + (size_t)blockIdx.x * (DIMD * DIMD);
#pragma unroll
    for (int i = 0; i < 4; ++i) {
        int r0 = ti * 128 + wr * 64 + i * 16 + kg * 4;
#pragma unroll
        for (int j = 0; j < 4; ++j) {
            int cn = tj * 128 + wc * 64 + j * 16 + m16;
#pragma unroll
            for (int rg = 0; rg < 4; ++rg)
                rp[(size_t)(r0 + rg) * DIMD + cn] = acc[i][j][rg];
        }
    }
}

// ---------------- K9b: reduce R partials ----------------
__global__ __launch_bounds__(256) void r_reduce_kernel(const float* __restrict__ Rpart,
                                                       float* __restrict__ R) {
    int e = blockIdx.x * 256 + threadIdx.x;
    float s = 0.f;
    for (int p = 0; p < RSPLIT; ++p) s += Rpart[(size_t)p * (DIMD * DIMD) + e];
    R[e] = s;
}

// ---------------- K10: attn BN -> fused scale/offset per hidden channel ----------------
__global__ __launch_bounds__(256) void attn_bn_kernel(const float* __restrict__ R,
                                                      const float* __restrict__ mu,
                                                      const float* __restrict__ aw1,
                                                      const float* __restrict__ ab1,
                                                      const float* __restrict__ ag1,
                                                      const float* __restrict__ abe1,
                                                      float* __restrict__ attA) {
    int c = blockIdx.x;
    int t = threadIdx.x;
    __shared__ float wsh[DIMD];
    __shared__ float red[DIMD];
    wsh[t] = aw1[(size_t)c * DIMD + t];
    __syncthreads();
    const float* Rr = R + (size_t)t * DIMD;
    float q = 0.f;
#pragma unroll 4
    for (int j = 0; j < DIMD; ++j) q += Rr[j] * wsh[j];
    red[t] = q * wsh[t];
    __syncthreads();
    for (int off = 128; off >= 1; off >>= 1) {
        if (t < off) red[t] += red[t + off];
        __syncthreads();
    }
    float wRw = red[0];
    __syncthreads();
    red[t] = wsh[t] * mu[t];
    __syncthreads();
    for (int off = 128; off >= 1; off >>= 1) {
        if (t < off) red[t] += red[t + off];
        __syncthreads();
    }
    if (t == 0) {
        float M = (float)(BB * NN * KK);
        float wmu = red[0] / M;
        float b1c = ab1[c];
        float Eh = wmu + b1c;
        float Eh2 = wRw / M + 2.f * b1c * wmu + b1c * b1c;
        float var = Eh2 - Eh * Eh;
        float a1 = ag1[c] * rsqrtf(var + EPSF);
        attA[c] = a1;
        attA[AHH + c] = a1 * b1c + abe1[c] - Eh * a1;
    }
}

// ---------------- K10b: convert W1, W2, pos_w2 to bf16 ----------------
__global__ void cvt_w_kernel(const float* __restrict__ aw1, const float* __restrict__ aw2,
                             const float* __restrict__ pw2,
                             ushort_t* __restrict__ w1b, ushort_t* __restrict__ w2b,
                             ushort_t* __restrict__ pw2b) {
    int i = blockIdx.x * 256 + threadIdx.x;
    if (i < AHH * DIMD) w1b[i] = f2b(aw1[i]);
    else if (i < 2 * AHH * DIMD) w2b[i - AHH * DIMD] = f2b(aw2[i - AHH * DIMD]);
    else {
        int j = i - 2 * AHH * DIMD;
        if (j < DIMD * PHH) pw2b[j] = f2b(pw2[j]);
    }
}

// ---------------- MFMA GEMM (s-build only): C = A(MxK)·B(NxK)^T, EPI 2 ----------------
template <int KDIM>
__global__ __launch_bounds__(256) void gemmS_kernel(const ushort_t* __restrict__ A,
                                                    const ushort_t* __restrict__ Bm,
                                                    const float* __restrict__ p0,
                                                    ushort_t* __restrict__ Sb,
                                                    const float* __restrict__ qT,
                                                    const float* __restrict__ kT,
                                                    const int* __restrict__ gidx) {
    __shared__ ushort_t lA[128 * 32];
    __shared__ ushort_t lB[128 * 32];
    int t = threadIdx.x;
    int lane = t & 63, w = t >> 6;
    int wr = w >> 1, wc = w & 1;
    size_t row0 = (size_t)blockIdx.x * 128;
    int col0 = blockIdx.y * 128;
    int m16 = lane & 15, kg = lane >> 4;

    f32x4 acc[4][4];
#pragma unroll
    for (int i = 0; i < 4; ++i)
#pragma unroll
        for (int j = 0; j < 4; ++j) acc[i][j] = (f32x4){0.f, 0.f, 0.f, 0.f};

    const ushort_t* gA = A + (row0 + (size_t)w * 16 + m16) * KDIM + kg * 8;
    const ushort_t* gB = Bm + ((size_t)(col0 + w * 16 + m16)) * KDIM + kg * 8;
    ushort_t* lA0 = lA + w * 512;
    ushort_t* lB0 = lB + w * 512;

    for (int kt = 0; kt < KDIM / 32; ++kt) {
        int ko = kt * 32;
        GLDS16(gA + ko, lA0);
        GLDS16(gA + (size_t)64 * KDIM + ko, lA0 + 2048);
        GLDS16(gB + ko, lB0);
        GLDS16(gB + (size_t)64 * KDIM + ko, lB0 + 2048);
        __syncthreads();
        short8 af[4], bf[4];
#pragma unroll
        for (int i = 0; i < 4; ++i) {
            af[i] = *(const short8*)(lA + ((wr * 4 + i) * 512 + kg * 128 + m16 * 8));
            bf[i] = *(const short8*)(lB + ((wc * 4 + i) * 512 + kg * 128 + m16 * 8));
        }
#pragma unroll
        for (int i = 0; i < 4; ++i)
#pragma unroll
            for (int j = 0; j < 4; ++j)
                acc[i][j] = __builtin_amdgcn_mfma_f32_16x16x32_bf16(af[i], bf[j], acc[i][j], 0, 0, 0);
        __syncthreads();
    }

    int nn[4]; float bi[4];
#pragma unroll
    for (int j = 0; j < 4; ++j) { nn[j] = col0 + wc * 64 + j * 16 + m16; bi[j] = p0[nn[j]]; }
#pragma unroll
    for (int i = 0; i < 4; ++i) {
        size_t r = row0 + wr * 64 + i * 16 + kg * 4;
#pragma unroll
        for (int rg = 0; rg < 4; ++rg) {
            size_t rr = r + rg;
            int p = (int)(rr >> 4);
            int krow = (p & ~(NN - 1)) + gidx[rr];
            const float* qrow = qT + (size_t)p * DIMD;
            const float* kro = kT + (size_t)krow * DIMD;
#pragma unroll
            for (int j = 0; j < 4; ++j) {
                float sv = qrow[nn[j]] - kro[nn[j]] + acc[i][j][rg] + bi[j];
                Sb[rr * (size_t)DIMD + nn[j]] = f2b(sv);
            }
        }
    }
}

// ---------------- K11: fused attn MLP (GEMM1+GEMM2) + softmax + aggregation --------
// Block = 64 samples (4 points), 256 threads (4 waves).
// GEMM1: Ht^T[128 hid][64 smp] = W1c . S^T (per jc chunk of 128 hidden)
// GEMM2: logits^T[256 out][64 smp] += W2c . Ht^T   (acc in VGPRs)
// Epilogue: softmax over the 16 m16-lanes (= neighbors of a point) + aggregation.
__global__ __launch_bounds__(256) void fused_mlp_kernel(const ushort_t* __restrict__ S,
                                                        const ushort_t* __restrict__ w1b,
                                                        const ushort_t* __restrict__ w2b,
                                                        const float* __restrict__ attA,
                                                        const float* __restrict__ ab2,
                                                        const int* __restrict__ idx,
                                                        const float* __restrict__ qT,
                                                        const float* __restrict__ kT,
                                                        const float* __restrict__ vT,
                                                        float* __restrict__ aggT) {
    __shared__ ushort_t lS[32 * 512];   // 64 smp x 256 k, frag-blocked, 32 KB
    __shared__ ushort_t lHt[4 * 2176];  // 128 hid x 64 smp, B-frag layout + pad, 17 KB
    int t = threadIdx.x;
    int lane = t & 63, w = t >> 6;
    int m16 = lane & 15, kg = lane >> 4;
    size_t row0 = (size_t)blockIdx.x * 64;

    // stage S slab: block lb = kt*4 + st of (16 samples x 32 k) = 1 KB each
#pragma unroll
    for (int i = 0; i < 8; ++i) {
        int lb = w * 8 + i;
        int kt = lb >> 2, st = lb & 3;
        const ushort_t* gp = S + (row0 + st * 16 + m16) * DIMD + kt * 32 + kg * 8;
        GLDS16(gp, lS + lb * 512);
    }

    f32x4 acc2[4][4];
#pragma unroll
    for (int i = 0; i < 4; ++i)
#pragma unroll
        for (int j = 0; j < 4; ++j) acc2[i][j] = (f32x4){0.f, 0.f, 0.f, 0.f};

    __syncthreads();

    for (int jc = 0; jc < 8; ++jc) {
        // GEMM1: wave w computes hid slice w*32..w*32+31 (2 tiles) x 64 samples
        f32x4 acc1[2][4];
#pragma unroll
        for (int hi = 0; hi < 2; ++hi)
#pragma unroll
            for (int sj = 0; sj < 4; ++sj) acc1[hi][sj] = (f32x4){0.f, 0.f, 0.f, 0.f};
#pragma unroll
        for (int kt = 0; kt < 8; ++kt) {
            short8 af[2], bf[4];
#pragma unroll
            for (int hi = 0; hi < 2; ++hi)
                af[hi] = *(const short8*)(w1b + ((size_t)(jc * 128 + w * 32 + hi * 16 + m16)) * DIMD + kt * 32 + kg * 8);
#pragma unroll
            for (int sj = 0; sj < 4; ++sj)
                bf[sj] = *(const short8*)(lS + (kt * 4 + sj) * 512 + kg * 128 + m16 * 8);
#pragma unroll
            for (int hi = 0; hi < 2; ++hi)
#pragma unroll
                for (int sj = 0; sj < 4; ++sj)
                    acc1[hi][sj] = __builtin_amdgcn_mfma_f32_16x16x32_bf16(af[hi], bf[sj], acc1[hi][sj], 0, 0, 0);
        }
        // affine + relu + bf16 pack + write to lHt (B-frag layout, pad-136)
#pragma unroll
        for (int hi = 0; hi < 2; ++hi) {
            float sc[4], ofs[4];
#pragma unroll
            for (int rg = 0; rg < 4; ++rg) {
                int hg = jc * 128 + w * 32 + hi * 16 + kg * 4 + rg;
                sc[rg] = attA[hg];
                ofs[rg] = attA[AHH + hg];
            }
#pragma unroll
            for (int sj = 0; sj < 4; ++sj) {
                u16x4 pk;
#pragma unroll
                for (int rg = 0; rg < 4; ++rg)
                    pk[rg] = f2b(fmaxf(sc[rg] * acc1[hi][sj][rg] + ofs[rg], 0.f));
                int ah = w * 2176 + sj * 544 + (hi * 2 + (kg >> 1)) * 136 + m16 * 8 + (kg & 1) * 4;
                *(u16x4*)(lHt + ah) = pk;
            }
        }
        __syncthreads();
        // GEMM2: wave w computes out slice w*64..w*64+63 (4 tiles) x 64 samples
#pragma unroll
        for (int g = 0; g < 4; ++g) {
            short8 af2[4], bf2[4];
#pragma unroll
            for (int oi = 0; oi < 4; ++oi)
                af2[oi] = *(const short8*)(w2b + ((size_t)(w * 64 + oi * 16 + m16)) * AHH + jc * 128 + g * 32 + kg * 8);
#pragma unroll
            for (int sj = 0; sj < 4; ++sj)
                bf2[sj] = *(const short8*)(lHt + g * 2176 + sj * 544 + kg * 136 + m16 * 8);
#pragma unroll
            for (int oi = 0; oi < 4; ++oi)
#pragma unroll
                for (int sj = 0; sj < 4; ++sj)
                    acc2[oi][sj] = __builtin_amdgcn_mfma_f32_16x16x32_bf16(af2[oi], bf2[sj], acc2[oi][sj], 0, 0, 0);
        }
        __syncthreads();
    }

    // Epilogue: logits^T C-layout: out = w*64+oi*16+kg*4+rg, sample = sj*16+m16.
    // Each sj tile = the 16 neighbors of point pt. Softmax across m16 lanes.
#pragma unroll
    for (int oi = 0; oi < 4; ++oi) {
        int ob = w * 64 + oi * 16 + kg * 4;
        float4 b2v = *(const float4*)(ab2 + ob);
#pragma unroll
        for (int sj = 0; sj < 4; ++sj) {
            int pt = (int)(row0 >> 4) + sj;
            int row = (int)row0 + sj * 16 + m16;
            int krow = (pt & ~(NN - 1)) + idx[row];
            u16x4 s4 = *(const u16x4*)(S + (size_t)row * DIMD + ob);
            float4 k4 = *(const float4*)(kT + (size_t)krow * DIMD + ob);
            float4 v4 = *(const float4*)(vT + (size_t)pt * DIMD + ob);
            float4 q4 = *(const float4*)(qT + (size_t)pt * DIMD + ob);
            float res[4];
#pragma unroll
            for (int rg = 0; rg < 4; ++rg) {
                float l = acc2[oi][sj][rg] + ((const float*)&b2v)[rg];
                float mx = l;
#pragma unroll
                for (int d = 1; d < 16; d <<= 1) mx = fmaxf(mx, __shfl_xor(mx, d));
                float e = expf(l - mx);
                float se = e;
#pragma unroll
                for (int d = 1; d < 16; d <<= 1) se += __shfl_xor(se, d);
                float p = e / se;
                float tv = p * (b2f(s4[rg]) + ((const float*)&k4)[rg]);
#pragma unroll
                for (int d = 1; d < 16; d <<= 1) tv += __shfl_xor(tv, d);
                res[rg] = ((const float*)&v4)[rg] - ((const float*)&q4)[rg] + tv;
            }
            if (m16 == 0) {
                float4 o4 = {res[0], res[1], res[2], res[3]};
                *(float4*)(aggT + (size_t)pt * DIMD + ob) = o4;
            }
        }
    }
}

// ---------------- K12: y = we·agg + be + identity (LDS-staged, coalesced) ----------------
__global__ __launch_bounds__(256) void final_kernel(const float* __restrict__ aggT,
                                                    const float* __restrict__ we,
                                                    const float* __restrict__ be,
                                                    const float* __restrict__ value,
                                                    float* __restrict__ out) {
    __shared__ float xs[2 * FPT][DIMD];
    int b = blockIdx.y;
    int n0 = blockIdx.x * (2 * FPT);
    int t = threadIdx.x;
    const float4* src = (const float4*)(aggT + ((size_t)b * NN + n0) * DIMD);
    float4* dst = (float4*)xs;
#pragma unroll
    for (int l = 0; l < (2 * FPT * DIMD / 4) / 256; ++l) dst[t + 256 * l] = src[t + 256 * l];
    __syncthreads();
    int o = t & 127, ph = t >> 7;
    float acc[FPT];
#pragma unroll
    for (int p = 0; p < FPT; ++p) acc[p] = 0.f;
    const float4* wr = (const float4*)(we + (size_t)o * DIMD);
#pragma unroll 8
    for (int i4 = 0; i4 < DIMD / 4; ++i4) {
        float4 w4 = wr[i4];
#pragma unroll
        for (int p = 0; p < FPT; ++p) {
            float4 x4 = *(const float4*)&xs[ph * FPT + p][i4 * 4];
            acc[p] += w4.x * x4.x + w4.y * x4.y + w4.z * x4.z + w4.w * x4.w;
        }
    }
    float bo = be[o];
#pragma unroll
    for (int p = 0; p < FPT; ++p) {
        size_t oi = ((size_t)b * CC + o) * NN + n0 + ph * FPT + p;
        out[oi] = acc[p] + bo + value[oi];
    }
}

extern "C" void kernel_launch(void* const* d_in, const int* in_sizes, int n_in,
                              void* d_out, int out_size, void* d_ws, size_t ws_size,
                              hipStream_t stream) {
    (void)in_sizes; (void)n_in; (void)out_size; (void)ws_size;
    const float* pos     = (const float*)d_in[0];
    const float* key     = (const float*)d_in[1];
    const float* query   = (const float*)d_in[2];
    const float* mlpv_w1 = (const float*)d_in[3];
    const float* mlpv_b1 = (const float*)d_in[4];
    const float* mlpv_w2 = (const float*)d_in[5];
    const float* mlpv_b2 = (const float*)d_in[6];
    const float* mlpv_ws = (const float*)d_in[7];
    const float* mlpv_bs = (const float*)d_in[8];
    const float* wk  = (const float*)d_in[9];
    const float* bk  = (const float*)d_in[10];
    const float* wq  = (const float*)d_in[11];
    const float* bq  = (const float*)d_in[12];
    const float* wv  = (const float*)d_in[13];
    const float* bv  = (const float*)d_in[14];
    const float* pw1 = (const float*)d_in[15];
    const float* pb1 = (const float*)d_in[16];
    const float* pg1 = (const float*)d_in[17];
    const float* pbe1= (const float*)d_in[18];
    const float* pw2 = (const float*)d_in[19];
    const float* pb2 = (const float*)d_in[20];
    const float* aw1 = (const float*)d_in[21];
    const float* ab1 = (const float*)d_in[22];
    const float* ag1 = (const float*)d_in[23];
    const float* abe1= (const float*)d_in[24];
    const float* aw2 = (const float*)d_in[25];
    const float* ab2 = (const float*)d_in[26];
    const float* we  = (const float*)d_in[27];
    const float* be  = (const float*)d_in[28];
    float* out = (float*)d_out;

    char* wsb = (char*)d_ws;
    size_t off = 0;
    auto alloc = [&](size_t bytes) {
        void* p = wsb + off;
        off += (bytes + 255) & ~(size_t)255;
        return p;
    };
    const size_t M = (size_t)BB * NN * KK;  // 131072 rows
    int*   idx   = (int*)  alloc(M * 4);
    float* h1buf = (float*)alloc((size_t)BB * CC * NN * 4);
    float* value = (float*)alloc((size_t)BB * CC * NN * 4);
    float* kT    = (float*)alloc((size_t)BB * NN * DIMD * 4);
    float* qT    = (float*)alloc((size_t)BB * NN * DIMD * 4);
    float* vT    = (float*)alloc((size_t)BB * NN * DIMD * 4);
    float* aggT  = (float*)alloc((size_t)BB * NN * DIMD * 4);
    float* zero0 = (float*)alloc((size_t)(16 + 256 + 65536) * 4);
    float* stats = zero0;
    float* mu    = zero0 + 16;
    float* R     = zero0 + 16 + 256;
    float* posA  = (float*)alloc((size_t)2 * PHH * 4);
    float* attA  = (float*)alloc((size_t)2 * AHH * 4);
    ushort_t* w1b = (ushort_t*)alloc((size_t)AHH * DIMD * 2);
    ushort_t* w2b = (ushort_t*)alloc((size_t)DIMD * AHH * 2);
    ushort_t* pw2b = (ushort_t*)alloc((size_t)DIMD * PHH * 2);
    ushort_t* sb16 = (ushort_t*)alloc(M * DIMD * 2);          //  67 MB
    // overlay: p1buf (16.8 MB) used by p1/gemmS, then Rpart (33.5 MB) by rg/r_reduce
    char* ovl = (char*)alloc((size_t)RSPLIT * DIMD * DIMD * 4);
    ushort_t* p1buf = (ushort_t*)ovl;
    float*    Rpart = (float*)ovl;
    // total ~142 MB

    int ZN = 16 + 256 + 65536;
    zero_kernel<<<(ZN + 255) / 256, 256, 0, stream>>>(zero0, ZN);
    knn_kernel<<<BB * NN, 256, 0, stream>>>(pos, idx);
    h1_kernel<<<dim3(NN / 256, CC, BB), 256, 0, stream>>>(key, query, mlpv_w1, mlpv_b1, h1buf);
    value_kernel<<<dim3(NN / 256, CC, BB), 256, 0, stream>>>(key, query, h1buf, mlpv_w2, mlpv_b2, mlpv_ws, mlpv_bs, value);
    convT_kernel<<<dim3(NN / PT, BB), 256, 0, stream>>>(wk, bk, key, kT);
    convT_kernel<<<dim3(NN / PT, BB), 256, 0, stream>>>(wq, bq, query, qT);
    convT_kernel<<<dim3(NN / PT, BB), 256, 0, stream>>>(wv, bv, value, vT);
    pos_stats_kernel<<<BB * NN * KK / 256, 256, 0, stream>>>(pos, idx, stats);
    pos_bn_kernel<<<1, 64, 0, stream>>>(stats, pw1, pb1, pg1, pbe1, posA);
    cvt_w_kernel<<<(2 * AHH * DIMD + DIMD * PHH + 255) / 256, 256, 0, stream>>>(aw1, aw2, pw2, w1b, w2b, pw2b);
    p1_kernel<<<(int)(M * PHH / 256), 256, 0, stream>>>(pos, idx, pw1, pb1, posA, p1buf);
    gemmS_kernel<PHH><<<dim3(M / 128, DIMD / 128), 256, 0, stream>>>(p1buf, pw2b, pb2, sb16, qT, kT, idx);
    mu_kernel<<<M / 512, 256, 0, stream>>>(sb16, mu);
    rg_kernel<<<dim3(RSPLIT, 4), 256, 0, stream>>>(sb16, Rpart);
    r_reduce_kernel<<<DIMD * DIMD / 256, 256, 0, stream>>>(Rpart, R);
    attn_bn_kernel<<<AHH, DIMD, 0, stream>>>(R, mu, aw1, ab1, ag1, abe1, attA);
    fused_mlp_kernel<<<(int)(M / 64), 256, 0, stream>>>(sb16, w1b, w2b, attA, ab2, idx, qT, kT, vT, aggT);
    final_kernel<<<dim3(NN / (2 * FPT), BB), 256, 0, stream>>>(aggT, we, be, value, out);
}

// Round 9
// 824.458 us; speedup vs baseline: 6.7122x; 1.0684x over previous
//
#include <hip/hip_runtime.h>
#include <math.h>

#define BB 2
#define CC 128
#define NN 4096
#define KK 16
#define DIMD 256
#define PHH 64
#define AHH 1024
#define EPSF 1e-5f
#define PT 16
#define RSPLIT 128
#define RKCH ((BB * NN * KK) / RSPLIT)   // 1024 samples per R block
#define LSTR 258    // LDS row stride (halfwords): conflict-free transposed gathers
#define KNN_CAP 512
#define FPT 8       // final_kernel points per thread

typedef unsigned short ushort_t;
typedef unsigned long long u64;
typedef __attribute__((ext_vector_type(8))) short short8;
typedef __attribute__((ext_vector_type(8))) unsigned short u16x8;
typedef __attribute__((ext_vector_type(4))) unsigned short u16x4;
typedef __attribute__((ext_vector_type(2))) unsigned short u16x2;
typedef __attribute__((ext_vector_type(4))) float f32x4;

__device__ __forceinline__ ushort_t f2b(float x) {
    union { float f; unsigned u; } v; v.f = x;
    unsigned r = v.u + 0x7fff + ((v.u >> 16) & 1);
    return (ushort_t)(r >> 16);
}
__device__ __forceinline__ float b2f(ushort_t x) {
    union { unsigned u; float f; } v; v.u = ((unsigned)x) << 16;
    return v.f;
}
__device__ __forceinline__ unsigned fsort(float x) {
    union { float f; unsigned u; } v; v.f = x;
    return v.u ^ ((v.u >> 31) ? 0xFFFFFFFFu : 0x80000000u);
}

#define GLDS16(gp, lp) __builtin_amdgcn_global_load_lds( \
    (const __attribute__((address_space(1))) void*)(gp), \
    (__attribute__((address_space(3))) void*)(lp), 16, 0, 0)

// ---------------- K0: zero scratch accumulators ----------------
__global__ void zero_kernel(float* p, int n) {
    int i = blockIdx.x * blockDim.x + threadIdx.x;
    if (i < n) p[i] = 0.f;
}

// ---------------- K1: exact kNN via u64-key threshold select ----------------
__global__ __launch_bounds__(256) void knn_kernel(const float* __restrict__ pos,
                                                  int* __restrict__ idx) {
    int bid = blockIdx.x;
    int b = bid / NN, n = bid % NN;
    int t = threadIdx.x;
    int lane = t & 63, w = t >> 6;
    const float* px = pos + (size_t)b * 3 * NN;
    const float* py = px + NN;
    const float* pz = px + 2 * NN;
    float qx = px[n], qy = py[n], qz = pz[n];
    float qs = qx * qx + qy * qy + qz * qz;

    u64 keys[KK];
    u64 lmin = ~0ull;
#pragma unroll
    for (int j = 0; j < KK; ++j) {
        int m = t + 256 * j;
        float mx = px[m], my = py[m], mz = pz[m];
        float ms = mx * mx + my * my + mz * mz;
        float dt = qx * mx + qy * my + qz * mz;
        float d = qs + ms - 2.f * dt;
        u64 k = ((u64)fsort(d) << 32) | (unsigned)m;
        keys[j] = k;
        lmin = k < lmin ? k : lmin;
    }

    __shared__ u64 T0s[4];
    __shared__ u64 pool[KNN_CAP];
    __shared__ int cnt;

    u64 k = lmin, m4 = 0;
#pragma unroll
    for (int r = 0; r < 4; ++r) {
        u64 mv = k;
#pragma unroll
        for (int off = 32; off >= 1; off >>= 1) {
            u64 o = __shfl_xor(mv, off);
            mv = o < mv ? o : mv;
        }
        if (r == 3) m4 = mv;
        if (k == mv) k = ~0ull;
    }
    if (lane == 0) T0s[w] = m4;
    if (t == 0) cnt = 0;
    __syncthreads();
    u64 T0 = T0s[0];
    T0 = T0s[1] > T0 ? T0s[1] : T0;
    T0 = T0s[2] > T0 ? T0s[2] : T0;
    T0 = T0s[3] > T0 ? T0s[3] : T0;

#pragma unroll
    for (int j = 0; j < KK; ++j) {
        if (keys[j] <= T0) {
            int p = atomicAdd(&cnt, 1);
            if (p < KNN_CAP) pool[p] = keys[j];
        }
    }
    __syncthreads();
    int C = cnt < KNN_CAP ? cnt : KNN_CAP;
    if (t < C) {
        u64 me = pool[t];
        int r = 0;
        for (int i = 0; i < C; ++i) r += (pool[i] < me);
        if (r < KK) idx[(size_t)bid * KK + r] = (int)(me & 0xFFFFFFFFu);
    }
}

// ---------------- K2: h1 = relu(W1·[key;query] + b1) ----------------
__global__ __launch_bounds__(256) void h1_kernel(const float* __restrict__ key,
                                                 const float* __restrict__ query,
                                                 const float* __restrict__ w1,
                                                 const float* __restrict__ b1,
                                                 float* __restrict__ h1) {
    int n = blockIdx.x * 256 + threadIdx.x;
    int o = blockIdx.y, b = blockIdx.z;
    const float* wr = w1 + (size_t)o * 256;
    const float* kb = key + (size_t)b * CC * NN;
    const float* qb = query + (size_t)b * CC * NN;
    float acc = b1[o];
#pragma unroll 4
    for (int i = 0; i < CC; ++i) acc += wr[i] * kb[(size_t)i * NN + n];
#pragma unroll 4
    for (int i = 0; i < CC; ++i) acc += wr[CC + i] * qb[(size_t)i * NN + n];
    h1[((size_t)b * CC + o) * NN + n] = fmaxf(acc, 0.f);
}

// ---------------- K3: value = W2·h1 + b2 + Ws·[key;query] + bs ----------------
__global__ __launch_bounds__(256) void value_kernel(const float* __restrict__ key,
                                                    const float* __restrict__ query,
                                                    const float* __restrict__ h1buf,
                                                    const float* __restrict__ w2,
                                                    const float* __restrict__ b2,
                                                    const float* __restrict__ wsk,
                                                    const float* __restrict__ bs,
                                                    float* __restrict__ value) {
    int n = blockIdx.x * 256 + threadIdx.x;
    int o = blockIdx.y, b = blockIdx.z;
    const float* w2r = w2 + (size_t)o * CC;
    const float* wsr = wsk + (size_t)o * 256;
    const float* kb = key + (size_t)b * CC * NN;
    const float* qb = query + (size_t)b * CC * NN;
    const float* hb = h1buf + (size_t)b * CC * NN;
    float acc = b2[o] + bs[o];
#pragma unroll 4
    for (int i = 0; i < CC; ++i) acc += w2r[i] * hb[(size_t)i * NN + n];
#pragma unroll 4
    for (int i = 0; i < CC; ++i) acc += wsr[i] * kb[(size_t)i * NN + n];
#pragma unroll 4
    for (int i = 0; i < CC; ++i) acc += wsr[CC + i] * qb[(size_t)i * NN + n];
    value[((size_t)b * CC + o) * NN + n] = acc;
}

// ---------------- K4: outT[b][n][o] = bias[o] + W(256x128)·X[b,:,n] ----------------
__global__ __launch_bounds__(256) void convT_kernel(const float* __restrict__ W,
                                                    const float* __restrict__ bias,
                                                    const float* __restrict__ X,
                                                    float* __restrict__ outT) {
    __shared__ float xs[PT][CC + 1];
    int b = blockIdx.y;
    int n0 = blockIdx.x * PT;
    int t = threadIdx.x;
    for (int l = t; l < PT * CC; l += 256) {
        int p = l & (PT - 1); int i = l >> 4;
        xs[p][i] = X[((size_t)b * CC + i) * NN + n0 + p];
    }
    __syncthreads();
    int o = t;
    const float* wr = W + (size_t)o * CC;
    float acc[PT];
    float bo = bias[o];
#pragma unroll
    for (int p = 0; p < PT; ++p) acc[p] = bo;
    for (int i = 0; i < CC; ++i) {
        float w = wr[i];
#pragma unroll
        for (int p = 0; p < PT; ++p) acc[p] += w * xs[p][i];
    }
#pragma unroll
    for (int p = 0; p < PT; ++p)
        outT[((size_t)b * NN + n0 + p) * DIMD + o] = acc[p];
}

// ---------------- K5: pos_rel first/second moments (9 sums) ----------------
__global__ __launch_bounds__(256) void pos_stats_kernel(const float* __restrict__ pos,
                                                        const int* __restrict__ idx,
                                                        float* __restrict__ stats) {
    int sid = blockIdx.x * 256 + threadIdx.x;
    int b = sid / (NN * KK);
    int r = sid % (NN * KK);
    int n = r / KK;
    int m = idx[sid];
    const float* px = pos + (size_t)b * 3 * NN;
    float dx = px[n] - px[m];
    float dy = px[NN + n] - px[NN + m];
    float dz = px[2 * NN + n] - px[2 * NN + m];
    float v[9] = {dx, dy, dz, dx * dx, dy * dy, dz * dz, dx * dy, dx * dz, dy * dz};
    __shared__ float red[256];
    for (int j = 0; j < 9; ++j) {
        red[threadIdx.x] = v[j];
        __syncthreads();
        for (int off = 128; off >= 1; off >>= 1) {
            if (threadIdx.x < off) red[threadIdx.x] += red[threadIdx.x + off];
            __syncthreads();
        }
        if (threadIdx.x == 0) atomicAdd(&stats[j], red[0]);
        __syncthreads();
    }
}

// ---------------- K6: pos BN affine (a1, a0) per 64 channels ----------------
__global__ void pos_bn_kernel(const float* __restrict__ stats, const float* __restrict__ pw1,
                              const float* __restrict__ pb1, const float* __restrict__ pg1,
                              const float* __restrict__ pbe1, float* __restrict__ posA) {
    int c = threadIdx.x;
    if (c >= PHH) return;
    float M = (float)(BB * NN * KK);
    float mu0 = stats[0] / M, mu1 = stats[1] / M, mu2 = stats[2] / M;
    float E00 = stats[3] / M, E11 = stats[4] / M, E22 = stats[5] / M;
    float E01 = stats[6] / M, E02 = stats[7] / M, E12 = stats[8] / M;
    float w0 = pw1[c * 3], w1 = pw1[c * 3 + 1], w2 = pw1[c * 3 + 2];
    float wmu = w0 * mu0 + w1 * mu1 + w2 * mu2;
    float mean_h = wmu + pb1[c];
    float Eh2 = w0 * w0 * E00 + w1 * w1 * E11 + w2 * w2 * E22
              + 2.f * (w0 * w1 * E01 + w0 * w2 * E02 + w1 * w2 * E12)
              + 2.f * pb1[c] * wmu + pb1[c] * pb1[c];
    float var = Eh2 - mean_h * mean_h;
    float a1 = pg1[c] * rsqrtf(var + EPSF);
    posA[c] = a1;
    posA[PHH + c] = pbe1[c] - mean_h * a1;
}

// ---------------- K7a: P1 = relu(BNaffine(pw1 . pos_rel)) bf16 (M x 64) ----------------
__global__ __launch_bounds__(256) void p1_kernel(const float* __restrict__ pos,
                                                 const int* __restrict__ idx,
                                                 const float* __restrict__ pw1,
                                                 const float* __restrict__ pb1,
                                                 const float* __restrict__ posA,
                                                 ushort_t* __restrict__ p1) {
    int gid = blockIdx.x * 256 + threadIdx.x;
    int samp = gid >> 6, c = gid & 63;
    int p = samp >> 4;           // global point b*NN+n
    int b = p >> 12, n = p & (NN - 1);
    int m = idx[samp];
    const float* px = pos + (size_t)b * 3 * NN;
    float dx = px[n] - px[m];
    float dy = px[NN + n] - px[NN + m];
    float dz = px[2 * NN + n] - px[2 * NN + m];
    float h = pw1[c * 3] * dx + pw1[c * 3 + 1] * dy + pw1[c * 3 + 2] * dz + pb1[c];
    p1[gid] = f2b(fmaxf(h * posA[c] + posA[PHH + c], 0.f));
}

// ---------------- K8: mu = column sums of s ----------------
__global__ __launch_bounds__(256) void mu_kernel(const ushort_t* __restrict__ sb16,
                                                 float* __restrict__ mu) {
    int c = threadIdx.x;
    const ushort_t* p = sb16 + (size_t)blockIdx.x * 512 * DIMD + c;
    float acc = 0.f;
    for (int i = 0; i < 512; ++i) acc += b2f(p[(size_t)i * DIMD]);
    atomicAdd(&mu[c], acc);
}

// ---------------- K9: R partials via MFMA: Rpart[chunk] = S_chunk^T * S_chunk ----------
__global__ __launch_bounds__(256) void rg_kernel(const ushort_t* __restrict__ S,
                                                 float* __restrict__ Rpart) {
    __shared__ ushort_t ls[32 * LSTR];
    int t = threadIdx.x;
    int lane = t & 63, w = t >> 6;
    int wr = w >> 1, wc = w & 1;
    int ti = blockIdx.y >> 1, tj = blockIdx.y & 1;
    int m16 = lane & 15, kg = lane >> 4;
    size_t kbase = (size_t)blockIdx.x * RKCH;

    f32x4 acc[4][4];
#pragma unroll
    for (int i = 0; i < 4; ++i)
#pragma unroll
        for (int j = 0; j < 4; ++j) acc[i][j] = (f32x4){0.f, 0.f, 0.f, 0.f};

    int lm = t >> 3;
    int lc = (t & 7) * 32;
    const ushort_t* gS = S + (kbase + lm) * DIMD + lc;
    ushort_t* lp = ls + lm * LSTR + lc;

    for (int kt = 0; kt < RKCH / 32; ++kt) {
        const ushort_t* gp = gS + (size_t)kt * 32 * DIMD;
        u16x8 v0 = *(const u16x8*)(gp);
        u16x8 v1 = *(const u16x8*)(gp + 8);
        u16x8 v2 = *(const u16x8*)(gp + 16);
        u16x8 v3 = *(const u16x8*)(gp + 24);
        __syncthreads();
#pragma unroll
        for (int q = 0; q < 4; ++q) {
            *(u16x2*)(lp + 0 + 2 * q) = (u16x2){v0[2 * q], v0[2 * q + 1]};
            *(u16x2*)(lp + 8 + 2 * q) = (u16x2){v1[2 * q], v1[2 * q + 1]};
            *(u16x2*)(lp + 16 + 2 * q) = (u16x2){v2[2 * q], v2[2 * q + 1]};
            *(u16x2*)(lp + 24 + 2 * q) = (u16x2){v3[2 * q], v3[2 * q + 1]};
        }
        __syncthreads();
        short8 af[4], bf[4];
#pragma unroll
        for (int i = 0; i < 4; ++i) {
            int chA = ti * 128 + wr * 64 + i * 16 + m16;
            int chB = tj * 128 + wc * 64 + i * 16 + m16;
#pragma unroll
            for (int j = 0; j < 8; ++j) {
                int k = kg * 8 + j;
                af[i][j] = (short)ls[k * LSTR + chA];
                bf[i][j] = (short)ls[k * LSTR + chB];
            }
        }
#pragma unroll
        for (int i = 0; i < 4; ++i)
#pragma unroll
            for (int j = 0; j < 4; ++j)
                acc[i][j] = __builtin_amdgcn_mfma_f32_16x16x32_bf16(af[i], bf[j], acc[i][j], 0, 0, 0);
    }

    float* rp = Rpart + (size_t)blockIdx.x * (DIMD * DIMD);
#pragma unroll
    for (int i = 0; i < 4; ++i) {
        int r0 = ti * 128 + wr * 64 + i * 16 + kg * 4;
#pragma unroll
        for (int j = 0; j < 4; ++j) {
            int cn = tj * 128 + wc * 64 + j * 16 + m16;
#pragma unroll
            for (int rg = 0; rg < 4; ++rg)
                rp[(size_t)(r0 + rg) * DIMD + cn] = acc[i][j][rg];
        }
    }
}

// ---------------- K9b: reduce R partials ----------------
__global__ __launch_bounds__(256) void r_reduce_kernel(const float* __restrict__ Rpart,
                                                       float* __restrict__ R) {
    int e = blockIdx.x * 256 + threadIdx.x;
    float s = 0.f;
    for (int p = 0; p < RSPLIT; ++p) s += Rpart[(size_t)p * (DIMD * DIMD) + e];
    R[e] = s;
}

// ---------------- K10: attn BN -> fused scale/offset per hidden channel ----------------
__global__ __launch_bounds__(256) void attn_bn_kernel(const float* __restrict__ R,
                                                      const float* __restrict__ mu,
                                                      const float* __restrict__ aw1,
                                                      const float* __restrict__ ab1,
                                                      const float* __restrict__ ag1,
                                                      const float* __restrict__ abe1,
                                                      float* __restrict__ attA) {
    int c = blockIdx.x;
    int t = threadIdx.x;
    __shared__ float wsh[DIMD];
    __shared__ float red[DIMD];
    wsh[t] = aw1[(size_t)c * DIMD + t];
    __syncthreads();
    const float* Rr = R + (size_t)t * DIMD;
    float q = 0.f;
#pragma unroll 4
    for (int j = 0; j < DIMD; ++j) q += Rr[j] * wsh[j];
    red[t] = q * wsh[t];
    __syncthreads();
    for (int off = 128; off >= 1; off >>= 1) {
        if (t < off) red[t] += red[t + off];
        __syncthreads();
    }
    float wRw = red[0];
    __syncthreads();
    red[t] = wsh[t] * mu[t];
    __syncthreads();
    for (int off = 128; off >= 1; off >>= 1) {
        if (t < off) red[t] += red[t + off];
        __syncthreads();
    }
    if (t == 0) {
        float M = (float)(BB * NN * KK);
        float wmu = red[0] / M;
        float b1c = ab1[c];
        float Eh = wmu + b1c;
        float Eh2 = wRw / M + 2.f * b1c * wmu + b1c * b1c;
        float var = Eh2 - Eh * Eh;
        float a1 = ag1[c] * rsqrtf(var + EPSF);
        attA[c] = a1;
        attA[AHH + c] = a1 * b1c + abe1[c] - Eh * a1;
    }
}

// ---------------- K10b: convert W1, W2, pos_w2 to bf16 ----------------
__global__ void cvt_w_kernel(const float* __restrict__ aw1, const float* __restrict__ aw2,
                             const float* __restrict__ pw2,
                             ushort_t* __restrict__ w1b, ushort_t* __restrict__ w2b,
                             ushort_t* __restrict__ pw2b) {
    int i = blockIdx.x * 256 + threadIdx.x;
    if (i < AHH * DIMD) w1b[i] = f2b(aw1[i]);
    else if (i < 2 * AHH * DIMD) w2b[i - AHH * DIMD] = f2b(aw2[i - AHH * DIMD]);
    else {
        int j = i - 2 * AHH * DIMD;
        if (j < DIMD * PHH) pw2b[j] = f2b(pw2[j]);
    }
}

// ---------------- MFMA GEMM (s-build only): C = A(MxK)·B(NxK)^T, EPI 2 ----------------
template <int KDIM>
__global__ __launch_bounds__(256) void gemmS_kernel(const ushort_t* __restrict__ A,
                                                    const ushort_t* __restrict__ Bm,
                                                    const float* __restrict__ p0,
                                                    ushort_t* __restrict__ Sb,
                                                    const float* __restrict__ qT,
                                                    const float* __restrict__ kT,
                                                    const int* __restrict__ gidx) {
    __shared__ ushort_t lA[128 * 32];
    __shared__ ushort_t lB[128 * 32];
    int t = threadIdx.x;
    int lane = t & 63, w = t >> 6;
    int wr = w >> 1, wc = w & 1;
    size_t row0 = (size_t)blockIdx.x * 128;
    int col0 = blockIdx.y * 128;
    int m16 = lane & 15, kg = lane >> 4;

    f32x4 acc[4][4];
#pragma unroll
    for (int i = 0; i < 4; ++i)
#pragma unroll
        for (int j = 0; j < 4; ++j) acc[i][j] = (f32x4){0.f, 0.f, 0.f, 0.f};

    const ushort_t* gA = A + (row0 + (size_t)w * 16 + m16) * KDIM + kg * 8;
    const ushort_t* gB = Bm + ((size_t)(col0 + w * 16 + m16)) * KDIM + kg * 8;
    ushort_t* lA0 = lA + w * 512;
    ushort_t* lB0 = lB + w * 512;

    for (int kt = 0; kt < KDIM / 32; ++kt) {
        int ko = kt * 32;
        GLDS16(gA + ko, lA0);
        GLDS16(gA + (size_t)64 * KDIM + ko, lA0 + 2048);
        GLDS16(gB + ko, lB0);
        GLDS16(gB + (size_t)64 * KDIM + ko, lB0 + 2048);
        __syncthreads();
        short8 af[4], bf[4];
#pragma unroll
        for (int i = 0; i < 4; ++i) {
            af[i] = *(const short8*)(lA + ((wr * 4 + i) * 512 + kg * 128 + m16 * 8));
            bf[i] = *(const short8*)(lB + ((wc * 4 + i) * 512 + kg * 128 + m16 * 8));
        }
#pragma unroll
        for (int i = 0; i < 4; ++i)
#pragma unroll
            for (int j = 0; j < 4; ++j)
                acc[i][j] = __builtin_amdgcn_mfma_f32_16x16x32_bf16(af[i], bf[j], acc[i][j], 0, 0, 0);
        __syncthreads();
    }

    int nn[4]; float bi[4];
#pragma unroll
    for (int j = 0; j < 4; ++j) { nn[j] = col0 + wc * 64 + j * 16 + m16; bi[j] = p0[nn[j]]; }
#pragma unroll
    for (int i = 0; i < 4; ++i) {
        size_t r = row0 + wr * 64 + i * 16 + kg * 4;
#pragma unroll
        for (int rg = 0; rg < 4; ++rg) {
            size_t rr = r + rg;
            int p = (int)(rr >> 4);
            int krow = (p & ~(NN - 1)) + gidx[rr];
            const float* qrow = qT + (size_t)p * DIMD;
            const float* kro = kT + (size_t)krow * DIMD;
#pragma unroll
            for (int j = 0; j < 4; ++j) {
                float sv = qrow[nn[j]] - kro[nn[j]] + acc[i][j][rg] + bi[j];
                Sb[rr * (size_t)DIMD + nn[j]] = f2b(sv);
            }
        }
    }
}

// ---------------- K11: fused attn MLP + softmax + aggregation (v2) ----------------
// Block = 64 samples (4 points), 4 waves. Double-buffered lHt in m97 frag layout
// (conflict-free GEMM2 reads), 1 barrier/jc. Epilogue: logits -> 64KB LDS (XOR
// swizzle) -> thread-per-out-channel softmax+agg with coalesced global gathers.
__global__ __launch_bounds__(256) void fused_mlp_kernel(const ushort_t* __restrict__ S,
                                                        const ushort_t* __restrict__ w1b,
                                                        const ushort_t* __restrict__ w2b,
                                                        const float* __restrict__ attA,
                                                        const float* __restrict__ ab2,
                                                        const int* __restrict__ idx,
                                                        const float* __restrict__ qT,
                                                        const float* __restrict__ kT,
                                                        const float* __restrict__ vT,
                                                        float* __restrict__ aggT) {
    __shared__ char smem[65536];
    ushort_t* lS  = (ushort_t*)smem;             // 32 KB: 64 smp x 256 k, frag-blocked
    ushort_t* lHt = (ushort_t*)(smem + 32768);   // 2 x 16 KB: 128 hid x 64 smp, frag layout
    float*    lgF = (float*)smem;                // epilogue: 64 smp x 256 out fp32, XOR swizzle

    int t = threadIdx.x;
    int lane = t & 63, w = t >> 6;
    int m16 = lane & 15, kg = lane >> 4;
    size_t row0 = (size_t)blockIdx.x * 64;

    // stage S slab: block lb = kt*4 + st of (16 samples x 32 k)
#pragma unroll
    for (int i = 0; i < 8; ++i) {
        int lb = w * 8 + i;
        int kt = lb >> 2, st = lb & 3;
        const ushort_t* gp = S + (row0 + st * 16 + m16) * DIMD + kt * 32 + kg * 8;
        GLDS16(gp, lS + lb * 512);
    }

    f32x4 acc2[4][4];
#pragma unroll
    for (int i = 0; i < 4; ++i)
#pragma unroll
        for (int j = 0; j < 4; ++j) acc2[i][j] = (f32x4){0.f, 0.f, 0.f, 0.f};

    __syncthreads();

    for (int jc = 0; jc < 8; ++jc) {
        ushort_t* buf = lHt + (jc & 1) * 8192;
        // GEMM1: wave w -> hid slice w*32..w*32+31 (2 tiles) x 64 samples
        f32x4 acc1[2][4];
#pragma unroll
        for (int hi = 0; hi < 2; ++hi)
#pragma unroll
            for (int sj = 0; sj < 4; ++sj) acc1[hi][sj] = (f32x4){0.f, 0.f, 0.f, 0.f};
#pragma unroll
        for (int kt = 0; kt < 8; ++kt) {
            short8 af[2], bf[4];
#pragma unroll
            for (int hi = 0; hi < 2; ++hi)
                af[hi] = *(const short8*)(w1b + ((size_t)(jc * 128 + w * 32 + hi * 16 + m16)) * DIMD + kt * 32 + kg * 8);
#pragma unroll
            for (int sj = 0; sj < 4; ++sj)
                bf[sj] = *(const short8*)(lS + (kt * 4 + sj) * 512 + kg * 128 + m16 * 8);
#pragma unroll
            for (int hi = 0; hi < 2; ++hi)
#pragma unroll
                for (int sj = 0; sj < 4; ++sj)
                    acc1[hi][sj] = __builtin_amdgcn_mfma_f32_16x16x32_bf16(af[hi], bf[sj], acc1[hi][sj], 0, 0, 0);
        }
        // affine + relu + pack into buf (m97 frag layout: tile (w*4+sj), stride 128)
#pragma unroll
        for (int hi = 0; hi < 2; ++hi) {
            float4 sc4 = *(const float4*)(attA + jc * 128 + w * 32 + hi * 16 + kg * 4);
            float4 of4 = *(const float4*)(attA + AHH + jc * 128 + w * 32 + hi * 16 + kg * 4);
#pragma unroll
            for (int sj = 0; sj < 4; ++sj) {
                u16x4 pk;
                pk[0] = f2b(fmaxf(sc4.x * acc1[hi][sj][0] + of4.x, 0.f));
                pk[1] = f2b(fmaxf(sc4.y * acc1[hi][sj][1] + of4.y, 0.f));
                pk[2] = f2b(fmaxf(sc4.z * acc1[hi][sj][2] + of4.z, 0.f));
                pk[3] = f2b(fmaxf(sc4.w * acc1[hi][sj][3] + of4.w, 0.f));
                int ah = (w * 4 + sj) * 512 + (hi * 2 + (kg >> 1)) * 128 + m16 * 8 + (kg & 1) * 4;
                *(u16x4*)(buf + ah) = pk;
            }
        }
        __syncthreads();
        // GEMM2: wave w -> out slice w*64..w*64+63 (4 tiles) x 64 samples
#pragma unroll
        for (int g = 0; g < 4; ++g) {
            short8 af2[4], bf2[4];
#pragma unroll
            for (int oi = 0; oi < 4; ++oi)
                af2[oi] = *(const short8*)(w2b + ((size_t)(w * 64 + oi * 16 + m16)) * AHH + jc * 128 + g * 32 + kg * 8);
#pragma unroll
            for (int sj = 0; sj < 4; ++sj)
                bf2[sj] = *(const short8*)(buf + (g * 4 + sj) * 512 + kg * 128 + m16 * 8);
#pragma unroll
            for (int oi = 0; oi < 4; ++oi)
#pragma unroll
                for (int sj = 0; sj < 4; ++sj)
                    acc2[oi][sj] = __builtin_amdgcn_mfma_f32_16x16x32_bf16(af2[oi], bf2[sj], acc2[oi][sj], 0, 0, 0);
        }
        // single barrier per jc: double-buffered lHt makes the pre-write wait implicit
    }
    __syncthreads();

    // Epilogue phase 1: logits (+b2) -> lgF[smp][out], XOR-swizzled, conflict-free
#pragma unroll
    for (int oi = 0; oi < 4; ++oi) {
        int ob = w * 64 + oi * 16 + kg * 4;
        float4 b2v = *(const float4*)(ab2 + ob);
#pragma unroll
        for (int sj = 0; sj < 4; ++sj) {
            int smp = sj * 16 + m16;
            float4 lv;
            lv.x = acc2[oi][sj][0] + b2v.x;
            lv.y = acc2[oi][sj][1] + b2v.y;
            lv.z = acc2[oi][sj][2] + b2v.z;
            lv.w = acc2[oi][sj][3] + b2v.w;
            *(float4*)(lgF + smp * 256 + (ob ^ ((smp & 7) << 2))) = lv;
        }
    }
    __syncthreads();

    // Epilogue phase 2: thread t owns out-channel t; 4 points; serial softmax in regs.
    int out = t;
    for (int pt = 0; pt < 4; ++pt) {
        int pid = (int)(row0 >> 4) + pt;
        float lg[KK];
#pragma unroll
        for (int s = 0; s < KK; ++s)
            lg[s] = lgF[(pt * 16 + s) * 256 + (out ^ ((s & 7) << 2))];
        float mx = lg[0];
#pragma unroll
        for (int s = 1; s < KK; ++s) mx = fmaxf(mx, lg[s]);
        float se = 0.f;
#pragma unroll
        for (int s = 0; s < KK; ++s) { lg[s] = expf(lg[s] - mx); se += lg[s]; }
        float inv = 1.f / se;
        int base = pid & ~(NN - 1);
        float acc = 0.f;
#pragma unroll
        for (int s = 0; s < KK; ++s) {
            int row = pid * KK + s;
            int krow = base + idx[row];
            float sv = b2f(S[(size_t)row * DIMD + out]);
            float kv = kT[(size_t)krow * DIMD + out];
            acc += lg[s] * (sv + kv);
        }
        float vf = vT[(size_t)pid * DIMD + out];
        float q  = qT[(size_t)pid * DIMD + out];
        // agg = sum_s p_s (vf + s - q + k) = vf - q + sum_s p_s (s + k)   [sum p = 1]
        aggT[(size_t)pid * DIMD + out] = vf - q + acc * inv;
    }
}

// ---------------- K12: y = we·agg + be + identity (LDS-staged, coalesced) ----------------
__global__ __launch_bounds__(256) void final_kernel(const float* __restrict__ aggT,
                                                    const float* __restrict__ we,
                                                    const float* __restrict__ be,
                                                    const float* __restrict__ value,
                                                    float* __restrict__ out) {
    __shared__ float xs[2 * FPT][DIMD];
    int b = blockIdx.y;
    int n0 = blockIdx.x * (2 * FPT);
    int t = threadIdx.x;
    const float4* src = (const float4*)(aggT + ((size_t)b * NN + n0) * DIMD);
    float4* dst = (float4*)xs;
#pragma unroll
    for (int l = 0; l < (2 * FPT * DIMD / 4) / 256; ++l) dst[t + 256 * l] = src[t + 256 * l];
    __syncthreads();
    int o = t & 127, ph = t >> 7;
    float acc[FPT];
#pragma unroll
    for (int p = 0; p < FPT; ++p) acc[p] = 0.f;
    const float4* wr = (const float4*)(we + (size_t)o * DIMD);
#pragma unroll 8
    for (int i4 = 0; i4 < DIMD / 4; ++i4) {
        float4 w4 = wr[i4];
#pragma unroll
        for (int p = 0; p < FPT; ++p) {
            float4 x4 = *(const float4*)&xs[ph * FPT + p][i4 * 4];
            acc[p] += w4.x * x4.x + w4.y * x4.y + w4.z * x4.z + w4.w * x4.w;
        }
    }
    float bo = be[o];
#pragma unroll
    for (int p = 0; p < FPT; ++p) {
        size_t oi = ((size_t)b * CC + o) * NN + n0 + ph * FPT + p;
        out[oi] = acc[p] + bo + value[oi];
    }
}

extern "C" void kernel_launch(void* const* d_in, const int* in_sizes, int n_in,
                              void* d_out, int out_size, void* d_ws, size_t ws_size,
                              hipStream_t stream) {
    (void)in_sizes; (void)n_in; (void)out_size; (void)ws_size;
    const float* pos     = (const float*)d_in[0];
    const float* key     = (const float*)d_in[1];
    const float* query   = (const float*)d_in[2];
    const float* mlpv_w1 = (const float*)d_in[3];
    const float* mlpv_b1 = (const float*)d_in[4];
    const float* mlpv_w2 = (const float*)d_in[5];
    const float* mlpv_b2 = (const float*)d_in[6];
    const float* mlpv_ws = (const float*)d_in[7];
    const float* mlpv_bs = (const float*)d_in[8];
    const float* wk  = (const float*)d_in[9];
    const float* bk  = (const float*)d_in[10];
    const float* wq  = (const float*)d_in[11];
    const float* bq  = (const float*)d_in[12];
    const float* wv  = (const float*)d_in[13];
    const float* bv  = (const float*)d_in[14];
    const float* pw1 = (const float*)d_in[15];
    const float* pb1 = (const float*)d_in[16];
    const float* pg1 = (const float*)d_in[17];
    const float* pbe1= (const float*)d_in[18];
    const float* pw2 = (const float*)d_in[19];
    const float* pb2 = (const float*)d_in[20];
    const float* aw1 = (const float*)d_in[21];
    const float* ab1 = (const float*)d_in[22];
    const float* ag1 = (const float*)d_in[23];
    const float* abe1= (const float*)d_in[24];
    const float* aw2 = (const float*)d_in[25];
    const float* ab2 = (const float*)d_in[26];
    const float* we  = (const float*)d_in[27];
    const float* be  = (const float*)d_in[28];
    float* out = (float*)d_out;

    char* wsb = (char*)d_ws;
    size_t off = 0;
    auto alloc = [&](size_t bytes) {
        void* p = wsb + off;
        off += (bytes + 255) & ~(size_t)255;
        return p;
    };
    const size_t M = (size_t)BB * NN * KK;  // 131072 rows
    int*   idx   = (int*)  alloc(M * 4);
    float* h1buf = (float*)alloc((size_t)BB * CC * NN * 4);
    float* value = (float*)alloc((size_t)BB * CC * NN * 4);
    float* kT    = (float*)alloc((size_t)BB * NN * DIMD * 4);
    float* qT    = (float*)alloc((size_t)BB * NN * DIMD * 4);
    float* vT    = (float*)alloc((size_t)BB * NN * DIMD * 4);
    float* aggT  = (float*)alloc((size_t)BB * NN * DIMD * 4);
    float* zero0 = (float*)alloc((size_t)(16 + 256 + 65536) * 4);
    float* stats = zero0;
    float* mu    = zero0 + 16;
    float* R     = zero0 + 16 + 256;
    float* posA  = (float*)alloc((size_t)2 * PHH * 4);
    float* attA  = (float*)alloc((size_t)2 * AHH * 4);
    ushort_t* w1b = (ushort_t*)alloc((size_t)AHH * DIMD * 2);
    ushort_t* w2b = (ushort_t*)alloc((size_t)DIMD * AHH * 2);
    ushort_t* pw2b = (ushort_t*)alloc((size_t)DIMD * PHH * 2);
    ushort_t* sb16 = (ushort_t*)alloc(M * DIMD * 2);          //  67 MB
    // overlay: p1buf (16.8 MB) used by p1/gemmS, then Rpart (33.5 MB) by rg/r_reduce
    char* ovl = (char*)alloc((size_t)RSPLIT * DIMD * DIMD * 4);
    ushort_t* p1buf = (ushort_t*)ovl;
    float*    Rpart = (float*)ovl;
    // total ~142 MB

    int ZN = 16 + 256 + 65536;
    zero_kernel<<<(ZN + 255) / 256, 256, 0, stream>>>(zero0, ZN);
    knn_kernel<<<BB * NN, 256, 0, stream>>>(pos, idx);
    h1_kernel<<<dim3(NN / 256, CC, BB), 256, 0, stream>>>(key, query, mlpv_w1, mlpv_b1, h1buf);
    value_kernel<<<dim3(NN / 256, CC, BB), 256, 0, stream>>>(key, query, h1buf, mlpv_w2, mlpv_b2, mlpv_ws, mlpv_bs, value);
    convT_kernel<<<dim3(NN / PT, BB), 256, 0, stream>>>(wk, bk, key, kT);
    convT_kernel<<<dim3(NN / PT, BB), 256, 0, stream>>>(wq, bq, query, qT);
    convT_kernel<<<dim3(NN / PT, BB), 256, 0, stream>>>(wv, bv, value, vT);
    pos_stats_kernel<<<BB * NN * KK / 256, 256, 0, stream>>>(pos, idx, stats);
    pos_bn_kernel<<<1, 64, 0, stream>>>(stats, pw1, pb1, pg1, pbe1, posA);
    cvt_w_kernel<<<(2 * AHH * DIMD + DIMD * PHH + 255) / 256, 256, 0, stream>>>(aw1, aw2, pw2, w1b, w2b, pw2b);
    p1_kernel<<<(int)(M * PHH / 256), 256, 0, stream>>>(pos, idx, pw1, pb1, posA, p1buf);
    gemmS_kernel<PHH><<<dim3(M / 128, DIMD / 128), 256, 0, stream>>>(p1buf, pw2b, pb2, sb16, qT, kT, idx);
    mu_kernel<<<M / 512, 256, 0, stream>>>(sb16, mu);
    rg_kernel<<<dim3(RSPLIT, 4), 256, 0, stream>>>(sb16, Rpart);
    r_reduce_kernel<<<DIMD * DIMD / 256, 256, 0, stream>>>(Rpart, R);
    attn_bn_kernel<<<AHH, DIMD, 0, stream>>>(R, mu, aw1, ab1, ag1, abe1, attA);
    fused_mlp_kernel<<<(int)(M / 64), 256, 0, stream>>>(sb16, w1b, w2b, attA, ab2, idx, qT, kT, vT, aggT);
    final_kernel<<<dim3(NN / (2 * FPT), BB), 256, 0, stream>>>(aggT, we, be, value, out);
}

// Round 10
// 704.064 us; speedup vs baseline: 7.8600x; 1.1710x over previous
//
#include <hip/hip_runtime.h>
#include <math.h>

#define BB 2
#define CC 128
#define NN 4096
#define KK 16
#define DIMD 256
#define PHH 64
#define AHH 1024
#define EPSF 1e-5f
#define RSPLIT 128
#define RKCH ((BB * NN * KK) / RSPLIT)   // 1024 samples per R block
#define LSTR 258    // LDS row stride (halfwords): conflict-free transposed gathers
#define KNN_CAP 512
#define FPT 8       // final_kernel points per thread

typedef unsigned short ushort_t;
typedef unsigned long long u64;
typedef __attribute__((ext_vector_type(8))) short short8;
typedef __attribute__((ext_vector_type(8))) unsigned short u16x8;
typedef __attribute__((ext_vector_type(4))) unsigned short u16x4;
typedef __attribute__((ext_vector_type(2))) unsigned short u16x2;
typedef __attribute__((ext_vector_type(4))) float f32x4;

__device__ __forceinline__ ushort_t f2b(float x) {
    union { float f; unsigned u; } v; v.f = x;
    unsigned r = v.u + 0x7fff + ((v.u >> 16) & 1);
    return (ushort_t)(r >> 16);
}
__device__ __forceinline__ float b2f(ushort_t x) {
    union { unsigned u; float f; } v; v.u = ((unsigned)x) << 16;
    return v.f;
}
__device__ __forceinline__ unsigned fsort(float x) {
    union { float f; unsigned u; } v; v.f = x;
    return v.u ^ ((v.u >> 31) ? 0xFFFFFFFFu : 0x80000000u);
}

#define GLDS16(gp, lp) __builtin_amdgcn_global_load_lds( \
    (const __attribute__((address_space(1))) void*)(gp), \
    (__attribute__((address_space(3))) void*)(lp), 16, 0, 0)

// ---------------- K0: zero scratch accumulators ----------------
__global__ void zero_kernel(float* p, int n) {
    int i = blockIdx.x * blockDim.x + threadIdx.x;
    if (i < n) p[i] = 0.f;
}

// ---------------- K1: exact kNN via u64-key threshold select ----------------
__global__ __launch_bounds__(256) void knn_kernel(const float* __restrict__ pos,
                                                  int* __restrict__ idx) {
    int bid = blockIdx.x;
    int b = bid / NN, n = bid % NN;
    int t = threadIdx.x;
    int lane = t & 63, w = t >> 6;
    const float* px = pos + (size_t)b * 3 * NN;
    const float* py = px + NN;
    const float* pz = px + 2 * NN;
    float qx = px[n], qy = py[n], qz = pz[n];
    float qs = qx * qx + qy * qy + qz * qz;

    u64 keys[KK];
    u64 lmin = ~0ull;
#pragma unroll
    for (int j = 0; j < KK; ++j) {
        int m = t + 256 * j;
        float mx = px[m], my = py[m], mz = pz[m];
        float ms = mx * mx + my * my + mz * mz;
        float dt = qx * mx + qy * my + qz * mz;
        float d = qs + ms - 2.f * dt;
        u64 k = ((u64)fsort(d) << 32) | (unsigned)m;
        keys[j] = k;
        lmin = k < lmin ? k : lmin;
    }

    __shared__ u64 T0s[4];
    __shared__ u64 pool[KNN_CAP];
    __shared__ int cnt;

    u64 k = lmin, m4 = 0;
#pragma unroll
    for (int r = 0; r < 4; ++r) {
        u64 mv = k;
#pragma unroll
        for (int off = 32; off >= 1; off >>= 1) {
            u64 o = __shfl_xor(mv, off);
            mv = o < mv ? o : mv;
        }
        if (r == 3) m4 = mv;
        if (k == mv) k = ~0ull;
    }
    if (lane == 0) T0s[w] = m4;
    if (t == 0) cnt = 0;
    __syncthreads();
    u64 T0 = T0s[0];
    T0 = T0s[1] > T0 ? T0s[1] : T0;
    T0 = T0s[2] > T0 ? T0s[2] : T0;
    T0 = T0s[3] > T0 ? T0s[3] : T0;

#pragma unroll
    for (int j = 0; j < KK; ++j) {
        if (keys[j] <= T0) {
            int p = atomicAdd(&cnt, 1);
            if (p < KNN_CAP) pool[p] = keys[j];
        }
    }
    __syncthreads();
    int C = cnt < KNN_CAP ? cnt : KNN_CAP;
    if (t < C) {
        u64 me = pool[t];
        int r = 0;
        for (int i = 0; i < C; ++i) r += (pool[i] < me);
        if (r < KK) idx[(size_t)bid * KK + r] = (int)(me & 0xFFFFFFFFu);
    }
}

// ---------------- K2: transpose key/query -> kqT bf16 (8192 x 256) ----------------
__global__ __launch_bounds__(256) void cvtx_kernel(const float* __restrict__ key,
                                                   const float* __restrict__ query,
                                                   ushort_t* __restrict__ kqT) {
    __shared__ float xs[128][65];
    int b = blockIdx.y, n0 = blockIdx.x * 64, t = threadIdx.x;
    for (int h = 0; h < 2; ++h) {
        const float* src = (h ? query : key) + (size_t)b * CC * NN;
        if (h) __syncthreads();
#pragma unroll
        for (int it = 0; it < 32; ++it) {
            int l = it * 256 + t;
            xs[l >> 6][l & 63] = src[(size_t)(l >> 6) * NN + n0 + (l & 63)];
        }
        __syncthreads();
#pragma unroll
        for (int it = 0; it < 8; ++it) {
            int l = it * 256 + t;
            int row = l >> 5, c0 = (l & 31) * 4;
            u16x4 pk;
            pk[0] = f2b(xs[c0][row]);
            pk[1] = f2b(xs[c0 + 1][row]);
            pk[2] = f2b(xs[c0 + 2][row]);
            pk[3] = f2b(xs[c0 + 3][row]);
            *(u16x4*)(kqT + ((size_t)b * NN + n0 + row) * 256 + h * 128 + c0) = pk;
        }
    }
}

// ---------------- K3: generic MFMA GEMM, 128x128 tile ----------------
// EPI 0: outB[r*OSTR+n] = bf16(relu(acc + bias[n]))
// EPI 1: outF[r*OSTR+n] = acc + bias[n]
template <int KLOOP, int ASTR, int EPI, int OSTR>
__global__ __launch_bounds__(256) void gemmT_kernel(const ushort_t* __restrict__ A,
                                                    const ushort_t* __restrict__ Bm,
                                                    const float* __restrict__ bias,
                                                    float* __restrict__ outF,
                                                    ushort_t* __restrict__ outB) {
    __shared__ ushort_t lA[128 * 32];
    __shared__ ushort_t lB[128 * 32];
    int t = threadIdx.x, lane = t & 63, w = t >> 6;
    int wr = w >> 1, wc = w & 1;
    size_t row0 = (size_t)blockIdx.x * 128;
    int col0 = blockIdx.y * 128;
    int m16 = lane & 15, kg = lane >> 4;
    f32x4 acc[4][4];
#pragma unroll
    for (int i = 0; i < 4; ++i)
#pragma unroll
        for (int j = 0; j < 4; ++j) acc[i][j] = (f32x4){0.f, 0.f, 0.f, 0.f};

    const ushort_t* gA = A + (row0 + (size_t)w * 16 + m16) * ASTR + kg * 8;
    const ushort_t* gB = Bm + ((size_t)(col0 + w * 16 + m16)) * KLOOP + kg * 8;
    ushort_t* lA0 = lA + w * 512;
    ushort_t* lB0 = lB + w * 512;
    for (int kt = 0; kt < KLOOP / 32; ++kt) {
        int ko = kt * 32;
        GLDS16(gA + ko, lA0);
        GLDS16(gA + (size_t)64 * ASTR + ko, lA0 + 2048);
        GLDS16(gB + ko, lB0);
        GLDS16(gB + (size_t)64 * KLOOP + ko, lB0 + 2048);
        __syncthreads();
        short8 af[4], bf[4];
#pragma unroll
        for (int i = 0; i < 4; ++i) {
            af[i] = *(const short8*)(lA + ((wr * 4 + i) * 512 + kg * 128 + m16 * 8));
            bf[i] = *(const short8*)(lB + ((wc * 4 + i) * 512 + kg * 128 + m16 * 8));
        }
#pragma unroll
        for (int i = 0; i < 4; ++i)
#pragma unroll
            for (int j = 0; j < 4; ++j)
                acc[i][j] = __builtin_amdgcn_mfma_f32_16x16x32_bf16(af[i], bf[j], acc[i][j], 0, 0, 0);
        __syncthreads();
    }
#pragma unroll
    for (int j = 0; j < 4; ++j) {
        int n = col0 + wc * 64 + j * 16 + m16;
        float bi = bias[n];
#pragma unroll
        for (int i = 0; i < 4; ++i) {
            size_t r = row0 + wr * 64 + i * 16 + kg * 4;
#pragma unroll
            for (int rg = 0; rg < 4; ++rg) {
                float v = acc[i][j][rg] + bi;
                if (EPI == 0) outB[(r + rg) * (size_t)OSTR + n] = f2b(fmaxf(v, 0.f));
                else          outF[(r + rg) * (size_t)OSTR + n] = v;
            }
        }
    }
}

// ---------------- K3b: value = Ws·kq + W2·h1 + b2 + bs (dual-K), fp32+bf16 out ------
__global__ __launch_bounds__(256) void gemmval_kernel(const ushort_t* __restrict__ kqT,
                                                      const ushort_t* __restrict__ h1T,
                                                      const ushort_t* __restrict__ wsb,
                                                      const ushort_t* __restrict__ w2vb,
                                                      const float* __restrict__ b2,
                                                      const float* __restrict__ bs,
                                                      float* __restrict__ valueTf,
                                                      ushort_t* __restrict__ valueTb) {
    __shared__ ushort_t lA[128 * 32];
    __shared__ ushort_t lB[128 * 32];
    int t = threadIdx.x, lane = t & 63, w = t >> 6;
    int wr = w >> 1, wc = w & 1;
    size_t row0 = (size_t)blockIdx.x * 128;
    int m16 = lane & 15, kg = lane >> 4;
    f32x4 acc[4][4];
#pragma unroll
    for (int i = 0; i < 4; ++i)
#pragma unroll
        for (int j = 0; j < 4; ++j) acc[i][j] = (f32x4){0.f, 0.f, 0.f, 0.f};
    ushort_t* lA0 = lA + w * 512;
    ushort_t* lB0 = lB + w * 512;

    // phase A: K=256 over kqT with Ws
    {
        const ushort_t* gA = kqT + (row0 + (size_t)w * 16 + m16) * 256 + kg * 8;
        const ushort_t* gB = wsb + ((size_t)(w * 16 + m16)) * 256 + kg * 8;
        for (int kt = 0; kt < 8; ++kt) {
            int ko = kt * 32;
            GLDS16(gA + ko, lA0);
            GLDS16(gA + (size_t)64 * 256 + ko, lA0 + 2048);
            GLDS16(gB + ko, lB0);
            GLDS16(gB + (size_t)64 * 256 + ko, lB0 + 2048);
            __syncthreads();
            short8 af[4], bf[4];
#pragma unroll
            for (int i = 0; i < 4; ++i) {
                af[i] = *(const short8*)(lA + ((wr * 4 + i) * 512 + kg * 128 + m16 * 8));
                bf[i] = *(const short8*)(lB + ((wc * 4 + i) * 512 + kg * 128 + m16 * 8));
            }
#pragma unroll
            for (int i = 0; i < 4; ++i)
#pragma unroll
                for (int j = 0; j < 4; ++j)
                    acc[i][j] = __builtin_amdgcn_mfma_f32_16x16x32_bf16(af[i], bf[j], acc[i][j], 0, 0, 0);
            __syncthreads();
        }
    }
    // phase B: K=128 over h1T with W2
    {
        const ushort_t* gA = h1T + (row0 + (size_t)w * 16 + m16) * 128 + kg * 8;
        const ushort_t* gB = w2vb + ((size_t)(w * 16 + m16)) * 128 + kg * 8;
        for (int kt = 0; kt < 4; ++kt) {
            int ko = kt * 32;
            GLDS16(gA + ko, lA0);
            GLDS16(gA + (size_t)64 * 128 + ko, lA0 + 2048);
            GLDS16(gB + ko, lB0);
            GLDS16(gB + (size_t)64 * 128 + ko, lB0 + 2048);
            __syncthreads();
            short8 af[4], bf[4];
#pragma unroll
            for (int i = 0; i < 4; ++i) {
                af[i] = *(const short8*)(lA + ((wr * 4 + i) * 512 + kg * 128 + m16 * 8));
                bf[i] = *(const short8*)(lB + ((wc * 4 + i) * 512 + kg * 128 + m16 * 8));
            }
#pragma unroll
            for (int i = 0; i < 4; ++i)
#pragma unroll
                for (int j = 0; j < 4; ++j)
                    acc[i][j] = __builtin_amdgcn_mfma_f32_16x16x32_bf16(af[i], bf[j], acc[i][j], 0, 0, 0);
            __syncthreads();
        }
    }
#pragma unroll
    for (int j = 0; j < 4; ++j) {
        int n = wc * 64 + j * 16 + m16;
        float bi = b2[n] + bs[n];
#pragma unroll
        for (int i = 0; i < 4; ++i) {
            size_t r = row0 + wr * 64 + i * 16 + kg * 4;
#pragma unroll
            for (int rg = 0; rg < 4; ++rg) {
                float v = acc[i][j][rg] + bi;
                valueTf[(r + rg) * (size_t)CC + n] = v;
                valueTb[(r + rg) * (size_t)CC + n] = f2b(v);
            }
        }
    }
}

// ---------------- K3c: kT and qT in one launch (grid.y: 0,1=kT cols; 2,3=qT) --------
__global__ __launch_bounds__(256) void gemmkq_kernel(const ushort_t* __restrict__ kqT,
                                                     const ushort_t* __restrict__ wkb,
                                                     const ushort_t* __restrict__ wqb,
                                                     const float* __restrict__ bk,
                                                     const float* __restrict__ bq,
                                                     float* __restrict__ kT,
                                                     float* __restrict__ qT) {
    __shared__ ushort_t lA[128 * 32];
    __shared__ ushort_t lB[128 * 32];
    int half = blockIdx.y >> 1;
    int col0 = (blockIdx.y & 1) * 128;
    const ushort_t* A = kqT + half * 128;
    const ushort_t* Bm = half ? wqb : wkb;
    const float* bias = half ? bq : bk;
    float* outF = half ? qT : kT;

    int t = threadIdx.x, lane = t & 63, w = t >> 6;
    int wr = w >> 1, wc = w & 1;
    size_t row0 = (size_t)blockIdx.x * 128;
    int m16 = lane & 15, kg = lane >> 4;
    f32x4 acc[4][4];
#pragma unroll
    for (int i = 0; i < 4; ++i)
#pragma unroll
        for (int j = 0; j < 4; ++j) acc[i][j] = (f32x4){0.f, 0.f, 0.f, 0.f};
    const ushort_t* gA = A + (row0 + (size_t)w * 16 + m16) * 256 + kg * 8;
    const ushort_t* gB = Bm + ((size_t)(col0 + w * 16 + m16)) * 128 + kg * 8;
    ushort_t* lA0 = lA + w * 512;
    ushort_t* lB0 = lB + w * 512;
    for (int kt = 0; kt < 4; ++kt) {
        int ko = kt * 32;
        GLDS16(gA + ko, lA0);
        GLDS16(gA + (size_t)64 * 256 + ko, lA0 + 2048);
        GLDS16(gB + ko, lB0);
        GLDS16(gB + (size_t)64 * 128 + ko, lB0 + 2048);
        __syncthreads();
        short8 af[4], bf[4];
#pragma unroll
        for (int i = 0; i < 4; ++i) {
            af[i] = *(const short8*)(lA + ((wr * 4 + i) * 512 + kg * 128 + m16 * 8));
            bf[i] = *(const short8*)(lB + ((wc * 4 + i) * 512 + kg * 128 + m16 * 8));
        }
#pragma unroll
        for (int i = 0; i < 4; ++i)
#pragma unroll
            for (int j = 0; j < 4; ++j)
                acc[i][j] = __builtin_amdgcn_mfma_f32_16x16x32_bf16(af[i], bf[j], acc[i][j], 0, 0, 0);
        __syncthreads();
    }
#pragma unroll
    for (int j = 0; j < 4; ++j) {
        int n = col0 + wc * 64 + j * 16 + m16;
        float bi = bias[n];
#pragma unroll
        for (int i = 0; i < 4; ++i) {
            size_t r = row0 + wr * 64 + i * 16 + kg * 4;
#pragma unroll
            for (int rg = 0; rg < 4; ++rg)
                outF[(r + rg) * (size_t)DIMD + n] = acc[i][j][rg] + bi;
        }
    }
}

// ---------------- K5: pos_rel first/second moments (9 sums) ----------------
__global__ __launch_bounds__(256) void pos_stats_kernel(const float* __restrict__ pos,
                                                        const int* __restrict__ idx,
                                                        float* __restrict__ stats) {
    int sid = blockIdx.x * 256 + threadIdx.x;
    int b = sid / (NN * KK);
    int r = sid % (NN * KK);
    int n = r / KK;
    int m = idx[sid];
    const float* px = pos + (size_t)b * 3 * NN;
    float dx = px[n] - px[m];
    float dy = px[NN + n] - px[NN + m];
    float dz = px[2 * NN + n] - px[2 * NN + m];
    float v[9] = {dx, dy, dz, dx * dx, dy * dy, dz * dz, dx * dy, dx * dz, dy * dz};
    __shared__ float red[256];
    for (int j = 0; j < 9; ++j) {
        red[threadIdx.x] = v[j];
        __syncthreads();
        for (int off = 128; off >= 1; off >>= 1) {
            if (threadIdx.x < off) red[threadIdx.x] += red[threadIdx.x + off];
            __syncthreads();
        }
        if (threadIdx.x == 0) atomicAdd(&stats[j], red[0]);
        __syncthreads();
    }
}

// ---------------- K6: pos BN affine (a1, a0) per 64 channels ----------------
__global__ void pos_bn_kernel(const float* __restrict__ stats, const float* __restrict__ pw1,
                              const float* __restrict__ pb1, const float* __restrict__ pg1,
                              const float* __restrict__ pbe1, float* __restrict__ posA) {
    int c = threadIdx.x;
    if (c >= PHH) return;
    float M = (float)(BB * NN * KK);
    float mu0 = stats[0] / M, mu1 = stats[1] / M, mu2 = stats[2] / M;
    float E00 = stats[3] / M, E11 = stats[4] / M, E22 = stats[5] / M;
    float E01 = stats[6] / M, E02 = stats[7] / M, E12 = stats[8] / M;
    float w0 = pw1[c * 3], w1 = pw1[c * 3 + 1], w2 = pw1[c * 3 + 2];
    float wmu = w0 * mu0 + w1 * mu1 + w2 * mu2;
    float mean_h = wmu + pb1[c];
    float Eh2 = w0 * w0 * E00 + w1 * w1 * E11 + w2 * w2 * E22
              + 2.f * (w0 * w1 * E01 + w0 * w2 * E02 + w1 * w2 * E12)
              + 2.f * pb1[c] * wmu + pb1[c] * pb1[c];
    float var = Eh2 - mean_h * mean_h;
    float a1 = pg1[c] * rsqrtf(var + EPSF);
    posA[c] = a1;
    posA[PHH + c] = pbe1[c] - mean_h * a1;
}

// ---------------- K7a: P1 = relu(BNaffine(pw1 . pos_rel)) bf16 (M x 64) ----------------
__global__ __launch_bounds__(256) void p1_kernel(const float* __restrict__ pos,
                                                 const int* __restrict__ idx,
                                                 const float* __restrict__ pw1,
                                                 const float* __restrict__ pb1,
                                                 const float* __restrict__ posA,
                                                 ushort_t* __restrict__ p1) {
    int gid = blockIdx.x * 256 + threadIdx.x;
    int samp = gid >> 6, c = gid & 63;
    int p = samp >> 4;
    int b = p >> 12, n = p & (NN - 1);
    int m = idx[samp];
    const float* px = pos + (size_t)b * 3 * NN;
    float dx = px[n] - px[m];
    float dy = px[NN + n] - px[NN + m];
    float dz = px[2 * NN + n] - px[2 * NN + m];
    float h = pw1[c * 3] * dx + pw1[c * 3 + 1] * dy + pw1[c * 3 + 2] * dz + pb1[c];
    p1[gid] = f2b(fmaxf(h * posA[c] + posA[PHH + c], 0.f));
}

// ---------------- K8: mu = column sums of s ----------------
__global__ __launch_bounds__(256) void mu_kernel(const ushort_t* __restrict__ sb16,
                                                 float* __restrict__ mu) {
    int c = threadIdx.x;
    const ushort_t* p = sb16 + (size_t)blockIdx.x * 512 * DIMD + c;
    float acc = 0.f;
    for (int i = 0; i < 512; ++i) acc += b2f(p[(size_t)i * DIMD]);
    atomicAdd(&mu[c], acc);
}

// ---------------- K9: R partials via MFMA ----------------
__global__ __launch_bounds__(256) void rg_kernel(const ushort_t* __restrict__ S,
                                                 float* __restrict__ Rpart) {
    __shared__ ushort_t ls[32 * LSTR];
    int t = threadIdx.x;
    int lane = t & 63, w = t >> 6;
    int wr = w >> 1, wc = w & 1;
    int ti = blockIdx.y >> 1, tj = blockIdx.y & 1;
    int m16 = lane & 15, kg = lane >> 4;
    size_t kbase = (size_t)blockIdx.x * RKCH;

    f32x4 acc[4][4];
#pragma unroll
    for (int i = 0; i < 4; ++i)
#pragma unroll
        for (int j = 0; j < 4; ++j) acc[i][j] = (f32x4){0.f, 0.f, 0.f, 0.f};

    int lm = t >> 3;
    int lc = (t & 7) * 32;
    const ushort_t* gS = S + (kbase + lm) * DIMD + lc;
    ushort_t* lp = ls + lm * LSTR + lc;

    for (int kt = 0; kt < RKCH / 32; ++kt) {
        const ushort_t* gp = gS + (size_t)kt * 32 * DIMD;
        u16x8 v0 = *(const u16x8*)(gp);
        u16x8 v1 = *(const u16x8*)(gp + 8);
        u16x8 v2 = *(const u16x8*)(gp + 16);
        u16x8 v3 = *(const u16x8*)(gp + 24);
        __syncthreads();
#pragma unroll
        for (int q = 0; q < 4; ++q) {
            *(u16x2*)(lp + 0 + 2 * q) = (u16x2){v0[2 * q], v0[2 * q + 1]};
            *(u16x2*)(lp + 8 + 2 * q) = (u16x2){v1[2 * q], v1[2 * q + 1]};
            *(u16x2*)(lp + 16 + 2 * q) = (u16x2){v2[2 * q], v2[2 * q + 1]};
            *(u16x2*)(lp + 24 + 2 * q) = (u16x2){v3[2 * q], v3[2 * q + 1]};
        }
        __syncthreads();
        short8 af[4], bf[4];
#pragma unroll
        for (int i = 0; i < 4; ++i) {
            int chA = ti * 128 + wr * 64 + i * 16 + m16;
            int chB = tj * 128 + wc * 64 + i * 16 + m16;
#pragma unroll
            for (int j = 0; j < 8; ++j) {
                int k = kg * 8 + j;
                af[i][j] = (short)ls[k * LSTR + chA];
                bf[i][j] = (short)ls[k * LSTR + chB];
            }
        }
#pragma unroll
        for (int i = 0; i < 4; ++i)
#pragma unroll
            for (int j = 0; j < 4; ++j)
                acc[i][j] = __builtin_amdgcn_mfma_f32_16x16x32_bf16(af[i], bf[j], acc[i][j], 0, 0, 0);
    }

    float* rp = Rpart + (size_t)blockIdx.x * (DIMD * DIMD);
#pragma unroll
    for (int i = 0; i < 4; ++i) {
        int r0 = ti * 128 + wr * 64 + i * 16 + kg * 4;
#pragma unroll
        for (int j = 0; j < 4; ++j) {
            int cn = tj * 128 + wc * 64 + j * 16 + m16;
#pragma unroll
            for (int rg = 0; rg < 4; ++rg)
                rp[(size_t)(r0 + rg) * DIMD + cn] = acc[i][j][rg];
        }
    }
}

// ---------------- K9b: reduce R partials ----------------
__global__ __launch_bounds__(256) void r_reduce_kernel(const float* __restrict__ Rpart,
                                                       float* __restrict__ R) {
    int e = blockIdx.x * 256 + threadIdx.x;
    float s = 0.f;
    for (int p = 0; p < RSPLIT; ++p) s += Rpart[(size_t)p * (DIMD * DIMD) + e];
    R[e] = s;
}

// ---------------- K10: attn BN -> fused scale/offset per hidden channel ----------------
__global__ __launch_bounds__(256) void attn_bn_kernel(const float* __restrict__ R,
                                                      const float* __restrict__ mu,
                                                      const float* __restrict__ aw1,
                                                      const float* __restrict__ ab1,
                                                      const float* __restrict__ ag1,
                                                      const float* __restrict__ abe1,
                                                      float* __restrict__ attA) {
    int c = blockIdx.x;
    int t = threadIdx.x;
    __shared__ float wsh[DIMD];
    __shared__ float red[DIMD];
    wsh[t] = aw1[(size_t)c * DIMD + t];
    __syncthreads();
    const float* Rr = R + (size_t)t * DIMD;
    float q = 0.f;
#pragma unroll 4
    for (int j = 0; j < DIMD; ++j) q += Rr[j] * wsh[j];
    red[t] = q * wsh[t];
    __syncthreads();
    for (int off = 128; off >= 1; off >>= 1) {
        if (t < off) red[t] += red[t + off];
        __syncthreads();
    }
    float wRw = red[0];
    __syncthreads();
    red[t] = wsh[t] * mu[t];
    __syncthreads();
    for (int off = 128; off >= 1; off >>= 1) {
        if (t < off) red[t] += red[t + off];
        __syncthreads();
    }
    if (t == 0) {
        float M = (float)(BB * NN * KK);
        float wmu = red[0] / M;
        float b1c = ab1[c];
        float Eh = wmu + b1c;
        float Eh2 = wRw / M + 2.f * b1c * wmu + b1c * b1c;
        float var = Eh2 - Eh * Eh;
        float a1 = ag1[c] * rsqrtf(var + EPSF);
        attA[c] = a1;
        attA[AHH + c] = a1 * b1c + abe1[c] - Eh * a1;
    }
}

// ---------------- K10b: convert all weights to bf16 ----------------
__global__ void cvt_w_kernel(const float* __restrict__ aw1, const float* __restrict__ aw2,
                             const float* __restrict__ pw2,
                             const float* __restrict__ mw1, const float* __restrict__ mws,
                             const float* __restrict__ mw2,
                             const float* __restrict__ wk, const float* __restrict__ wq,
                             const float* __restrict__ wv,
                             ushort_t* __restrict__ w1b, ushort_t* __restrict__ w2b,
                             ushort_t* __restrict__ pw2b,
                             ushort_t* __restrict__ w1vb, ushort_t* __restrict__ wsvb,
                             ushort_t* __restrict__ w2vb,
                             ushort_t* __restrict__ wkb, ushort_t* __restrict__ wqb,
                             ushort_t* __restrict__ wvb) {
    int i = blockIdx.x * 256 + threadIdx.x;
    int o = i;
    if (o < 262144) { w1b[o] = f2b(aw1[o]); return; }   o -= 262144;
    if (o < 262144) { w2b[o] = f2b(aw2[o]); return; }   o -= 262144;
    if (o < 16384)  { pw2b[o] = f2b(pw2[o]); return; }  o -= 16384;
    if (o < 32768)  { w1vb[o] = f2b(mw1[o]); return; }  o -= 32768;
    if (o < 32768)  { wsvb[o] = f2b(mws[o]); return; }  o -= 32768;
    if (o < 16384)  { w2vb[o] = f2b(mw2[o]); return; }  o -= 16384;
    if (o < 32768)  { wkb[o] = f2b(wk[o]); return; }    o -= 32768;
    if (o < 32768)  { wqb[o] = f2b(wq[o]); return; }    o -= 32768;
    if (o < 32768)  { wvb[o] = f2b(wv[o]); }
}

// ---------------- MFMA GEMM (s-build): s = q - k_g + (P1·pw2^T + pb2) ----------------
template <int KDIM>
__global__ __launch_bounds__(256) void gemmS_kernel(const ushort_t* __restrict__ A,
                                                    const ushort_t* __restrict__ Bm,
                                                    const float* __restrict__ p0,
                                                    ushort_t* __restrict__ Sb,
                                                    const float* __restrict__ qT,
                                                    const float* __restrict__ kT,
                                                    const int* __restrict__ gidx) {
    __shared__ ushort_t lA[128 * 32];
    __shared__ ushort_t lB[128 * 32];
    int t = threadIdx.x;
    int lane = t & 63, w = t >> 6;
    int wr = w >> 1, wc = w & 1;
    size_t row0 = (size_t)blockIdx.x * 128;
    int col0 = blockIdx.y * 128;
    int m16 = lane & 15, kg = lane >> 4;

    f32x4 acc[4][4];
#pragma unroll
    for (int i = 0; i < 4; ++i)
#pragma unroll
        for (int j = 0; j < 4; ++j) acc[i][j] = (f32x4){0.f, 0.f, 0.f, 0.f};

    const ushort_t* gA = A + (row0 + (size_t)w * 16 + m16) * KDIM + kg * 8;
    const ushort_t* gB = Bm + ((size_t)(col0 + w * 16 + m16)) * KDIM + kg * 8;
    ushort_t* lA0 = lA + w * 512;
    ushort_t* lB0 = lB + w * 512;

    for (int kt = 0; kt < KDIM / 32; ++kt) {
        int ko = kt * 32;
        GLDS16(gA + ko, lA0);
        GLDS16(gA + (size_t)64 * KDIM + ko, lA0 + 2048);
        GLDS16(gB + ko, lB0);
        GLDS16(gB + (size_t)64 * KDIM + ko, lB0 + 2048);
        __syncthreads();
        short8 af[4], bf[4];
#pragma unroll
        for (int i = 0; i < 4; ++i) {
            af[i] = *(const short8*)(lA + ((wr * 4 + i) * 512 + kg * 128 + m16 * 8));
            bf[i] = *(const short8*)(lB + ((wc * 4 + i) * 512 + kg * 128 + m16 * 8));
        }
#pragma unroll
        for (int i = 0; i < 4; ++i)
#pragma unroll
            for (int j = 0; j < 4; ++j)
                acc[i][j] = __builtin_amdgcn_mfma_f32_16x16x32_bf16(af[i], bf[j], acc[i][j], 0, 0, 0);
        __syncthreads();
    }

    int nn[4]; float bi[4];
#pragma unroll
    for (int j = 0; j < 4; ++j) { nn[j] = col0 + wc * 64 + j * 16 + m16; bi[j] = p0[nn[j]]; }
#pragma unroll
    for (int i = 0; i < 4; ++i) {
        size_t r = row0 + wr * 64 + i * 16 + kg * 4;
#pragma unroll
        for (int rg = 0; rg < 4; ++rg) {
            size_t rr = r + rg;
            int p = (int)(rr >> 4);
            int krow = (p & ~(NN - 1)) + gidx[rr];
            const float* qrow = qT + (size_t)p * DIMD;
            const float* kro = kT + (size_t)krow * DIMD;
#pragma unroll
            for (int j = 0; j < 4; ++j) {
                float sv = qrow[nn[j]] - kro[nn[j]] + acc[i][j][rg] + bi[j];
                Sb[rr * (size_t)DIMD + nn[j]] = f2b(sv);
            }
        }
    }
}

// ---------------- K11: fused attn MLP + softmax + aggregation (v3) ----------------
// 48 KB LDS (3 blocks/CU): lS 32K + single lHt 16K; logits stored bf16 transposed
// (stride 72) overlaid on dead lS+lHt; phase-2 softmax/agg per out-channel.
__global__ __launch_bounds__(256) void fused_mlp_kernel(const ushort_t* __restrict__ S,
                                                        const ushort_t* __restrict__ w1b,
                                                        const ushort_t* __restrict__ w2b,
                                                        const float* __restrict__ attA,
                                                        const float* __restrict__ ab2,
                                                        const int* __restrict__ idx,
                                                        const float* __restrict__ qT,
                                                        const float* __restrict__ kT,
                                                        const float* __restrict__ vT,
                                                        float* __restrict__ aggT) {
    __shared__ char smem[49152];
    ushort_t* lS  = (ushort_t*)smem;             // 32 KB
    ushort_t* lHt = (ushort_t*)(smem + 32768);   // 16 KB single buffer
    ushort_t* lgB = (ushort_t*)smem;             // epilogue: 256 out x 64 smp, stride 72

    int t = threadIdx.x;
    int lane = t & 63, w = t >> 6;
    int m16 = lane & 15, kg = lane >> 4;
    size_t row0 = (size_t)blockIdx.x * 64;

#pragma unroll
    for (int i = 0; i < 8; ++i) {
        int lb = w * 8 + i;
        int kt = lb >> 2, st = lb & 3;
        const ushort_t* gp = S + (row0 + st * 16 + m16) * DIMD + kt * 32 + kg * 8;
        GLDS16(gp, lS + lb * 512);
    }

    f32x4 acc2[4][4];
#pragma unroll
    for (int i = 0; i < 4; ++i)
#pragma unroll
        for (int j = 0; j < 4; ++j) acc2[i][j] = (f32x4){0.f, 0.f, 0.f, 0.f};

    __syncthreads();

    for (int jc = 0; jc < 8; ++jc) {
        f32x4 acc1[2][4];
#pragma unroll
        for (int hi = 0; hi < 2; ++hi)
#pragma unroll
            for (int sj = 0; sj < 4; ++sj) acc1[hi][sj] = (f32x4){0.f, 0.f, 0.f, 0.f};
#pragma unroll
        for (int kt = 0; kt < 8; ++kt) {
            short8 af[2], bf[4];
#pragma unroll
            for (int hi = 0; hi < 2; ++hi)
                af[hi] = *(const short8*)(w1b + ((size_t)(jc * 128 + w * 32 + hi * 16 + m16)) * DIMD + kt * 32 + kg * 8);
#pragma unroll
            for (int sj = 0; sj < 4; ++sj)
                bf[sj] = *(const short8*)(lS + (kt * 4 + sj) * 512 + kg * 128 + m16 * 8);
#pragma unroll
            for (int hi = 0; hi < 2; ++hi)
#pragma unroll
                for (int sj = 0; sj < 4; ++sj)
                    acc1[hi][sj] = __builtin_amdgcn_mfma_f32_16x16x32_bf16(af[hi], bf[sj], acc1[hi][sj], 0, 0, 0);
        }
        __syncthreads();   // prior GEMM2 reads of lHt complete
#pragma unroll
        for (int hi = 0; hi < 2; ++hi) {
            float4 sc4 = *(const float4*)(attA + jc * 128 + w * 32 + hi * 16 + kg * 4);
            float4 of4 = *(const float4*)(attA + AHH + jc * 128 + w * 32 + hi * 16 + kg * 4);
#pragma unroll
            for (int sj = 0; sj < 4; ++sj) {
                u16x4 pk;
                pk[0] = f2b(fmaxf(sc4.x * acc1[hi][sj][0] + of4.x, 0.f));
                pk[1] = f2b(fmaxf(sc4.y * acc1[hi][sj][1] + of4.y, 0.f));
                pk[2] = f2b(fmaxf(sc4.z * acc1[hi][sj][2] + of4.z, 0.f));
                pk[3] = f2b(fmaxf(sc4.w * acc1[hi][sj][3] + of4.w, 0.f));
                int ah = (w * 4 + sj) * 512 + (hi * 2 + (kg >> 1)) * 128 + m16 * 8 + (kg & 1) * 4;
                *(u16x4*)(lHt + ah) = pk;
            }
        }
        __syncthreads();
#pragma unroll
        for (int g = 0; g < 4; ++g) {
            short8 af2[4], bf2[4];
#pragma unroll
            for (int oi = 0; oi < 4; ++oi)
                af2[oi] = *(const short8*)(w2b + ((size_t)(w * 64 + oi * 16 + m16)) * AHH + jc * 128 + g * 32 + kg * 8);
#pragma unroll
            for (int sj = 0; sj < 4; ++sj)
                bf2[sj] = *(const short8*)(lHt + (g * 4 + sj) * 512 + kg * 128 + m16 * 8);
#pragma unroll
            for (int oi = 0; oi < 4; ++oi)
#pragma unroll
                for (int sj = 0; sj < 4; ++sj)
                    acc2[oi][sj] = __builtin_amdgcn_mfma_f32_16x16x32_bf16(af2[oi], bf2[sj], acc2[oi][sj], 0, 0, 0);
        }
    }
    __syncthreads();

    // phase 1: logits -> lgB[out][smp] (bf16, stride 72)
#pragma unroll
    for (int oi = 0; oi < 4; ++oi) {
        int ob = w * 64 + oi * 16 + kg * 4;
        float4 b2v = *(const float4*)(ab2 + ob);
#pragma unroll
        for (int sj = 0; sj < 4; ++sj) {
            int smp = sj * 16 + m16;
            lgB[(ob + 0) * 72 + smp] = f2b(acc2[oi][sj][0] + b2v.x);
            lgB[(ob + 1) * 72 + smp] = f2b(acc2[oi][sj][1] + b2v.y);
            lgB[(ob + 2) * 72 + smp] = f2b(acc2[oi][sj][2] + b2v.z);
            lgB[(ob + 3) * 72 + smp] = f2b(acc2[oi][sj][3] + b2v.w);
        }
    }
    __syncthreads();

    // phase 2: thread t owns out-channel t; 4 points; serial softmax in regs.
    int out = t;
    for (int pt = 0; pt < 4; ++pt) {
        int pid = (int)(row0 >> 4) + pt;
        u16x8 v0 = *(const u16x8*)(lgB + out * 72 + pt * 16);
        u16x8 v1 = *(const u16x8*)(lgB + out * 72 + pt * 16 + 8);
        float lg[KK];
#pragma unroll
        for (int s = 0; s < 8; ++s) { lg[s] = b2f(v0[s]); lg[s + 8] = b2f(v1[s]); }
        float mx = lg[0];
#pragma unroll
        for (int s = 1; s < KK; ++s) mx = fmaxf(mx, lg[s]);
        float se = 0.f;
#pragma unroll
        for (int s = 0; s < KK; ++s) { lg[s] = expf(lg[s] - mx); se += lg[s]; }
        float inv = 1.f / se;
        int base = pid & ~(NN - 1);
        float acc = 0.f;
#pragma unroll
        for (int s = 0; s < KK; ++s) {
            int row = pid * KK + s;
            int krow = base + idx[row];
            float sv = b2f(S[(size_t)row * DIMD + out]);
            float kv = kT[(size_t)krow * DIMD + out];
            acc += lg[s] * (sv + kv);
        }
        float vf = vT[(size_t)pid * DIMD + out];
        float q  = qT[(size_t)pid * DIMD + out];
        aggT[(size_t)pid * DIMD + out] = vf - q + acc * inv;
    }
}

// ---------------- K12: y = we·agg + be + value (both LDS-staged, coalesced) --------
__global__ __launch_bounds__(256) void final_kernel(const float* __restrict__ aggT,
                                                    const float* __restrict__ we,
                                                    const float* __restrict__ be,
                                                    const float* __restrict__ valueTf,
                                                    float* __restrict__ out) {
    __shared__ float xs[2 * FPT][DIMD];
    __shared__ float vs[2 * FPT][CC];
    int b = blockIdx.y;
    int n0 = blockIdx.x * (2 * FPT);
    int t = threadIdx.x;
    const float4* src = (const float4*)(aggT + ((size_t)b * NN + n0) * DIMD);
    float4* dst = (float4*)xs;
#pragma unroll
    for (int l = 0; l < (2 * FPT * DIMD / 4) / 256; ++l) dst[t + 256 * l] = src[t + 256 * l];
    const float4* src2 = (const float4*)(valueTf + ((size_t)b * NN + n0) * CC);
    float4* dst2 = (float4*)vs;
#pragma unroll
    for (int l = 0; l < (2 * FPT * CC / 4) / 256; ++l) dst2[t + 256 * l] = src2[t + 256 * l];
    __syncthreads();
    int o = t & 127, ph = t >> 7;
    float acc[FPT];
#pragma unroll
    for (int p = 0; p < FPT; ++p) acc[p] = 0.f;
    const float4* wr = (const float4*)(we + (size_t)o * DIMD);
#pragma unroll 8
    for (int i4 = 0; i4 < DIMD / 4; ++i4) {
        float4 w4 = wr[i4];
#pragma unroll
        for (int p = 0; p < FPT; ++p) {
            float4 x4 = *(const float4*)&xs[ph * FPT + p][i4 * 4];
            acc[p] += w4.x * x4.x + w4.y * x4.y + w4.z * x4.z + w4.w * x4.w;
        }
    }
    float bo = be[o];
#pragma unroll
    for (int p = 0; p < FPT; ++p) {
        size_t oi = ((size_t)b * CC + o) * NN + n0 + ph * FPT + p;
        out[oi] = acc[p] + bo + vs[ph * FPT + p][o];
    }
}

extern "C" void kernel_launch(void* const* d_in, const int* in_sizes, int n_in,
                              void* d_out, int out_size, void* d_ws, size_t ws_size,
                              hipStream_t stream) {
    (void)in_sizes; (void)n_in; (void)out_size; (void)ws_size;
    const float* pos     = (const float*)d_in[0];
    const float* key     = (const float*)d_in[1];
    const float* query   = (const float*)d_in[2];
    const float* mlpv_w1 = (const float*)d_in[3];
    const float* mlpv_b1 = (const float*)d_in[4];
    const float* mlpv_w2 = (const float*)d_in[5];
    const float* mlpv_b2 = (const float*)d_in[6];
    const float* mlpv_ws = (const float*)d_in[7];
    const float* mlpv_bs = (const float*)d_in[8];
    const float* wk  = (const float*)d_in[9];
    const float* bk  = (const float*)d_in[10];
    const float* wq  = (const float*)d_in[11];
    const float* bq  = (const float*)d_in[12];
    const float* wv  = (const float*)d_in[13];
    const float* bv  = (const float*)d_in[14];
    const float* pw1 = (const float*)d_in[15];
    const float* pb1 = (const float*)d_in[16];
    const float* pg1 = (const float*)d_in[17];
    const float* pbe1= (const float*)d_in[18];
    const float* pw2 = (const float*)d_in[19];
    const float* pb2 = (const float*)d_in[20];
    const float* aw1 = (const float*)d_in[21];
    const float* ab1 = (const float*)d_in[22];
    const float* ag1 = (const float*)d_in[23];
    const float* abe1= (const float*)d_in[24];
    const float* aw2 = (const float*)d_in[25];
    const float* ab2 = (const float*)d_in[26];
    const float* we  = (const float*)d_in[27];
    const float* be  = (const float*)d_in[28];
    float* out = (float*)d_out;

    char* wsb = (char*)d_ws;
    size_t off = 0;
    auto alloc = [&](size_t bytes) {
        void* p = wsb + off;
        off += (bytes + 255) & ~(size_t)255;
        return p;
    };
    const size_t M = (size_t)BB * NN * KK;   // 131072 rows
    const size_t P = (size_t)BB * NN;        // 8192 points
    int*   idx   = (int*)  alloc(M * 4);
    ushort_t* kqT     = (ushort_t*)alloc(P * 256 * 2);
    ushort_t* h1T     = (ushort_t*)alloc(P * CC * 2);
    float*    valueTf = (float*)   alloc(P * CC * 4);
    ushort_t* valueTb = (ushort_t*)alloc(P * CC * 2);
    float* kT    = (float*)alloc(P * DIMD * 4);
    float* qT    = (float*)alloc(P * DIMD * 4);
    float* vT    = (float*)alloc(P * DIMD * 4);
    float* aggT  = (float*)alloc(P * DIMD * 4);
    float* zero0 = (float*)alloc((size_t)(16 + 256 + 65536) * 4);
    float* stats = zero0;
    float* mu    = zero0 + 16;
    float* R     = zero0 + 16 + 256;
    float* posA  = (float*)alloc((size_t)2 * PHH * 4);
    float* attA  = (float*)alloc((size_t)2 * AHH * 4);
    ushort_t* w1b  = (ushort_t*)alloc((size_t)AHH * DIMD * 2);
    ushort_t* w2b  = (ushort_t*)alloc((size_t)DIMD * AHH * 2);
    ushort_t* pw2b = (ushort_t*)alloc((size_t)DIMD * PHH * 2);
    ushort_t* w1vb = (ushort_t*)alloc((size_t)CC * 256 * 2);
    ushort_t* wsvb = (ushort_t*)alloc((size_t)CC * 256 * 2);
    ushort_t* w2vb = (ushort_t*)alloc((size_t)CC * CC * 2);
    ushort_t* wkb  = (ushort_t*)alloc((size_t)DIMD * CC * 2);
    ushort_t* wqb  = (ushort_t*)alloc((size_t)DIMD * CC * 2);
    ushort_t* wvb  = (ushort_t*)alloc((size_t)DIMD * CC * 2);
    ushort_t* sb16 = (ushort_t*)alloc(M * DIMD * 2);          //  67 MB
    char* ovl = (char*)alloc((size_t)RSPLIT * DIMD * DIMD * 4);
    ushort_t* p1buf = (ushort_t*)ovl;
    float*    Rpart = (float*)ovl;

    int ZN = 16 + 256 + 65536;
    zero_kernel<<<(ZN + 255) / 256, 256, 0, stream>>>(zero0, ZN);
    knn_kernel<<<BB * NN, 256, 0, stream>>>(pos, idx);
    cvt_w_kernel<<<(720896 + 255) / 256, 256, 0, stream>>>(aw1, aw2, pw2, mlpv_w1, mlpv_ws, mlpv_w2,
                                                           wk, wq, wv, w1b, w2b, pw2b,
                                                           w1vb, wsvb, w2vb, wkb, wqb, wvb);
    cvtx_kernel<<<dim3(NN / 64, BB), 256, 0, stream>>>(key, query, kqT);
    gemmT_kernel<256, 256, 0, 128><<<dim3(P / 128, 1), 256, 0, stream>>>(kqT, w1vb, mlpv_b1, nullptr, h1T);
    gemmval_kernel<<<dim3(P / 128, 1), 256, 0, stream>>>(kqT, h1T, wsvb, w2vb, mlpv_b2, mlpv_bs, valueTf, valueTb);
    gemmkq_kernel<<<dim3(P / 128, 4), 256, 0, stream>>>(kqT, wkb, wqb, bk, bq, kT, qT);
    gemmT_kernel<128, 128, 1, 256><<<dim3(P / 128, 2), 256, 0, stream>>>(valueTb, wvb, bv, vT, nullptr);
    pos_stats_kernel<<<BB * NN * KK / 256, 256, 0, stream>>>(pos, idx, stats);
    pos_bn_kernel<<<1, 64, 0, stream>>>(stats, pw1, pb1, pg1, pbe1, posA);
    p1_kernel<<<(int)(M * PHH / 256), 256, 0, stream>>>(pos, idx, pw1, pb1, posA, p1buf);
    gemmS_kernel<PHH><<<dim3(M / 128, DIMD / 128), 256, 0, stream>>>(p1buf, pw2b, pb2, sb16, qT, kT, idx);
    mu_kernel<<<M / 512, 256, 0, stream>>>(sb16, mu);
    rg_kernel<<<dim3(RSPLIT, 4), 256, 0, stream>>>(sb16, Rpart);
    r_reduce_kernel<<<DIMD * DIMD / 256, 256, 0, stream>>>(Rpart, R);
    attn_bn_kernel<<<AHH, DIMD, 0, stream>>>(R, mu, aw1, ab1, ag1, abe1, attA);
    fused_mlp_kernel<<<(int)(M / 64), 256, 0, stream>>>(sb16, w1b, w2b, attA, ab2, idx, qT, kT, vT, aggT);
    final_kernel<<<dim3(NN / (2 * FPT), BB), 256, 0, stream>>>(aggT, we, be, valueTf, out);
}